// Round 1
// baseline (1107.705 us; speedup 1.0000x reference)
//
#include <hip/hip_runtime.h>
#include <hip/hip_bf16.h>
#include <math.h>

#define N_TOK 4096
#define DM 512
#define FDIM 128
#define G 8
#define FG 16
#define DH 128
#define DE 256
#define ES 4
#define E_EXP 32
#define LN_EPS 1e-5f
#define ETT 16   // expert token tile

__device__ __forceinline__ float gelu_t(float x) {
    const float c = 0.7978845608028654f; // sqrt(2/pi)
    float x3 = x * x * x;
    return 0.5f * x * (1.0f + tanhf(c * (x + 0.044715f * x3)));
}

// ---------------- LN of hidden: both pre_ln (-> h_norm) and rh_ln (-> hL) ----------------
__global__ void k_ln_hidden(const float* __restrict__ hidden,
                            const float* __restrict__ pg, const float* __restrict__ pb,
                            const float* __restrict__ rg, const float* __restrict__ rb,
                            float* __restrict__ h_norm, float* __restrict__ hL) {
    int n = blockIdx.x;
    int j = threadIdx.x; // 0..255
    const float* x = hidden + (size_t)n * DM;
    float v0 = x[j], v1 = x[j + 256];
    float s = v0 + v1, q = v0 * v0 + v1 * v1;
#pragma unroll
    for (int o = 32; o; o >>= 1) { s += __shfl_down(s, o); q += __shfl_down(q, o); }
    __shared__ float red[8];
    int w = j >> 6;
    if ((j & 63) == 0) { red[w] = s; red[4 + w] = q; }
    __syncthreads();
    float sum = red[0] + red[1] + red[2] + red[3];
    float sq  = red[4] + red[5] + red[6] + red[7];
    float m = sum * (1.0f / DM);
    float var = sq * (1.0f / DM) - m * m;
    float rs = rsqrtf(var + LN_EPS);
    float t0 = (v0 - m) * rs, t1 = (v1 - m) * rs;
    size_t base = (size_t)n * DM;
    h_norm[base + j]       = t0 * pg[j]       + pb[j];
    h_norm[base + j + 256] = t1 * pg[j + 256] + pb[j + 256];
    hL[base + j]           = t0 * rg[j]       + rb[j];
    hL[base + j + 256]     = t1 * rg[j + 256] + rb[j + 256];
}

// ---------------- LN of feat (sf_ln) -> sL ----------------
__global__ void k_ln_feat(const float* __restrict__ feat,
                          const float* __restrict__ g, const float* __restrict__ b,
                          float* __restrict__ sL) {
    int n = blockIdx.x;
    int j = threadIdx.x; // 0..127
    float v = feat[(size_t)n * FDIM + j];
    float s = v, q = v * v;
#pragma unroll
    for (int o = 32; o; o >>= 1) { s += __shfl_down(s, o); q += __shfl_down(q, o); }
    __shared__ float red[4];
    int w = j >> 6;
    if ((j & 63) == 0) { red[w] = s; red[2 + w] = q; }
    __syncthreads();
    float sum = red[0] + red[1], sq = red[2] + red[3];
    float m = sum * (1.0f / FDIM);
    float var = sq * (1.0f / FDIM) - m * m;
    float rs = rsqrtf(var + LN_EPS);
    sL[(size_t)n * FDIM + j] = (v - m) * rs * g[j] + b[j];
}

// ---------------- generic 2-layer MLP: Y = gelu(X@W1+b1)@W2+b2, 4 tokens/block ----------------
template <int K>
__global__ void k_mlp2(const float* __restrict__ X, const float* __restrict__ W1,
                       const float* __restrict__ B1, const float* __restrict__ W2,
                       const float* __restrict__ B2, float* __restrict__ Y) {
    __shared__ float xs[4][K];
    __shared__ float ts[4][DH];
    int n0 = blockIdx.x * 4;
    int j = threadIdx.x; // 0..127
    for (int idx = j; idx < 4 * K; idx += 128) {
        int t = idx / K, k = idx % K;
        xs[t][k] = X[(size_t)(n0 + t) * K + k];
    }
    __syncthreads();
    float a0 = 0, a1 = 0, a2 = 0, a3 = 0;
    for (int k = 0; k < K; k++) {
        float w = W1[(size_t)k * DH + j];
        a0 += xs[0][k] * w; a1 += xs[1][k] * w; a2 += xs[2][k] * w; a3 += xs[3][k] * w;
    }
    float b = B1[j];
    ts[0][j] = gelu_t(a0 + b); ts[1][j] = gelu_t(a1 + b);
    ts[2][j] = gelu_t(a2 + b); ts[3][j] = gelu_t(a3 + b);
    __syncthreads();
    a0 = a1 = a2 = a3 = 0;
    for (int i = 0; i < DH; i++) {
        float w = W2[(size_t)i * DH + j];
        a0 += ts[0][i] * w; a1 += ts[1][i] * w; a2 += ts[2][i] * w; a3 += ts[3][i] * w;
    }
    b = B2[j];
    Y[(size_t)(n0 + 0) * DH + j] = a0 + b;
    Y[(size_t)(n0 + 1) * DH + j] = a1 + b;
    Y[(size_t)(n0 + 2) * DH + j] = a2 + b;
    Y[(size_t)(n0 + 3) * DH + j] = a3 + b;
}

// ---------------- group encoders: LN(16) -> 16->128 gelu -> 128->128, 2 tokens/block ----------------
__global__ void k_group_enc(const float* __restrict__ feat,
                            const float* __restrict__ gln_g, const float* __restrict__ gln_b,
                            const float* __restrict__ gw1, const float* __restrict__ gb1,
                            const float* __restrict__ gw2, const float* __restrict__ gb2,
                            float* __restrict__ g_enc) {
    int n0 = blockIdx.x * 2;
    int j = threadIdx.x; // 0..127
    __shared__ float fs[2][FDIM];
    __shared__ float xn[2][FG];
    __shared__ float t1[2][DH];
    for (int idx = j; idx < 2 * FDIM; idx += 128)
        fs[idx / FDIM][idx % FDIM] = feat[(size_t)(n0 + idx / FDIM) * FDIM + (idx % FDIM)];
    __syncthreads();
    for (int g = 0; g < G; g++) {
        if (j < 32) {
            int t = j >> 4, i = j & 15;
            float m = 0;
            for (int k = 0; k < FG; k++) m += fs[t][g * FG + k];
            m *= (1.0f / FG);
            float q = 0;
            for (int k = 0; k < FG; k++) { float d = fs[t][g * FG + k] - m; q += d * d; }
            q *= (1.0f / FG);
            float rs = rsqrtf(q + LN_EPS);
            xn[t][i] = (fs[t][g * FG + i] - m) * rs * gln_g[g * FG + i] + gln_b[g * FG + i];
        }
        __syncthreads();
        float a0 = 0, a1 = 0;
        for (int k = 0; k < FG; k++) {
            float w = gw1[((size_t)g * FG + k) * DH + j];
            a0 += xn[0][k] * w; a1 += xn[1][k] * w;
        }
        float b = gb1[g * DH + j];
        t1[0][j] = gelu_t(a0 + b); t1[1][j] = gelu_t(a1 + b);
        __syncthreads();
        a0 = 0; a1 = 0;
        for (int i = 0; i < DH; i++) {
            float w = gw2[((size_t)g * DH + i) * DH + j];
            a0 += t1[0][i] * w; a1 += t1[1][i] * w;
        }
        b = gb2[g * DH + j];
        g_enc[((size_t)(n0 + 0) * G + g) * DH + j] = a0 + b;
        g_enc[((size_t)(n0 + 1) * G + g) * DH + j] = a1 + b;
        __syncthreads();
    }
}

// ---------------- fused router: build router_in in LDS, compute pg_h/ir_h, logits ----------------
__global__ void k_router(const float* __restrict__ h_enc, const float* __restrict__ s_enc,
                         const float* __restrict__ g_enc,
                         const float* __restrict__ pw1, const float* __restrict__ pb1,
                         const float* __restrict__ pw2, const float* __restrict__ pb2,
                         const float* __restrict__ iw1, const float* __restrict__ ib1,
                         const float* __restrict__ iw2, const float* __restrict__ ib2,
                         float* __restrict__ glog, float* __restrict__ ilog) {
    const int g = blockIdx.y;
    const int n0 = blockIdx.x * 16;
    __shared__ float rin[16][512];
    __shared__ float ph[16][DH];
    __shared__ float ih[16][DH];
    int j = threadIdx.x; // 0..127
    for (int t = 0; t < 16; t++) {
        int n = n0 + t;
        float he = h_enc[(size_t)n * DH + j];
        float se = s_enc[(size_t)n * DH + j];
        float ge = g_enc[((size_t)n * G + g) * DH + j];
        rin[t][j] = he; rin[t][128 + j] = se; rin[t][256 + j] = ge; rin[t][384 + j] = he * ge;
    }
    __syncthreads();
    float ap[16], ai[16];
#pragma unroll
    for (int t = 0; t < 16; t++) { ap[t] = 0.f; ai[t] = 0.f; }
    const float* iw1g = iw1 + (size_t)g * 512 * DH;
    for (int k = 0; k < 512; k += 4) {
        float wp0 = pw1[(size_t)(k + 0) * DH + j], wp1 = pw1[(size_t)(k + 1) * DH + j];
        float wp2 = pw1[(size_t)(k + 2) * DH + j], wp3 = pw1[(size_t)(k + 3) * DH + j];
        float wi0 = iw1g[(size_t)(k + 0) * DH + j], wi1 = iw1g[(size_t)(k + 1) * DH + j];
        float wi2 = iw1g[(size_t)(k + 2) * DH + j], wi3 = iw1g[(size_t)(k + 3) * DH + j];
#pragma unroll
        for (int t = 0; t < 16; t++) {
            float4 r = *(const float4*)&rin[t][k];
            ap[t] += r.x * wp0 + r.y * wp1 + r.z * wp2 + r.w * wp3;
            ai[t] += r.x * wi0 + r.y * wi1 + r.z * wi2 + r.w * wi3;
        }
    }
    float bp = pb1[j], bi = ib1[g * DH + j];
#pragma unroll
    for (int t = 0; t < 16; t++) {
        ph[t][j] = gelu_t(ap[t] + bp);
        ih[t][j] = gelu_t(ai[t] + bi);
    }
    __syncthreads();
    if (j < 16) {
        float s = pb2[0];
        for (int i = 0; i < DH; i++) s += ph[j][i] * pw2[i];
        glog[(size_t)(n0 + j) * G + g] = s; // TEMP = 1.0
    }
    if (j < 64) {
        int t = j >> 2, e = j & 3;
        float s = ib2[g * ES + e];
        const float* w = iw2 + (size_t)g * DH * ES;
        for (int i = 0; i < DH; i++) s += ih[t][i] * w[i * ES + e];
        ilog[((size_t)(n0 + t) * G + g) * ES + e] = s;
    }
}

// ---------------- top-k softmax + dispatch to per-expert lists ----------------
__global__ void k_topk(const float* __restrict__ glog, const float* __restrict__ ilog,
                       int* __restrict__ cnt, int* __restrict__ toks, float* __restrict__ wgts) {
    int n = blockIdx.x * blockDim.x + threadIdx.x;
    if (n >= N_TOK) return;
    float gl[G];
#pragma unroll
    for (int g = 0; g < G; g++) gl[g] = glog[(size_t)n * G + g];
    int i1 = 0; float v1 = gl[0];
#pragma unroll
    for (int g = 1; g < G; g++) if (gl[g] > v1) { v1 = gl[g]; i1 = g; }
    int i2 = -1; float v2 = -1e30f;
#pragma unroll
    for (int g = 0; g < G; g++) if (g != i1 && gl[g] > v2) { v2 = gl[g]; i2 = g; }
    float eg = expf(v2 - v1);
    float den = 1.0f / (1.0f + eg);
    float gw_sel[2] = { den, eg * den };
    int g_sel[2] = { i1, i2 };
#pragma unroll
    for (int s = 0; s < 2; s++) {
        int g = g_sel[s]; float gw = gw_sel[s];
        float il[ES];
#pragma unroll
        for (int e = 0; e < ES; e++) il[e] = ilog[((size_t)n * G + g) * ES + e];
        int j1 = 0; float u1 = il[0];
#pragma unroll
        for (int e = 1; e < ES; e++) if (il[e] > u1) { u1 = il[e]; j1 = e; }
        int j2 = -1; float u2 = -1e30f;
#pragma unroll
        for (int e = 0; e < ES; e++) if (e != j1 && il[e] > u2) { u2 = il[e]; j2 = e; }
        float ei = expf(u2 - u1);
        float d2 = 1.0f / (1.0f + ei);
        int ex1 = g * ES + j1, ex2 = g * ES + j2;
        int p1 = atomicAdd(&cnt[ex1], 1);
        toks[(size_t)ex1 * N_TOK + p1] = n; wgts[(size_t)ex1 * N_TOK + p1] = gw * d2;
        int p2 = atomicAdd(&cnt[ex2], 1);
        toks[(size_t)ex2 * N_TOK + p2] = n; wgts[(size_t)ex2 * N_TOK + p2] = gw * ei * d2;
    }
}

// ---------------- sparse expert MLPs: gather tile of tokens for one expert ----------------
__global__ void k_expert(const float* __restrict__ h_norm,
                         const float* __restrict__ ew1, const float* __restrict__ eb1,
                         const float* __restrict__ ew2, const float* __restrict__ eb2,
                         const int* __restrict__ cnt, const int* __restrict__ toks,
                         const float* __restrict__ wgts, float* __restrict__ out) {
    const int e = blockIdx.y;
    const int c = cnt[e];
    const int start = blockIdx.x * ETT;
    if (start >= c) return;
    const int m = min(ETT, c - start);
    __shared__ float hs[ETT][DM];
    __shared__ float es[ETT][DE + 1];
    __shared__ int tok_s[ETT];
    __shared__ float w_s[ETT];
    if (threadIdx.x < ETT) {
        int ok = (int)threadIdx.x < m;
        tok_s[threadIdx.x] = ok ? toks[(size_t)e * N_TOK + start + threadIdx.x] : 0;
        w_s[threadIdx.x]   = ok ? wgts[(size_t)e * N_TOK + start + threadIdx.x] : 0.f;
    }
    __syncthreads();
    for (int idx = threadIdx.x; idx < m * DM; idx += 256) {
        int t = idx >> 9, k = idx & 511;
        hs[t][k] = h_norm[(size_t)tok_s[t] * DM + k];
    }
    __syncthreads();
    // phase 1: es[t][j] = gelu(hs[t] . w1[:,j] + b1[j])
    {
        int j = threadIdx.x; // 0..255
        const float* w1 = ew1 + (size_t)e * DM * DE;
        float acc[ETT];
#pragma unroll
        for (int t = 0; t < ETT; t++) acc[t] = 0.f;
        for (int k = 0; k < DM; k += 4) {
            float wa = w1[(size_t)(k + 0) * DE + j], wb = w1[(size_t)(k + 1) * DE + j];
            float wc = w1[(size_t)(k + 2) * DE + j], wd = w1[(size_t)(k + 3) * DE + j];
#pragma unroll
            for (int t = 0; t < ETT; t++) {
                float4 h4 = *(const float4*)&hs[t][k];
                acc[t] += h4.x * wa + h4.y * wb + h4.z * wc + h4.w * wd;
            }
        }
        float b = eb1[e * DE + j];
#pragma unroll
        for (int t = 0; t < ETT; t++) es[t][j] = gelu_t(acc[t] + b);
    }
    __syncthreads();
    // phase 2: out[tok[t]] += w * (es[t] @ w2 + b2)
    {
        int t = threadIdx.x >> 4;   // 0..15
        int lb = threadIdx.x & 15;
        if (t < m) {
            const float* w2 = ew2 + (size_t)e * DE * DM;
            float4 acc4[8];
#pragma unroll
            for (int i = 0; i < 8; i++) acc4[i] = make_float4(0.f, 0.f, 0.f, 0.f);
            for (int jj = 0; jj < DE; jj++) {
                float ev = es[t][jj];
                const float4* wrow = (const float4*)(w2 + (size_t)jj * DM);
#pragma unroll
                for (int i = 0; i < 8; i++) {
                    float4 wv = wrow[i * 16 + lb];
                    acc4[i].x += ev * wv.x; acc4[i].y += ev * wv.y;
                    acc4[i].z += ev * wv.z; acc4[i].w += ev * wv.w;
                }
            }
            float w = w_s[t];
            float* orow = out + (size_t)tok_s[t] * DM;
            const float* b2 = eb2 + (size_t)e * DM;
#pragma unroll
            for (int i = 0; i < 8; i++) {
                int d = (i * 16 + lb) * 4;
                atomicAdd(&orow[d + 0], w * (acc4[i].x + b2[d + 0]));
                atomicAdd(&orow[d + 1], w * (acc4[i].y + b2[d + 1]));
                atomicAdd(&orow[d + 2], w * (acc4[i].z + b2[d + 2]));
                atomicAdd(&orow[d + 3], w * (acc4[i].w + b2[d + 3]));
            }
        }
    }
}

extern "C" void kernel_launch(void* const* d_in, const int* in_sizes, int n_in,
                              void* d_out, int out_size, void* d_ws, size_t ws_size,
                              hipStream_t stream) {
    const float* hidden  = (const float*)d_in[0];
    const float* feat    = (const float*)d_in[1];
    const float* pre_g   = (const float*)d_in[2];
    const float* pre_b   = (const float*)d_in[3];
    const float* rh_g    = (const float*)d_in[4];
    const float* rh_b    = (const float*)d_in[5];
    const float* rh_w1   = (const float*)d_in[6];
    const float* rh_b1   = (const float*)d_in[7];
    const float* rh_w2   = (const float*)d_in[8];
    const float* rh_b2   = (const float*)d_in[9];
    const float* sf_g    = (const float*)d_in[10];
    const float* sf_b    = (const float*)d_in[11];
    const float* sf_w1   = (const float*)d_in[12];
    const float* sf_b1   = (const float*)d_in[13];
    const float* sf_w2   = (const float*)d_in[14];
    const float* sf_b2   = (const float*)d_in[15];
    const float* gln_g   = (const float*)d_in[16];
    const float* gln_b   = (const float*)d_in[17];
    const float* gf_w1   = (const float*)d_in[18];
    const float* gf_b1   = (const float*)d_in[19];
    const float* gf_w2   = (const float*)d_in[20];
    const float* gf_b2   = (const float*)d_in[21];
    const float* pgs_w1  = (const float*)d_in[22];
    const float* pgs_b1  = (const float*)d_in[23];
    const float* pgs_w2  = (const float*)d_in[24];
    const float* pgs_b2  = (const float*)d_in[25];
    const float* ir_w1   = (const float*)d_in[26];
    const float* ir_b1   = (const float*)d_in[27];
    const float* ir_w2   = (const float*)d_in[28];
    const float* ir_b2   = (const float*)d_in[29];
    const float* ex_w1   = (const float*)d_in[30];
    const float* ex_b1   = (const float*)d_in[31];
    const float* ex_w2   = (const float*)d_in[32];
    const float* ex_b2   = (const float*)d_in[33];
    float* out = (float*)d_out;

    // workspace layout (fp32 unless noted)
    float* p = (float*)d_ws;
    float* h_norm = p; p += (size_t)N_TOK * DM;
    float* hL     = p; p += (size_t)N_TOK * DM;
    float* sL     = p; p += (size_t)N_TOK * FDIM;
    float* h_enc  = p; p += (size_t)N_TOK * DH;
    float* s_enc  = p; p += (size_t)N_TOK * DH;
    float* g_enc  = p; p += (size_t)N_TOK * G * DH;
    float* glog   = p; p += (size_t)N_TOK * G;
    float* ilog   = p; p += (size_t)N_TOK * G * ES;
    float* wgts   = p; p += (size_t)E_EXP * N_TOK;
    int* cnt  = (int*)p;
    int* toks = cnt + E_EXP;

    hipMemsetAsync(out, 0, (size_t)N_TOK * DM * sizeof(float), stream);
    hipMemsetAsync(cnt, 0, E_EXP * sizeof(int), stream);

    k_ln_hidden<<<N_TOK, 256, 0, stream>>>(hidden, pre_g, pre_b, rh_g, rh_b, h_norm, hL);
    k_ln_feat<<<N_TOK, 128, 0, stream>>>(feat, sf_g, sf_b, sL);
    k_mlp2<512><<<N_TOK / 4, 128, 0, stream>>>(hL, rh_w1, rh_b1, rh_w2, rh_b2, h_enc);
    k_mlp2<128><<<N_TOK / 4, 128, 0, stream>>>(sL, sf_w1, sf_b1, sf_w2, sf_b2, s_enc);
    k_group_enc<<<N_TOK / 2, 128, 0, stream>>>(feat, gln_g, gln_b, gf_w1, gf_b1, gf_w2, gf_b2, g_enc);
    dim3 rgrid(N_TOK / 16, G);
    k_router<<<rgrid, 128, 0, stream>>>(h_enc, s_enc, g_enc, pgs_w1, pgs_b1, pgs_w2, pgs_b2,
                                        ir_w1, ir_b1, ir_w2, ir_b2, glog, ilog);
    k_topk<<<N_TOK / 256, 256, 0, stream>>>(glog, ilog, cnt, toks, wgts);
    dim3 egrid(N_TOK / ETT, E_EXP);
    k_expert<<<egrid, 256, 0, stream>>>(h_norm, ex_w1, ex_b1, ex_w2, ex_b2, cnt, toks, wgts, out);
}

// Round 2
// 740.748 us; speedup vs baseline: 1.4954x; 1.4954x over previous
//
#include <hip/hip_runtime.h>
#include <hip/hip_bf16.h>
#include <math.h>

#define N_TOK 4096
#define DM 512
#define FDIM 128
#define G 8
#define FG 16
#define DH 128
#define DE 256
#define ES 4
#define E_EXP 32
#define LN_EPS 1e-5f
#define BT 32   // expert token tile (MFMA)

typedef __attribute__((ext_vector_type(8))) short bf16x8;  // 8 bf16 = 4 VGPRs
typedef __attribute__((ext_vector_type(4))) float f32x4;

__device__ __forceinline__ float gelu_t(float x) {
    const float c = 0.7978845608028654f; // sqrt(2/pi)
    float x3 = x * x * x;
    return 0.5f * x * (1.0f + tanhf(c * (x + 0.044715f * x3)));
}

__device__ __forceinline__ short f2bf(float f) {
    __hip_bfloat16 h = __float2bfloat16(f);
    return *reinterpret_cast<short*>(&h);
}

// ---------------- LN of hidden: pre_ln -> h_norm (bf16) and rh_ln -> hL (fp32) ----------------
__global__ void k_ln_hidden(const float* __restrict__ hidden,
                            const float* __restrict__ pg, const float* __restrict__ pb,
                            const float* __restrict__ rg, const float* __restrict__ rb,
                            __hip_bfloat16* __restrict__ h_normb, float* __restrict__ hL) {
    int n = blockIdx.x;
    int j = threadIdx.x; // 0..255
    const float* x = hidden + (size_t)n * DM;
    float v0 = x[j], v1 = x[j + 256];
    float s = v0 + v1, q = v0 * v0 + v1 * v1;
#pragma unroll
    for (int o = 32; o; o >>= 1) { s += __shfl_down(s, o); q += __shfl_down(q, o); }
    __shared__ float red[8];
    int w = j >> 6;
    if ((j & 63) == 0) { red[w] = s; red[4 + w] = q; }
    __syncthreads();
    float sum = red[0] + red[1] + red[2] + red[3];
    float sq  = red[4] + red[5] + red[6] + red[7];
    float m = sum * (1.0f / DM);
    float var = sq * (1.0f / DM) - m * m;
    float rs = rsqrtf(var + LN_EPS);
    float t0 = (v0 - m) * rs, t1 = (v1 - m) * rs;
    size_t base = (size_t)n * DM;
    h_normb[base + j]       = __float2bfloat16(t0 * pg[j]       + pb[j]);
    h_normb[base + j + 256] = __float2bfloat16(t1 * pg[j + 256] + pb[j + 256]);
    hL[base + j]           = t0 * rg[j]       + rb[j];
    hL[base + j + 256]     = t1 * rg[j + 256] + rb[j + 256];
}

// ---------------- LN of feat (sf_ln) -> sL ----------------
__global__ void k_ln_feat(const float* __restrict__ feat,
                          const float* __restrict__ g, const float* __restrict__ b,
                          float* __restrict__ sL) {
    int n = blockIdx.x;
    int j = threadIdx.x; // 0..127
    float v = feat[(size_t)n * FDIM + j];
    float s = v, q = v * v;
#pragma unroll
    for (int o = 32; o; o >>= 1) { s += __shfl_down(s, o); q += __shfl_down(q, o); }
    __shared__ float red[4];
    int w = j >> 6;
    if ((j & 63) == 0) { red[w] = s; red[2 + w] = q; }
    __syncthreads();
    float sum = red[0] + red[1], sq = red[2] + red[3];
    float m = sum * (1.0f / FDIM);
    float var = sq * (1.0f / FDIM) - m * m;
    float rs = rsqrtf(var + LN_EPS);
    sL[(size_t)n * FDIM + j] = (v - m) * rs * g[j] + b[j];
}

// ---------------- generic 2-layer MLP: Y = gelu(X@W1+b1)@W2+b2, 4 tokens/block ----------------
template <int K>
__global__ void k_mlp2(const float* __restrict__ X, const float* __restrict__ W1,
                       const float* __restrict__ B1, const float* __restrict__ W2,
                       const float* __restrict__ B2, float* __restrict__ Y) {
    __shared__ float xs[4][K];
    __shared__ float ts[4][DH];
    int n0 = blockIdx.x * 4;
    int j = threadIdx.x; // 0..127
    for (int idx = j; idx < 4 * K; idx += 128) {
        int t = idx / K, k = idx % K;
        xs[t][k] = X[(size_t)(n0 + t) * K + k];
    }
    __syncthreads();
    float a0 = 0, a1 = 0, a2 = 0, a3 = 0;
    for (int k = 0; k < K; k++) {
        float w = W1[(size_t)k * DH + j];
        a0 += xs[0][k] * w; a1 += xs[1][k] * w; a2 += xs[2][k] * w; a3 += xs[3][k] * w;
    }
    float b = B1[j];
    ts[0][j] = gelu_t(a0 + b); ts[1][j] = gelu_t(a1 + b);
    ts[2][j] = gelu_t(a2 + b); ts[3][j] = gelu_t(a3 + b);
    __syncthreads();
    a0 = a1 = a2 = a3 = 0;
    for (int i = 0; i < DH; i++) {
        float w = W2[(size_t)i * DH + j];
        a0 += ts[0][i] * w; a1 += ts[1][i] * w; a2 += ts[2][i] * w; a3 += ts[3][i] * w;
    }
    b = B2[j];
    Y[(size_t)(n0 + 0) * DH + j] = a0 + b;
    Y[(size_t)(n0 + 1) * DH + j] = a1 + b;
    Y[(size_t)(n0 + 2) * DH + j] = a2 + b;
    Y[(size_t)(n0 + 3) * DH + j] = a3 + b;
}

// ---------------- group encoders: LN(16) -> 16->128 gelu -> 128->128, 2 tokens/block ----------------
__global__ void k_group_enc(const float* __restrict__ feat,
                            const float* __restrict__ gln_g, const float* __restrict__ gln_b,
                            const float* __restrict__ gw1, const float* __restrict__ gb1,
                            const float* __restrict__ gw2, const float* __restrict__ gb2,
                            float* __restrict__ g_enc) {
    int n0 = blockIdx.x * 2;
    int j = threadIdx.x; // 0..127
    __shared__ float fs[2][FDIM];
    __shared__ float xn[2][FG];
    __shared__ float t1[2][DH];
    for (int idx = j; idx < 2 * FDIM; idx += 128)
        fs[idx / FDIM][idx % FDIM] = feat[(size_t)(n0 + idx / FDIM) * FDIM + (idx % FDIM)];
    __syncthreads();
    for (int g = 0; g < G; g++) {
        if (j < 32) {
            int t = j >> 4, i = j & 15;
            float m = 0;
            for (int k = 0; k < FG; k++) m += fs[t][g * FG + k];
            m *= (1.0f / FG);
            float q = 0;
            for (int k = 0; k < FG; k++) { float d = fs[t][g * FG + k] - m; q += d * d; }
            q *= (1.0f / FG);
            float rs = rsqrtf(q + LN_EPS);
            xn[t][i] = (fs[t][g * FG + i] - m) * rs * gln_g[g * FG + i] + gln_b[g * FG + i];
        }
        __syncthreads();
        float a0 = 0, a1 = 0;
        for (int k = 0; k < FG; k++) {
            float w = gw1[((size_t)g * FG + k) * DH + j];
            a0 += xn[0][k] * w; a1 += xn[1][k] * w;
        }
        float b = gb1[g * DH + j];
        t1[0][j] = gelu_t(a0 + b); t1[1][j] = gelu_t(a1 + b);
        __syncthreads();
        a0 = 0; a1 = 0;
        for (int i = 0; i < DH; i++) {
            float w = gw2[((size_t)g * DH + i) * DH + j];
            a0 += t1[0][i] * w; a1 += t1[1][i] * w;
        }
        b = gb2[g * DH + j];
        g_enc[((size_t)(n0 + 0) * G + g) * DH + j] = a0 + b;
        g_enc[((size_t)(n0 + 1) * G + g) * DH + j] = a1 + b;
        __syncthreads();
    }
}

// ---------------- fused router: build router_in in LDS, compute pg_h/ir_h, logits ----------------
__global__ void k_router(const float* __restrict__ h_enc, const float* __restrict__ s_enc,
                         const float* __restrict__ g_enc,
                         const float* __restrict__ pw1, const float* __restrict__ pb1,
                         const float* __restrict__ pw2, const float* __restrict__ pb2,
                         const float* __restrict__ iw1, const float* __restrict__ ib1,
                         const float* __restrict__ iw2, const float* __restrict__ ib2,
                         float* __restrict__ glog, float* __restrict__ ilog) {
    const int g = blockIdx.y;
    const int n0 = blockIdx.x * 16;
    __shared__ float rin[16][512];
    __shared__ float ph[16][DH];
    __shared__ float ih[16][DH];
    int j = threadIdx.x; // 0..127
    for (int t = 0; t < 16; t++) {
        int n = n0 + t;
        float he = h_enc[(size_t)n * DH + j];
        float se = s_enc[(size_t)n * DH + j];
        float ge = g_enc[((size_t)n * G + g) * DH + j];
        rin[t][j] = he; rin[t][128 + j] = se; rin[t][256 + j] = ge; rin[t][384 + j] = he * ge;
    }
    __syncthreads();
    float ap[16], ai[16];
#pragma unroll
    for (int t = 0; t < 16; t++) { ap[t] = 0.f; ai[t] = 0.f; }
    const float* iw1g = iw1 + (size_t)g * 512 * DH;
    for (int k = 0; k < 512; k += 4) {
        float wp0 = pw1[(size_t)(k + 0) * DH + j], wp1 = pw1[(size_t)(k + 1) * DH + j];
        float wp2 = pw1[(size_t)(k + 2) * DH + j], wp3 = pw1[(size_t)(k + 3) * DH + j];
        float wi0 = iw1g[(size_t)(k + 0) * DH + j], wi1 = iw1g[(size_t)(k + 1) * DH + j];
        float wi2 = iw1g[(size_t)(k + 2) * DH + j], wi3 = iw1g[(size_t)(k + 3) * DH + j];
#pragma unroll
        for (int t = 0; t < 16; t++) {
            float4 r = *(const float4*)&rin[t][k];
            ap[t] += r.x * wp0 + r.y * wp1 + r.z * wp2 + r.w * wp3;
            ai[t] += r.x * wi0 + r.y * wi1 + r.z * wi2 + r.w * wi3;
        }
    }
    float bp = pb1[j], bi = ib1[g * DH + j];
#pragma unroll
    for (int t = 0; t < 16; t++) {
        ph[t][j] = gelu_t(ap[t] + bp);
        ih[t][j] = gelu_t(ai[t] + bi);
    }
    __syncthreads();
    if (j < 16) {
        float s = pb2[0];
        for (int i = 0; i < DH; i++) s += ph[j][i] * pw2[i];
        glog[(size_t)(n0 + j) * G + g] = s; // TEMP = 1.0
    }
    if (j < 64) {
        int t = j >> 2, e = j & 3;
        float s = ib2[g * ES + e];
        const float* w = iw2 + (size_t)g * DH * ES;
        for (int i = 0; i < DH; i++) s += ih[t][i] * w[i * ES + e];
        ilog[((size_t)(n0 + t) * G + g) * ES + e] = s;
    }
}

// ---------------- top-k softmax + dispatch to per-expert lists ----------------
// toks entries are packed (n*4 + slot); part buffer is indexed by that value.
__global__ void k_topk(const float* __restrict__ glog, const float* __restrict__ ilog,
                       int* __restrict__ cnt, int* __restrict__ toks, float* __restrict__ wgts) {
    int n = blockIdx.x * blockDim.x + threadIdx.x;
    if (n >= N_TOK) return;
    float gl[G];
#pragma unroll
    for (int g = 0; g < G; g++) gl[g] = glog[(size_t)n * G + g];
    int i1 = 0; float v1 = gl[0];
#pragma unroll
    for (int g = 1; g < G; g++) if (gl[g] > v1) { v1 = gl[g]; i1 = g; }
    int i2 = -1; float v2 = -1e30f;
#pragma unroll
    for (int g = 0; g < G; g++) if (g != i1 && gl[g] > v2) { v2 = gl[g]; i2 = g; }
    float eg = expf(v2 - v1);
    float den = 1.0f / (1.0f + eg);
    float gw_sel[2] = { den, eg * den };
    int g_sel[2] = { i1, i2 };
#pragma unroll
    for (int s = 0; s < 2; s++) {
        int g = g_sel[s]; float gw = gw_sel[s];
        float il[ES];
#pragma unroll
        for (int e = 0; e < ES; e++) il[e] = ilog[((size_t)n * G + g) * ES + e];
        int j1 = 0; float u1 = il[0];
#pragma unroll
        for (int e = 1; e < ES; e++) if (il[e] > u1) { u1 = il[e]; j1 = e; }
        int j2 = -1; float u2 = -1e30f;
#pragma unroll
        for (int e = 0; e < ES; e++) if (e != j1 && il[e] > u2) { u2 = il[e]; j2 = e; }
        float ei = expf(u2 - u1);
        float d2 = 1.0f / (1.0f + ei);
        int ex1 = g * ES + j1, ex2 = g * ES + j2;
        int p1 = atomicAdd(&cnt[ex1], 1);
        toks[(size_t)ex1 * N_TOK + p1] = n * 4 + s * 2;     wgts[(size_t)ex1 * N_TOK + p1] = gw * d2;
        int p2 = atomicAdd(&cnt[ex2], 1);
        toks[(size_t)ex2 * N_TOK + p2] = n * 4 + s * 2 + 1; wgts[(size_t)ex2 * N_TOK + p2] = gw * ei * d2;
    }
}

// ---------------- weight re-tiling to MFMA B-fragment layout, bf16 ----------------
// dst[((e*KB + kb)*NB + nb)*512 + lane*8 + j] = bf16(src[e][kb*32 + (lane>>4)*8 + j][nb*16 + (lane&15)])
__global__ void k_conv_w(const float* __restrict__ src, short* __restrict__ dst, int KB, int NB) {
    int e = blockIdx.x / KB, kb = blockIdx.x % KB;
    const float* s = src + (size_t)e * (size_t)(KB * 32) * (NB * 16);
    short* d = dst + (size_t)blockIdx.x * NB * 512;
    int ncols = NB * 16;
    for (int p = threadIdx.x; p < NB * 64; p += 256) {
        int nb = p >> 6, lane = p & 63;
        int row0 = kb * 32 + ((lane >> 4) << 3);
        int col = nb * 16 + (lane & 15);
        union { short sh[8]; uint4 v; } tmp;
#pragma unroll
        for (int j = 0; j < 8; j++) tmp.sh[j] = f2bf(s[(size_t)(row0 + j) * ncols + col]);
        *(uint4*)&d[(size_t)p * 8] = tmp.v;
    }
}

// ---------------- sparse expert MLPs via bf16 MFMA ----------------
// part[(n*4+slot)*DM + d] = w * (expert_out + b2)   (each (n,slot) written exactly once)
__global__ __launch_bounds__(256) void k_expert_mfma(
        const __hip_bfloat16* __restrict__ h_normb,
        const short* __restrict__ wB1, const float* __restrict__ eb1,
        const short* __restrict__ wB2, const float* __restrict__ eb2,
        const int* __restrict__ cnt, const int* __restrict__ toks,
        const float* __restrict__ wgts, float* __restrict__ part) {
    const int e = blockIdx.y;
    const int c = cnt[e];
    const int start = blockIdx.x * BT;
    if (start >= c) return;
    const int m = min(BT, c - start);

    __shared__ short hs[BT][520];   // bf16 bits, row pad -> 2-way bank aliasing (free)
    __shared__ short es[BT][264];
    __shared__ int   tok_s[BT];     // packed n*4+slot
    __shared__ float w_s[BT];

    const int tid = threadIdx.x;
    if (tid < BT) {
        bool ok = tid < m;
        tok_s[tid] = ok ? toks[(size_t)e * N_TOK + start + tid] : 0;
        w_s[tid]   = ok ? wgts[(size_t)e * N_TOK + start + tid] : 0.f;
    }
    __syncthreads();
    // gather 32 token rows (512 bf16 each) into LDS; zero the padding rows
    for (int idx = tid; idx < BT * 64; idx += 256) {
        int t = idx >> 6, ch = idx & 63;
        uint4 v = make_uint4(0, 0, 0, 0);
        if (t < m) v = *((const uint4*)(h_normb + (size_t)(tok_s[t] >> 2) * DM) + ch);
        *(uint4*)&hs[t][ch * 8] = v;
    }
    __syncthreads();

    const int wave = tid >> 6, lane = tid & 63;
    const int quad = lane >> 4, lm = lane & 15;
    const int mt = wave & 1;            // token tile (16 rows)

    // ---- phase 1: es = gelu(hs @ W1 + b1), 32x256 ----
    {
        const int ng = (wave >> 1) * 8; // 8 n-tiles of 16 per wave
        f32x4 acc[8];
#pragma unroll
        for (int i = 0; i < 8; i++) acc[i] = (f32x4)(0.f);
        const short* w1e = wB1 + (size_t)e * DM * DE;
        for (int kb = 0; kb < 16; kb++) {
            bf16x8 a = *(const bf16x8*)&hs[mt * 16 + lm][kb * 32 + quad * 8];
            const short* wp = w1e + ((size_t)kb * 16 + ng) * 512 + lane * 8;
#pragma unroll
            for (int nt = 0; nt < 8; nt++) {
                bf16x8 b = *(const bf16x8*)(wp + nt * 512);
                acc[nt] = __builtin_amdgcn_mfma_f32_16x16x32_bf16(a, b, acc[nt], 0, 0, 0);
            }
        }
#pragma unroll
        for (int nt = 0; nt < 8; nt++) {
            int col = (ng + nt) * 16 + lm;
            float b1 = eb1[e * DE + col];
#pragma unroll
            for (int r = 0; r < 4; r++) {
                int row = mt * 16 + quad * 4 + r;
                es[row][col] = f2bf(gelu_t(acc[nt][r] + b1));
            }
        }
    }
    __syncthreads();

    // ---- phase 2: part[tok] = w * (es @ W2 + b2), 32x512 ----
    {
        const int ng2 = (wave >> 1) * 16; // 16 n-tiles of 16 per wave
        f32x4 acc[16];
#pragma unroll
        for (int i = 0; i < 16; i++) acc[i] = (f32x4)(0.f);
        const short* w2e = wB2 + (size_t)e * DE * DM;
        for (int kb = 0; kb < 8; kb++) {
            bf16x8 a = *(const bf16x8*)&es[mt * 16 + lm][kb * 32 + quad * 8];
            const short* wp = w2e + ((size_t)kb * 32 + ng2) * 512 + lane * 8;
#pragma unroll
            for (int nt = 0; nt < 16; nt++) {
                bf16x8 b = *(const bf16x8*)(wp + nt * 512);
                acc[nt] = __builtin_amdgcn_mfma_f32_16x16x32_bf16(a, b, acc[nt], 0, 0, 0);
            }
        }
        const float* b2 = eb2 + (size_t)e * DM;
#pragma unroll
        for (int r = 0; r < 4; r++) {
            int row = mt * 16 + quad * 4 + r;
            if (row < m) {
                float w = w_s[row];
                float* prow = part + (size_t)tok_s[row] * DM;
#pragma unroll
                for (int nt = 0; nt < 16; nt++) {
                    int col = (ng2 + nt) * 16 + lm;
                    prow[col] = w * (acc[nt][r] + b2[col]);
                }
            }
        }
    }
}

// ---------------- final reduce: out[n] = sum_s part[n*4+s] ----------------
__global__ void k_reduce(const float* __restrict__ part, float* __restrict__ out) {
    int n = blockIdx.x;
    int j = threadIdx.x; // 0..127
    const float4* p = (const float4*)(part + (size_t)n * 4 * DM);
    float4 a = p[j], b = p[128 + j], c = p[256 + j], d = p[384 + j];
    float4 r = make_float4(a.x + b.x + c.x + d.x, a.y + b.y + c.y + d.y,
                           a.z + b.z + c.z + d.z, a.w + b.w + c.w + d.w);
    ((float4*)(out + (size_t)n * DM))[j] = r;
}

extern "C" void kernel_launch(void* const* d_in, const int* in_sizes, int n_in,
                              void* d_out, int out_size, void* d_ws, size_t ws_size,
                              hipStream_t stream) {
    const float* hidden  = (const float*)d_in[0];
    const float* feat    = (const float*)d_in[1];
    const float* pre_g   = (const float*)d_in[2];
    const float* pre_b   = (const float*)d_in[3];
    const float* rh_g    = (const float*)d_in[4];
    const float* rh_b    = (const float*)d_in[5];
    const float* rh_w1   = (const float*)d_in[6];
    const float* rh_b1   = (const float*)d_in[7];
    const float* rh_w2   = (const float*)d_in[8];
    const float* rh_b2   = (const float*)d_in[9];
    const float* sf_g    = (const float*)d_in[10];
    const float* sf_b    = (const float*)d_in[11];
    const float* sf_w1   = (const float*)d_in[12];
    const float* sf_b1   = (const float*)d_in[13];
    const float* sf_w2   = (const float*)d_in[14];
    const float* sf_b2   = (const float*)d_in[15];
    const float* gln_g   = (const float*)d_in[16];
    const float* gln_b   = (const float*)d_in[17];
    const float* gf_w1   = (const float*)d_in[18];
    const float* gf_b1   = (const float*)d_in[19];
    const float* gf_w2   = (const float*)d_in[20];
    const float* gf_b2   = (const float*)d_in[21];
    const float* pgs_w1  = (const float*)d_in[22];
    const float* pgs_b1  = (const float*)d_in[23];
    const float* pgs_w2  = (const float*)d_in[24];
    const float* pgs_b2  = (const float*)d_in[25];
    const float* ir_w1   = (const float*)d_in[26];
    const float* ir_b1   = (const float*)d_in[27];
    const float* ir_w2   = (const float*)d_in[28];
    const float* ir_b2   = (const float*)d_in[29];
    const float* ex_w1   = (const float*)d_in[30];
    const float* ex_b1   = (const float*)d_in[31];
    const float* ex_w2   = (const float*)d_in[32];
    const float* ex_b2   = (const float*)d_in[33];
    float* out = (float*)d_out;

    // workspace carving (256B-aligned)
    char* w = (char*)d_ws;
    auto alloc = [&](size_t bytes) { void* r = (void*)w; w += (bytes + 255) & ~(size_t)255; return r; };
    __hip_bfloat16* h_normb = (__hip_bfloat16*)alloc((size_t)N_TOK * DM * 2);
    float* hL    = (float*)alloc((size_t)N_TOK * DM * 4);
    float* sL    = (float*)alloc((size_t)N_TOK * FDIM * 4);
    float* h_enc = (float*)alloc((size_t)N_TOK * DH * 4);
    float* s_enc = (float*)alloc((size_t)N_TOK * DH * 4);
    float* g_enc = (float*)alloc((size_t)N_TOK * G * DH * 4);
    float* glog  = (float*)alloc((size_t)N_TOK * G * 4);
    float* ilog  = (float*)alloc((size_t)N_TOK * G * ES * 4);
    float* wgts  = (float*)alloc((size_t)E_EXP * N_TOK * 4);
    short* wB1   = (short*)alloc((size_t)E_EXP * DM * DE * 2);
    short* wB2   = (short*)alloc((size_t)E_EXP * DE * DM * 2);
    float* part  = (float*)alloc((size_t)N_TOK * 4 * DM * 4);
    int* cnt     = (int*)alloc(E_EXP * 4);
    int* toks    = (int*)alloc((size_t)E_EXP * N_TOK * 4);

    hipMemsetAsync(cnt, 0, E_EXP * sizeof(int), stream);

    // weight re-tiling (independent of token pipeline)
    k_conv_w<<<E_EXP * 16, 256, 0, stream>>>(ex_w1, wB1, 16, 16);
    k_conv_w<<<E_EXP * 8, 256, 0, stream>>>(ex_w2, wB2, 8, 32);

    k_ln_hidden<<<N_TOK, 256, 0, stream>>>(hidden, pre_g, pre_b, rh_g, rh_b, h_normb, hL);
    k_ln_feat<<<N_TOK, 128, 0, stream>>>(feat, sf_g, sf_b, sL);
    k_mlp2<512><<<N_TOK / 4, 128, 0, stream>>>(hL, rh_w1, rh_b1, rh_w2, rh_b2, h_enc);
    k_mlp2<128><<<N_TOK / 4, 128, 0, stream>>>(sL, sf_w1, sf_b1, sf_w2, sf_b2, s_enc);
    k_group_enc<<<N_TOK / 2, 128, 0, stream>>>(feat, gln_g, gln_b, gf_w1, gf_b1, gf_w2, gf_b2, g_enc);
    dim3 rgrid(N_TOK / 16, G);
    k_router<<<rgrid, 128, 0, stream>>>(h_enc, s_enc, g_enc, pgs_w1, pgs_b1, pgs_w2, pgs_b2,
                                        ir_w1, ir_b1, ir_w2, ir_b2, glog, ilog);
    k_topk<<<N_TOK / 256, 256, 0, stream>>>(glog, ilog, cnt, toks, wgts);
    dim3 egrid(N_TOK / BT, E_EXP);
    k_expert_mfma<<<egrid, 256, 0, stream>>>(h_normb, wB1, ex_b1, wB2, ex_b2, cnt, toks, wgts, part);
    k_reduce<<<N_TOK, 128, 0, stream>>>(part, out);
}

// Round 4
// 496.464 us; speedup vs baseline: 2.2312x; 1.4920x over previous
//
#include <hip/hip_runtime.h>
#include <hip/hip_bf16.h>
#include <math.h>

#define N_TOK 4096
#define DM 512
#define FDIM 128
#define G 8
#define FG 16
#define DH 128
#define DE 256
#define ES 4
#define E_EXP 32
#define LN_EPS 1e-5f
#define BT 32   // expert token tile (MFMA)
#define GP 4    // groups per router pass (memory cap)

typedef __attribute__((ext_vector_type(8))) short bf16x8;  // 8 bf16 = 4 VGPRs
typedef __attribute__((ext_vector_type(4))) float f32x4;

__device__ __forceinline__ float gelu_t(float x) {
    const float c = 0.7978845608028654f; // sqrt(2/pi)
    float x3 = x * x * x;
    return 0.5f * x * (1.0f + tanhf(c * (x + 0.044715f * x3)));
}

__device__ __forceinline__ short f2bf(float f) {
    __hip_bfloat16 h = __float2bfloat16(f);
    return *reinterpret_cast<short*>(&h);
}
__device__ __forceinline__ float bf2f(short s) {
    __hip_bfloat16 h = *reinterpret_cast<__hip_bfloat16*>(&s);
    return __bfloat162float(h);
}
// exact 3-way split: x == bf2f(h)+bf2f(m)+bf2f(l) bit-exactly for fp32 x
__device__ __forceinline__ void split3(float x, short& h, short& m, short& l) {
    h = f2bf(x);
    float r = x - bf2f(h);   // exact in fp32
    m = f2bf(r);
    float r2 = r - bf2f(m);  // exact; <=6 significant bits remain
    l = f2bf(r2);            // exact
}

// ---------------- LN of hidden: pre_ln -> h_norm (bf16) and rh_ln -> hL (fp32) ----------------
__global__ void k_ln_hidden(const float* __restrict__ hidden,
                            const float* __restrict__ pg, const float* __restrict__ pb,
                            const float* __restrict__ rg, const float* __restrict__ rb,
                            __hip_bfloat16* __restrict__ h_normb, float* __restrict__ hL) {
    int n = blockIdx.x;
    int j = threadIdx.x; // 0..255
    const float* x = hidden + (size_t)n * DM;
    float v0 = x[j], v1 = x[j + 256];
    float s = v0 + v1, q = v0 * v0 + v1 * v1;
#pragma unroll
    for (int o = 32; o; o >>= 1) { s += __shfl_down(s, o); q += __shfl_down(q, o); }
    __shared__ float red[8];
    int w = j >> 6;
    if ((j & 63) == 0) { red[w] = s; red[4 + w] = q; }
    __syncthreads();
    float sum = red[0] + red[1] + red[2] + red[3];
    float sq  = red[4] + red[5] + red[6] + red[7];
    float m = sum * (1.0f / DM);
    float var = sq * (1.0f / DM) - m * m;
    float rs = rsqrtf(var + LN_EPS);
    float t0 = (v0 - m) * rs, t1 = (v1 - m) * rs;
    size_t base = (size_t)n * DM;
    h_normb[base + j]       = __float2bfloat16(t0 * pg[j]       + pb[j]);
    h_normb[base + j + 256] = __float2bfloat16(t1 * pg[j + 256] + pb[j + 256]);
    hL[base + j]           = t0 * rg[j]       + rb[j];
    hL[base + j + 256]     = t1 * rg[j + 256] + rb[j + 256];
}

// ---------------- LN of feat (sf_ln) -> sL ----------------
__global__ void k_ln_feat(const float* __restrict__ feat,
                          const float* __restrict__ g, const float* __restrict__ b,
                          float* __restrict__ sL) {
    int n = blockIdx.x;
    int j = threadIdx.x; // 0..127
    float v = feat[(size_t)n * FDIM + j];
    float s = v, q = v * v;
#pragma unroll
    for (int o = 32; o; o >>= 1) { s += __shfl_down(s, o); q += __shfl_down(q, o); }
    __shared__ float red[4];
    int w = j >> 6;
    if ((j & 63) == 0) { red[w] = s; red[2 + w] = q; }
    __syncthreads();
    float sum = red[0] + red[1], sq = red[2] + red[3];
    float m = sum * (1.0f / FDIM);
    float var = sq * (1.0f / FDIM) - m * m;
    float rs = rsqrtf(var + LN_EPS);
    sL[(size_t)n * FDIM + j] = (v - m) * rs * g[j] + b[j];
}

// ---------------- generic 2-layer MLP: Y = gelu(X@W1+b1)@W2+b2, 4 tokens/block ----------------
template <int K>
__global__ void k_mlp2(const float* __restrict__ X, const float* __restrict__ W1,
                       const float* __restrict__ B1, const float* __restrict__ W2,
                       const float* __restrict__ B2, float* __restrict__ Y) {
    __shared__ float xs[4][K];
    __shared__ float ts[4][DH];
    int n0 = blockIdx.x * 4;
    int j = threadIdx.x; // 0..127
    for (int idx = j; idx < 4 * K; idx += 128) {
        int t = idx / K, k = idx % K;
        xs[t][k] = X[(size_t)(n0 + t) * K + k];
    }
    __syncthreads();
    float a0 = 0, a1 = 0, a2 = 0, a3 = 0;
    for (int k = 0; k < K; k++) {
        float w = W1[(size_t)k * DH + j];
        a0 += xs[0][k] * w; a1 += xs[1][k] * w; a2 += xs[2][k] * w; a3 += xs[3][k] * w;
    }
    float b = B1[j];
    ts[0][j] = gelu_t(a0 + b); ts[1][j] = gelu_t(a1 + b);
    ts[2][j] = gelu_t(a2 + b); ts[3][j] = gelu_t(a3 + b);
    __syncthreads();
    a0 = a1 = a2 = a3 = 0;
    for (int i = 0; i < DH; i++) {
        float w = W2[(size_t)i * DH + j];
        a0 += ts[0][i] * w; a1 += ts[1][i] * w; a2 += ts[2][i] * w; a3 += ts[3][i] * w;
    }
    b = B2[j];
    Y[(size_t)(n0 + 0) * DH + j] = a0 + b;
    Y[(size_t)(n0 + 1) * DH + j] = a1 + b;
    Y[(size_t)(n0 + 2) * DH + j] = a2 + b;
    Y[(size_t)(n0 + 3) * DH + j] = a3 + b;
}

// ---------------- group encoders: LN(16) -> 16->128 gelu -> 128->128, 2 tokens/block ----------------
__global__ void k_group_enc(const float* __restrict__ feat,
                            const float* __restrict__ gln_g, const float* __restrict__ gln_b,
                            const float* __restrict__ gw1, const float* __restrict__ gb1,
                            const float* __restrict__ gw2, const float* __restrict__ gb2,
                            float* __restrict__ g_enc) {
    int n0 = blockIdx.x * 2;
    int j = threadIdx.x; // 0..127
    __shared__ float fs[2][FDIM];
    __shared__ float xn[2][FG];
    __shared__ float t1[2][DH];
    for (int idx = j; idx < 2 * FDIM; idx += 128)
        fs[idx / FDIM][idx % FDIM] = feat[(size_t)(n0 + idx / FDIM) * FDIM + (idx % FDIM)];
    __syncthreads();
    for (int g = 0; g < G; g++) {
        if (j < 32) {
            int t = j >> 4, i = j & 15;
            float m = 0;
            for (int k = 0; k < FG; k++) m += fs[t][g * FG + k];
            m *= (1.0f / FG);
            float q = 0;
            for (int k = 0; k < FG; k++) { float d = fs[t][g * FG + k] - m; q += d * d; }
            q *= (1.0f / FG);
            float rs = rsqrtf(q + LN_EPS);
            xn[t][i] = (fs[t][g * FG + i] - m) * rs * gln_g[g * FG + i] + gln_b[g * FG + i];
        }
        __syncthreads();
        float a0 = 0, a1 = 0;
        for (int k = 0; k < FG; k++) {
            float w = gw1[((size_t)g * FG + k) * DH + j];
            a0 += xn[0][k] * w; a1 += xn[1][k] * w;
        }
        float b = gb1[g * DH + j];
        t1[0][j] = gelu_t(a0 + b); t1[1][j] = gelu_t(a1 + b);
        __syncthreads();
        a0 = 0; a1 = 0;
        for (int i = 0; i < DH; i++) {
            float w = gw2[((size_t)g * DH + i) * DH + j];
            a0 += t1[0][i] * w; a1 += t1[1][i] * w;
        }
        b = gb2[g * DH + j];
        g_enc[((size_t)(n0 + 0) * G + g) * DH + j] = a0 + b;
        g_enc[((size_t)(n0 + 1) * G + g) * DH + j] = a1 + b;
        __syncthreads();
    }
}

// ---------------- stage A-fragments (3-way split bf16) for router layer-1 ----------------
// A_hs: k in [0,256) = [h_enc | s_enc], layout [(T16*8 + kb)*64 + lane]*8
__global__ void k_stage_hs(const float* __restrict__ h_enc, const float* __restrict__ s_enc,
                           short* __restrict__ Ah, short* __restrict__ Am, short* __restrict__ Al) {
    int T16 = blockIdx.x;
    for (int slot = threadIdx.x; slot < 512; slot += 256) {
        int kb = slot >> 6, lane = slot & 63;
        int quad = lane >> 4, lm = lane & 15;
        int n = T16 * 16 + lm;
        int c0 = kb * 32 + quad * 8; // 0..255
        const float* src = (c0 < 128) ? (h_enc + (size_t)n * DH + c0)
                                      : (s_enc + (size_t)n * DH + (c0 - 128));
        float4 x0 = *(const float4*)src;
        float4 x1 = *(const float4*)(src + 4);
        float xv[8] = {x0.x, x0.y, x0.z, x0.w, x1.x, x1.y, x1.z, x1.w};
        union { short sh[8]; uint4 v; } hi, mi, lo;
#pragma unroll
        for (int j = 0; j < 8; j++) split3(xv[j], hi.sh[j], mi.sh[j], lo.sh[j]);
        size_t base = ((size_t)T16 * 512 + slot) * 8;
        *(uint4*)&Ah[base] = hi.v;
        *(uint4*)&Am[base] = mi.v;
        *(uint4*)&Al[base] = lo.v;
    }
}

// A_g: k in [256,512) = [g_enc | h_enc*g_enc], pass of GP groups starting g0
// layout [((T16*GP + gl)*8 + kbl)*64 + lane]*8
__global__ void k_stage_g(const float* __restrict__ h_enc, const float* __restrict__ g_enc,
                          short* __restrict__ Ah, short* __restrict__ Am, short* __restrict__ Al,
                          int g0) {
    int T16 = blockIdx.x, gl = blockIdx.y;
    int g = g0 + gl;
    for (int slot = threadIdx.x; slot < 512; slot += 256) {
        int kb = slot >> 6, lane = slot & 63;
        int quad = lane >> 4, lm = lane & 15;
        int n = T16 * 16 + lm;
        int c0 = kb * 32 + quad * 8; // 0..255
        float xv[8];
        if (c0 < 128) {
            const float* gs = g_enc + ((size_t)n * G + g) * DH + c0;
            float4 x0 = *(const float4*)gs, x1 = *(const float4*)(gs + 4);
            xv[0]=x0.x; xv[1]=x0.y; xv[2]=x0.z; xv[3]=x0.w;
            xv[4]=x1.x; xv[5]=x1.y; xv[6]=x1.z; xv[7]=x1.w;
        } else {
            int c = c0 - 128;
            const float* gs = g_enc + ((size_t)n * G + g) * DH + c;
            const float* hs = h_enc + (size_t)n * DH + c;
            float4 g0v = *(const float4*)gs, g1v = *(const float4*)(gs + 4);
            float4 h0v = *(const float4*)hs, h1v = *(const float4*)(hs + 4);
            xv[0]=h0v.x*g0v.x; xv[1]=h0v.y*g0v.y; xv[2]=h0v.z*g0v.z; xv[3]=h0v.w*g0v.w;
            xv[4]=h1v.x*g1v.x; xv[5]=h1v.y*g1v.y; xv[6]=h1v.z*g1v.z; xv[7]=h1v.w*g1v.w;
        }
        union { short sh[8]; uint4 v; } hi, mi, lo;
#pragma unroll
        for (int j = 0; j < 8; j++) split3(xv[j], hi.sh[j], mi.sh[j], lo.sh[j]);
        size_t base = (((size_t)T16 * GP + gl) * 512 + slot) * 8;
        *(uint4*)&Ah[base] = hi.v;
        *(uint4*)&Am[base] = mi.v;
        *(uint4*)&Al[base] = lo.v;
    }
}

// ---------------- weight conversion to B-frag layout, 3-way split ----------------
__global__ void k_conv_b3(const float* __restrict__ src, short* __restrict__ dh,
                          short* __restrict__ dm, short* __restrict__ dl, int KB, int NB) {
    int mat = blockIdx.x / KB, kb = blockIdx.x % KB;
    int ncols = NB * 16;
    const float* s = src + (size_t)mat * (size_t)(KB * 32) * ncols;
    size_t dbase = ((size_t)mat * KB + kb) * NB * 512;
    for (int p = threadIdx.x; p < NB * 64; p += 256) {
        int nb = p >> 6, lane = p & 63;
        int row0 = kb * 32 + ((lane >> 4) << 3);
        int col = nb * 16 + (lane & 15);
        union { short sh[8]; uint4 v; } hi, mi, lo;
#pragma unroll
        for (int j = 0; j < 8; j++)
            split3(s[(size_t)(row0 + j) * ncols + col], hi.sh[j], mi.sh[j], lo.sh[j]);
        *(uint4*)&dh[dbase + (size_t)p * 8] = hi.v;
        *(uint4*)&dm[dbase + (size_t)p * 8] = mi.v;
        *(uint4*)&dl[dbase + (size_t)p * 8] = lo.v;
    }
}

// ---------------- MFMA router: 32 tokens x 1 group per block, 3-split bf16 layer1 (6 MFMA terms) ----------------
__global__ __launch_bounds__(256) void k_router_mfma(
        const short* __restrict__ AhsH, const short* __restrict__ AhsM, const short* __restrict__ AhsL,
        const short* __restrict__ AgH,  const short* __restrict__ AgM,  const short* __restrict__ AgL,
        const short* __restrict__ BpgH, const short* __restrict__ BpgM, const short* __restrict__ BpgL,
        const short* __restrict__ BirH, const short* __restrict__ BirM, const short* __restrict__ BirL,
        const float* __restrict__ pb1, const float* __restrict__ pw2, const float* __restrict__ pb2,
        const float* __restrict__ ib1, const float* __restrict__ iw2, const float* __restrict__ ib2,
        float* __restrict__ glog, float* __restrict__ ilog, int g0) {
    const int bx = blockIdx.x;      // 32-token tile
    const int gl = blockIdx.y;
    const int g = g0 + gl;
    const int tid = threadIdx.x;
    const int wave = tid >> 6, lane = tid & 63;
    const int quad = lane >> 4, lm = lane & 15;
    const bool is_pg = wave < 2;
    const int nbase = (wave & 1) * 4;          // 4 n-tiles per wave
    const short* Bh = is_pg ? BpgH : (BirH + (size_t)g * 65536);
    const short* Bm = is_pg ? BpgM : (BirM + (size_t)g * 65536);
    const short* Bl = is_pg ? BpgL : (BirL + (size_t)g * 65536);

    f32x4 acc[2][4];
#pragma unroll
    for (int mt = 0; mt < 2; mt++)
#pragma unroll
        for (int nt = 0; nt < 4; nt++) acc[mt][nt] = (f32x4)(0.f);

    for (int kb = 0; kb < 16; kb++) {
        bf16x8 Ahf[2], Amf[2], Alf[2];
#pragma unroll
        for (int mt = 0; mt < 2; mt++) {
            size_t ai;
            const short *ah, *am, *al;
            if (kb < 8) {
                ai = (((size_t)(2 * bx + mt) * 8 + kb) * 64 + lane) * 8;
                ah = AhsH; am = AhsM; al = AhsL;
            } else {
                ai = ((((size_t)(2 * bx + mt) * GP + gl) * 8 + (kb - 8)) * 64 + lane) * 8;
                ah = AgH; am = AgM; al = AgL;
            }
            Ahf[mt] = *(const bf16x8*)&ah[ai];
            Amf[mt] = *(const bf16x8*)&am[ai];
            Alf[mt] = *(const bf16x8*)&al[ai];
        }
#pragma unroll
        for (int nt = 0; nt < 4; nt++) {
            int nb = nbase + nt;
            size_t bi = (((size_t)kb * 8 + nb) * 64 + lane) * 8;
            bf16x8 bh = *(const bf16x8*)&Bh[bi];
            bf16x8 bm = *(const bf16x8*)&Bm[bi];
            bf16x8 bl = *(const bf16x8*)&Bl[bi];
#pragma unroll
            for (int mt = 0; mt < 2; mt++) {
                // smallest terms first; exact 3-split -> residual ~2^-27 relative
                acc[mt][nt] = __builtin_amdgcn_mfma_f32_16x16x32_bf16(Alf[mt], bh, acc[mt][nt], 0, 0, 0);
                acc[mt][nt] = __builtin_amdgcn_mfma_f32_16x16x32_bf16(Amf[mt], bm, acc[mt][nt], 0, 0, 0);
                acc[mt][nt] = __builtin_amdgcn_mfma_f32_16x16x32_bf16(Ahf[mt], bl, acc[mt][nt], 0, 0, 0);
                acc[mt][nt] = __builtin_amdgcn_mfma_f32_16x16x32_bf16(Amf[mt], bh, acc[mt][nt], 0, 0, 0);
                acc[mt][nt] = __builtin_amdgcn_mfma_f32_16x16x32_bf16(Ahf[mt], bm, acc[mt][nt], 0, 0, 0);
                acc[mt][nt] = __builtin_amdgcn_mfma_f32_16x16x32_bf16(Ahf[mt], bh, acc[mt][nt], 0, 0, 0);
            }
        }
    }

    __shared__ float ph[32][129];   // odd stride: conflict-free column reads
    __shared__ float ih[32][129];
    float* dst = is_pg ? &ph[0][0] : &ih[0][0];
#pragma unroll
    for (int mt = 0; mt < 2; mt++)
#pragma unroll
    for (int nt = 0; nt < 4; nt++) {
        int col = (wave & 1) * 64 + nt * 16 + lm;
        float b1 = is_pg ? pb1[col] : ib1[g * DH + col];
#pragma unroll
        for (int r = 0; r < 4; r++) {
            int row = mt * 16 + quad * 4 + r;
            dst[row * 129 + col] = gelu_t(acc[mt][nt][r] + b1);
        }
    }
    __syncthreads();

    int n0 = bx * 32;
    if (tid < 32) {
        float s = pb2[0];
        for (int i = 0; i < DH; i++) s += ph[tid][i] * pw2[i];
        glog[(size_t)(n0 + tid) * G + g] = s; // TEMP = 1.0
    } else if (tid >= 128) {
        int t = (tid - 128) >> 2, e = (tid - 128) & 3;
        float s = ib2[g * ES + e];
        const float* w = iw2 + (size_t)g * DH * ES;
        for (int i = 0; i < DH; i++) s += ih[t * 129 / 129][0] * 0.f + ih[t][i] * w[i * ES + e];
        ilog[((size_t)(n0 + t) * G + g) * ES + e] = s;
    }
}

// ---------------- top-k softmax + dispatch to per-expert lists ----------------
__global__ void k_topk(const float* __restrict__ glog, const float* __restrict__ ilog,
                       int* __restrict__ cnt, int* __restrict__ toks, float* __restrict__ wgts) {
    int n = blockIdx.x * blockDim.x + threadIdx.x;
    if (n >= N_TOK) return;
    float gl[G];
#pragma unroll
    for (int g = 0; g < G; g++) gl[g] = glog[(size_t)n * G + g];
    int i1 = 0; float v1 = gl[0];
#pragma unroll
    for (int g = 1; g < G; g++) if (gl[g] > v1) { v1 = gl[g]; i1 = g; }
    int i2 = -1; float v2 = -1e30f;
#pragma unroll
    for (int g = 0; g < G; g++) if (g != i1 && gl[g] > v2) { v2 = gl[g]; i2 = g; }
    float eg = expf(v2 - v1);
    float den = 1.0f / (1.0f + eg);
    float gw_sel[2] = { den, eg * den };
    int g_sel[2] = { i1, i2 };
#pragma unroll
    for (int s = 0; s < 2; s++) {
        int g = g_sel[s]; float gw = gw_sel[s];
        float il[ES];
#pragma unroll
        for (int e = 0; e < ES; e++) il[e] = ilog[((size_t)n * G + g) * ES + e];
        int j1 = 0; float u1 = il[0];
#pragma unroll
        for (int e = 1; e < ES; e++) if (il[e] > u1) { u1 = il[e]; j1 = e; }
        int j2 = -1; float u2 = -1e30f;
#pragma unroll
        for (int e = 0; e < ES; e++) if (e != j1 && il[e] > u2) { u2 = il[e]; j2 = e; }
        float ei = expf(u2 - u1);
        float d2 = 1.0f / (1.0f + ei);
        int ex1 = g * ES + j1, ex2 = g * ES + j2;
        int p1 = atomicAdd(&cnt[ex1], 1);
        toks[(size_t)ex1 * N_TOK + p1] = n * 4 + s * 2;     wgts[(size_t)ex1 * N_TOK + p1] = gw * d2;
        int p2 = atomicAdd(&cnt[ex2], 1);
        toks[(size_t)ex2 * N_TOK + p2] = n * 4 + s * 2 + 1; wgts[(size_t)ex2 * N_TOK + p2] = gw * ei * d2;
    }
}

// ---------------- weight re-tiling to MFMA B-fragment layout, plain bf16 (experts) ----------------
__global__ void k_conv_w(const float* __restrict__ src, short* __restrict__ dst, int KB, int NB) {
    int e = blockIdx.x / KB, kb = blockIdx.x % KB;
    const float* s = src + (size_t)e * (size_t)(KB * 32) * (NB * 16);
    short* d = dst + (size_t)blockIdx.x * NB * 512;
    int ncols = NB * 16;
    for (int p = threadIdx.x; p < NB * 64; p += 256) {
        int nb = p >> 6, lane = p & 63;
        int row0 = kb * 32 + ((lane >> 4) << 3);
        int col = nb * 16 + (lane & 15);
        union { short sh[8]; uint4 v; } tmp;
#pragma unroll
        for (int j = 0; j < 8; j++) tmp.sh[j] = f2bf(s[(size_t)(row0 + j) * ncols + col]);
        *(uint4*)&d[(size_t)p * 8] = tmp.v;
    }
}

// ---------------- sparse expert MLPs via bf16 MFMA ----------------
__global__ __launch_bounds__(256) void k_expert_mfma(
        const __hip_bfloat16* __restrict__ h_normb,
        const short* __restrict__ wB1, const float* __restrict__ eb1,
        const short* __restrict__ wB2, const float* __restrict__ eb2,
        const int* __restrict__ cnt, const int* __restrict__ toks,
        const float* __restrict__ wgts, float* __restrict__ part) {
    const int e = blockIdx.y;
    const int c = cnt[e];
    const int start = blockIdx.x * BT;
    if (start >= c) return;
    const int m = min(BT, c - start);

    __shared__ short hs[BT][520];
    __shared__ short es[BT][264];
    __shared__ int   tok_s[BT];
    __shared__ float w_s[BT];

    const int tid = threadIdx.x;
    if (tid < BT) {
        bool ok = tid < m;
        tok_s[tid] = ok ? toks[(size_t)e * N_TOK + start + tid] : 0;
        w_s[tid]   = ok ? wgts[(size_t)e * N_TOK + start + tid] : 0.f;
    }
    __syncthreads();
    for (int idx = tid; idx < BT * 64; idx += 256) {
        int t = idx >> 6, ch = idx & 63;
        uint4 v = make_uint4(0, 0, 0, 0);
        if (t < m) v = *((const uint4*)(h_normb + (size_t)(tok_s[t] >> 2) * DM) + ch);
        *(uint4*)&hs[t][ch * 8] = v;
    }
    __syncthreads();

    const int wave = tid >> 6, lane = tid & 63;
    const int quad = lane >> 4, lm = lane & 15;
    const int mt = wave & 1;

    {
        const int ng = (wave >> 1) * 8;
        f32x4 acc[8];
#pragma unroll
        for (int i = 0; i < 8; i++) acc[i] = (f32x4)(0.f);
        const short* w1e = wB1 + (size_t)e * DM * DE;
        for (int kb = 0; kb < 16; kb++) {
            bf16x8 a = *(const bf16x8*)&hs[mt * 16 + lm][kb * 32 + quad * 8];
            const short* wp = w1e + ((size_t)kb * 16 + ng) * 512 + lane * 8;
#pragma unroll
            for (int nt = 0; nt < 8; nt++) {
                bf16x8 b = *(const bf16x8*)(wp + nt * 512);
                acc[nt] = __builtin_amdgcn_mfma_f32_16x16x32_bf16(a, b, acc[nt], 0, 0, 0);
            }
        }
#pragma unroll
        for (int nt = 0; nt < 8; nt++) {
            int col = (ng + nt) * 16 + lm;
            float b1 = eb1[e * DE + col];
#pragma unroll
            for (int r = 0; r < 4; r++) {
                int row = mt * 16 + quad * 4 + r;
                es[row][col] = f2bf(gelu_t(acc[nt][r] + b1));
            }
        }
    }
    __syncthreads();

    {
        const int ng2 = (wave >> 1) * 16;
        f32x4 acc[16];
#pragma unroll
        for (int i = 0; i < 16; i++) acc[i] = (f32x4)(0.f);
        const short* w2e = wB2 + (size_t)e * DE * DM;
        for (int kb = 0; kb < 8; kb++) {
            bf16x8 a = *(const bf16x8*)&es[mt * 16 + lm][kb * 32 + quad * 8];
            const short* wp = w2e + ((size_t)kb * 32 + ng2) * 512 + lane * 8;
#pragma unroll
            for (int nt = 0; nt < 16; nt++) {
                bf16x8 b = *(const bf16x8*)(wp + nt * 512);
                acc[nt] = __builtin_amdgcn_mfma_f32_16x16x32_bf16(a, b, acc[nt], 0, 0, 0);
            }
        }
        const float* b2 = eb2 + (size_t)e * DM;
#pragma unroll
        for (int r = 0; r < 4; r++) {
            int row = mt * 16 + quad * 4 + r;
            if (row < m) {
                float w = w_s[row];
                float* prow = part + (size_t)tok_s[row] * DM;
#pragma unroll
                for (int nt = 0; nt < 16; nt++) {
                    int col = (ng2 + nt) * 16 + lm;
                    prow[col] = w * (acc[nt][r] + b2[col]);
                }
            }
        }
    }
}

// ---------------- final reduce: out[n] = sum_s part[n*4+s] ----------------
__global__ void k_reduce(const float* __restrict__ part, float* __restrict__ out) {
    int n = blockIdx.x;
    int j = threadIdx.x; // 0..127
    const float4* p = (const float4*)(part + (size_t)n * 4 * DM);
    float4 a = p[j], b = p[128 + j], c = p[256 + j], d = p[384 + j];
    float4 r = make_float4(a.x + b.x + c.x + d.x, a.y + b.y + c.y + d.y,
                           a.z + b.z + c.z + d.z, a.w + b.w + c.w + d.w);
    ((float4*)(out + (size_t)n * DM))[j] = r;
}

extern "C" void kernel_launch(void* const* d_in, const int* in_sizes, int n_in,
                              void* d_out, int out_size, void* d_ws, size_t ws_size,
                              hipStream_t stream) {
    const float* hidden  = (const float*)d_in[0];
    const float* feat    = (const float*)d_in[1];
    const float* pre_g   = (const float*)d_in[2];
    const float* pre_b   = (const float*)d_in[3];
    const float* rh_g    = (const float*)d_in[4];
    const float* rh_b    = (const float*)d_in[5];
    const float* rh_w1   = (const float*)d_in[6];
    const float* rh_b1   = (const float*)d_in[7];
    const float* rh_w2   = (const float*)d_in[8];
    const float* rh_b2   = (const float*)d_in[9];
    const float* sf_g    = (const float*)d_in[10];
    const float* sf_b    = (const float*)d_in[11];
    const float* sf_w1   = (const float*)d_in[12];
    const float* sf_b1   = (const float*)d_in[13];
    const float* sf_w2   = (const float*)d_in[14];
    const float* sf_b2   = (const float*)d_in[15];
    const float* gln_g   = (const float*)d_in[16];
    const float* gln_b   = (const float*)d_in[17];
    const float* gf_w1   = (const float*)d_in[18];
    const float* gf_b1   = (const float*)d_in[19];
    const float* gf_w2   = (const float*)d_in[20];
    const float* gf_b2   = (const float*)d_in[21];
    const float* pgs_w1  = (const float*)d_in[22];
    const float* pgs_b1  = (const float*)d_in[23];
    const float* pgs_w2  = (const float*)d_in[24];
    const float* pgs_b2  = (const float*)d_in[25];
    const float* ir_w1   = (const float*)d_in[26];
    const float* ir_b1   = (const float*)d_in[27];
    const float* ir_w2   = (const float*)d_in[28];
    const float* ir_b2   = (const float*)d_in[29];
    const float* ex_w1   = (const float*)d_in[30];
    const float* ex_b1   = (const float*)d_in[31];
    const float* ex_w2   = (const float*)d_in[32];
    const float* ex_b2   = (const float*)d_in[33];
    float* out = (float*)d_out;

    // workspace carving (256B-aligned); total ~89 MB
    char* w = (char*)d_ws;
    auto alloc = [&](size_t bytes) { void* r = (void*)w; w += (bytes + 255) & ~(size_t)255; return r; };
    __hip_bfloat16* h_normb = (__hip_bfloat16*)alloc((size_t)N_TOK * DM * 2);
    float* sL    = (float*)alloc((size_t)N_TOK * FDIM * 4);
    float* h_enc = (float*)alloc((size_t)N_TOK * DH * 4);
    float* s_enc = (float*)alloc((size_t)N_TOK * DH * 4);
    float* g_enc = (float*)alloc((size_t)N_TOK * G * DH * 4);
    float* glog  = (float*)alloc((size_t)N_TOK * G * 4);
    float* ilog  = (float*)alloc((size_t)N_TOK * G * ES * 4);
    float* wgts  = (float*)alloc((size_t)E_EXP * N_TOK * 4);
    short* wB1   = (short*)alloc((size_t)E_EXP * DM * DE * 2);
    short* wB2   = (short*)alloc((size_t)E_EXP * DE * DM * 2);
    short* AhsH  = (short*)alloc((size_t)N_TOK * 256 * 2);
    short* AhsM  = (short*)alloc((size_t)N_TOK * 256 * 2);
    short* AhsL  = (short*)alloc((size_t)N_TOK * 256 * 2);
    short* BpgH  = (short*)alloc((size_t)16 * 8 * 512 * 2);
    short* BpgM  = (short*)alloc((size_t)16 * 8 * 512 * 2);
    short* BpgL  = (short*)alloc((size_t)16 * 8 * 512 * 2);
    short* BirH  = (short*)alloc((size_t)G * 16 * 8 * 512 * 2);
    short* BirM  = (short*)alloc((size_t)G * 16 * 8 * 512 * 2);
    short* BirL  = (short*)alloc((size_t)G * 16 * 8 * 512 * 2);
    int* cnt     = (int*)alloc(E_EXP * 4);
    int* toks    = (int*)alloc((size_t)E_EXP * N_TOK * 4);
    // union region (disjoint live ranges, stream-ordered):
    //   hL   [k_ln_hidden -> k_mlp2<512>]          8.4 MB
    //   Ag3  [k_stage_g(p) -> k_router_mfma(p)]   25.2 MB per pass
    //   part [k_expert_mfma -> k_reduce]          33.6 MB
    size_t agsz = (size_t)N_TOK * GP * 256 * 2;   // 8.39 MB per split
    char* uni   = (char*)alloc((size_t)N_TOK * 4 * DM * 4); // 33.6 MB = max
    float* hL   = (float*)uni;
    short* AgH  = (short*)uni;
    short* AgM  = (short*)(uni + agsz);
    short* AgL  = (short*)(uni + 2 * agsz);
    float* part = (float*)uni;

    hipMemsetAsync(cnt, 0, E_EXP * sizeof(int), stream);

    // weight conversions (independent of token pipeline)
    k_conv_w<<<E_EXP * 16, 256, 0, stream>>>(ex_w1, wB1, 16, 16);
    k_conv_w<<<E_EXP * 8, 256, 0, stream>>>(ex_w2, wB2, 8, 32);
    k_conv_b3<<<16, 256, 0, stream>>>(pgs_w1, BpgH, BpgM, BpgL, 16, 8);
    k_conv_b3<<<G * 16, 256, 0, stream>>>(ir_w1, BirH, BirM, BirL, 16, 8);

    k_ln_hidden<<<N_TOK, 256, 0, stream>>>(hidden, pre_g, pre_b, rh_g, rh_b, h_normb, hL);
    k_ln_feat<<<N_TOK, 128, 0, stream>>>(feat, sf_g, sf_b, sL);
    k_mlp2<512><<<N_TOK / 4, 128, 0, stream>>>(hL, rh_w1, rh_b1, rh_w2, rh_b2, h_enc);
    k_mlp2<128><<<N_TOK / 4, 128, 0, stream>>>(sL, sf_w1, sf_b1, sf_w2, sf_b2, s_enc);
    k_group_enc<<<N_TOK / 2, 128, 0, stream>>>(feat, gln_g, gln_b, gf_w1, gf_b1, gf_w2, gf_b2, g_enc);

    k_stage_hs<<<N_TOK / 16, 256, 0, stream>>>(h_enc, s_enc, AhsH, AhsM, AhsL);

    // router in two passes of GP=4 groups (bounds Ag workspace)
    for (int g0 = 0; g0 < G; g0 += GP) {
        dim3 sgrid(N_TOK / 16, GP);
        k_stage_g<<<sgrid, 256, 0, stream>>>(h_enc, g_enc, AgH, AgM, AgL, g0);
        dim3 rgrid(N_TOK / 32, GP);
        k_router_mfma<<<rgrid, 256, 0, stream>>>(AhsH, AhsM, AhsL, AgH, AgM, AgL,
                                                 BpgH, BpgM, BpgL, BirH, BirM, BirL,
                                                 pgs_b1, pgs_w2, pgs_b2, ir_b1, ir_w2, ir_b2,
                                                 glog, ilog, g0);
    }

    k_topk<<<N_TOK / 256, 256, 0, stream>>>(glog, ilog, cnt, toks, wgts);
    dim3 egrid(N_TOK / BT, E_EXP);
    k_expert_mfma<<<egrid, 256, 0, stream>>>(h_normb, wB1, ex_b1, wB2, ex_b2, cnt, toks, wgts, part);
    k_reduce<<<N_TOK, 128, 0, stream>>>(part, out);
}

// Round 5
// 479.284 us; speedup vs baseline: 2.3112x; 1.0358x over previous
//
#include <hip/hip_runtime.h>
#include <hip/hip_bf16.h>
#include <math.h>

#define N_TOK 4096
#define DM 512
#define FDIM 128
#define G 8
#define FG 16
#define DH 128
#define DE 256
#define ES 4
#define E_EXP 32
#define LN_EPS 1e-5f
#define BT 32   // expert token tile (MFMA)
#define GP 4    // groups per router pass (memory cap)

typedef __attribute__((ext_vector_type(8))) short bf16x8;  // 8 bf16 = 4 VGPRs
typedef __attribute__((ext_vector_type(4))) float f32x4;

#define MFMA16(a, b, c) __builtin_amdgcn_mfma_f32_16x16x32_bf16((a), (b), (c), 0, 0, 0)

__device__ __forceinline__ float gelu_t(float x) {
    const float c = 0.7978845608028654f; // sqrt(2/pi)
    float x3 = x * x * x;
    return 0.5f * x * (1.0f + tanhf(c * (x + 0.044715f * x3)));
}

__device__ __forceinline__ short f2bf(float f) {
    __hip_bfloat16 h = __float2bfloat16(f);
    return *reinterpret_cast<short*>(&h);
}
__device__ __forceinline__ float bf2f(short s) {
    __hip_bfloat16 h = *reinterpret_cast<__hip_bfloat16*>(&s);
    return __bfloat162float(h);
}
// exact 3-way split: x == bf2f(h)+bf2f(m)+bf2f(l) bit-exactly for fp32 x
__device__ __forceinline__ void split3(float x, short& h, short& m, short& l) {
    h = f2bf(x);
    float r = x - bf2f(h);   // exact in fp32
    m = f2bf(r);
    float r2 = r - bf2f(m);  // exact; <=6 significant bits remain
    l = f2bf(r2);            // exact
}

// ---------------- LN of hidden: pre_ln -> h_norm (bf16) and rh_ln -> hL (fp32) ----------------
__global__ void k_ln_hidden(const float* __restrict__ hidden,
                            const float* __restrict__ pg, const float* __restrict__ pb,
                            const float* __restrict__ rg, const float* __restrict__ rb,
                            __hip_bfloat16* __restrict__ h_normb, float* __restrict__ hL) {
    int n = blockIdx.x;
    int j = threadIdx.x; // 0..255
    const float* x = hidden + (size_t)n * DM;
    float v0 = x[j], v1 = x[j + 256];
    float s = v0 + v1, q = v0 * v0 + v1 * v1;
#pragma unroll
    for (int o = 32; o; o >>= 1) { s += __shfl_down(s, o); q += __shfl_down(q, o); }
    __shared__ float red[8];
    int w = j >> 6;
    if ((j & 63) == 0) { red[w] = s; red[4 + w] = q; }
    __syncthreads();
    float sum = red[0] + red[1] + red[2] + red[3];
    float sq  = red[4] + red[5] + red[6] + red[7];
    float m = sum * (1.0f / DM);
    float var = sq * (1.0f / DM) - m * m;
    float rs = rsqrtf(var + LN_EPS);
    float t0 = (v0 - m) * rs, t1 = (v1 - m) * rs;
    size_t base = (size_t)n * DM;
    h_normb[base + j]       = __float2bfloat16(t0 * pg[j]       + pb[j]);
    h_normb[base + j + 256] = __float2bfloat16(t1 * pg[j + 256] + pb[j + 256]);
    hL[base + j]           = t0 * rg[j]       + rb[j];
    hL[base + j + 256]     = t1 * rg[j + 256] + rb[j + 256];
}

// ---------------- LN of feat (sf_ln) -> sL ----------------
__global__ void k_ln_feat(const float* __restrict__ feat,
                          const float* __restrict__ g, const float* __restrict__ b,
                          float* __restrict__ sL) {
    int n = blockIdx.x;
    int j = threadIdx.x; // 0..127
    float v = feat[(size_t)n * FDIM + j];
    float s = v, q = v * v;
#pragma unroll
    for (int o = 32; o; o >>= 1) { s += __shfl_down(s, o); q += __shfl_down(q, o); }
    __shared__ float red[4];
    int w = j >> 6;
    if ((j & 63) == 0) { red[w] = s; red[2 + w] = q; }
    __syncthreads();
    float sum = red[0] + red[1], sq = red[2] + red[3];
    float m = sum * (1.0f / FDIM);
    float var = sq * (1.0f / FDIM) - m * m;
    float rs = rsqrtf(var + LN_EPS);
    sL[(size_t)n * FDIM + j] = (v - m) * rs * g[j] + b[j];
}

// ---------------- weight conversion to B-frag layout, 3-way split, with K zero-pad ----------------
// per matrix [Kreal, NB*16] (row-major); dst mat stride = KB*NB*512
__global__ void k_conv_b3(const float* __restrict__ src, short* __restrict__ dh,
                          short* __restrict__ dm, short* __restrict__ dl,
                          int KB, int NB, int Kreal) {
    int mat = blockIdx.x / KB, kb = blockIdx.x % KB;
    int ncols = NB * 16;
    const float* s = src + (size_t)mat * Kreal * ncols;
    size_t dbase = ((size_t)mat * KB + kb) * NB * 512;
    for (int p = threadIdx.x; p < NB * 64; p += 256) {
        int nb = p >> 6, lane = p & 63;
        int row0 = kb * 32 + ((lane >> 4) << 3);
        int col = nb * 16 + (lane & 15);
        union { short sh[8]; uint4 v; } hi, mi, lo;
#pragma unroll
        for (int j = 0; j < 8; j++) {
            float x = (row0 + j < Kreal) ? s[(size_t)(row0 + j) * ncols + col] : 0.f;
            split3(x, hi.sh[j], mi.sh[j], lo.sh[j]);
        }
        *(uint4*)&dh[dbase + (size_t)p * 8] = hi.v;
        *(uint4*)&dm[dbase + (size_t)p * 8] = mi.v;
        *(uint4*)&dl[dbase + (size_t)p * 8] = lo.v;
    }
}

// ---------------- 2-layer MLP via 3-split MFMA: Y = gelu(X@W1+b1)@W2+b2 ----------------
// X [N, K=KB_TOT*32] fp32, W1 pre-split [KB_TOT,8 ntiles], W2 pre-split [4,8], Y [N,128] fp32
template <int KB_TOT>
__global__ __launch_bounds__(256) void k_enc2_mfma(
        const float* __restrict__ X,
        const short* __restrict__ W1h, const short* __restrict__ W1m, const short* __restrict__ W1l,
        const float* __restrict__ B1,
        const short* __restrict__ W2h, const short* __restrict__ W2m, const short* __restrict__ W2l,
        const float* __restrict__ B2,
        float* __restrict__ Y) {
    constexpr int K = KB_TOT * 32;
    constexpr int NCHUNK = KB_TOT / 4;
    const int n0 = blockIdx.x * 32;
    const int tid = threadIdx.x;
    const int wave = tid >> 6, lane = tid & 63;
    const int quad = lane >> 4, lm = lane & 15;
    const int mt = wave & 1;
    const int ngb = (wave >> 1) * 4;   // 4 n-tiles per wave

    __shared__ short Ah[32][132], Am[32][132], Al[32][132];

    f32x4 acc[4];
#pragma unroll
    for (int i = 0; i < 4; i++) acc[i] = (f32x4)(0.f);

    for (int ch = 0; ch < NCHUNK; ch++) {
        __syncthreads();   // protect previous chunk's reads
        for (int idx = tid; idx < 1024; idx += 256) {
            int row = idx >> 5, c4 = (idx & 31) * 4;
            float4 v = *(const float4*)&X[(size_t)(n0 + row) * K + ch * 128 + c4];
            float xv[4] = {v.x, v.y, v.z, v.w};
#pragma unroll
            for (int j = 0; j < 4; j++) {
                short h, m, l; split3(xv[j], h, m, l);
                Ah[row][c4 + j] = h; Am[row][c4 + j] = m; Al[row][c4 + j] = l;
            }
        }
        __syncthreads();
#pragma unroll
        for (int kb = 0; kb < 4; kb++) {
            int kbg = ch * 4 + kb;
            bf16x8 ah = *(const bf16x8*)&Ah[mt * 16 + lm][kb * 32 + quad * 8];
            bf16x8 am = *(const bf16x8*)&Am[mt * 16 + lm][kb * 32 + quad * 8];
            bf16x8 al = *(const bf16x8*)&Al[mt * 16 + lm][kb * 32 + quad * 8];
#pragma unroll
            for (int nt = 0; nt < 4; nt++) {
                size_t bi = (((size_t)kbg * 8 + ngb + nt) * 64 + lane) * 8;
                bf16x8 bh = *(const bf16x8*)&W1h[bi];
                bf16x8 bm = *(const bf16x8*)&W1m[bi];
                bf16x8 bl = *(const bf16x8*)&W1l[bi];
                acc[nt] = MFMA16(al, bh, acc[nt]);
                acc[nt] = MFMA16(am, bm, acc[nt]);
                acc[nt] = MFMA16(ah, bl, acc[nt]);
                acc[nt] = MFMA16(am, bh, acc[nt]);
                acc[nt] = MFMA16(ah, bm, acc[nt]);
                acc[nt] = MFMA16(ah, bh, acc[nt]);
            }
        }
    }
    __syncthreads();
    // layer-1 epilogue: +b1, gelu, split -> A2 frags (reuse Ah/Am/Al)
#pragma unroll
    for (int nt = 0; nt < 4; nt++) {
        int col = (ngb + nt) * 16 + lm;
        float b1 = B1[col];
#pragma unroll
        for (int r = 0; r < 4; r++) {
            int row = mt * 16 + quad * 4 + r;
            short h, m, l; split3(gelu_t(acc[nt][r] + b1), h, m, l);
            Ah[row][col] = h; Am[row][col] = m; Al[row][col] = l;
        }
    }
    __syncthreads();
    f32x4 acc2[4];
#pragma unroll
    for (int i = 0; i < 4; i++) acc2[i] = (f32x4)(0.f);
#pragma unroll
    for (int kb = 0; kb < 4; kb++) {
        bf16x8 ah = *(const bf16x8*)&Ah[mt * 16 + lm][kb * 32 + quad * 8];
        bf16x8 am = *(const bf16x8*)&Am[mt * 16 + lm][kb * 32 + quad * 8];
        bf16x8 al = *(const bf16x8*)&Al[mt * 16 + lm][kb * 32 + quad * 8];
#pragma unroll
        for (int nt = 0; nt < 4; nt++) {
            size_t bi = (((size_t)kb * 8 + ngb + nt) * 64 + lane) * 8;
            bf16x8 bh = *(const bf16x8*)&W2h[bi];
            bf16x8 bm = *(const bf16x8*)&W2m[bi];
            bf16x8 bl = *(const bf16x8*)&W2l[bi];
            acc2[nt] = MFMA16(al, bh, acc2[nt]);
            acc2[nt] = MFMA16(am, bm, acc2[nt]);
            acc2[nt] = MFMA16(ah, bl, acc2[nt]);
            acc2[nt] = MFMA16(am, bh, acc2[nt]);
            acc2[nt] = MFMA16(ah, bm, acc2[nt]);
            acc2[nt] = MFMA16(ah, bh, acc2[nt]);
        }
    }
#pragma unroll
    for (int nt = 0; nt < 4; nt++) {
        int col = (ngb + nt) * 16 + lm;
        float b2 = B2[col];
#pragma unroll
        for (int r = 0; r < 4; r++) {
            int row = mt * 16 + quad * 4 + r;
            Y[(size_t)(n0 + row) * DH + col] = acc2[nt][r] + b2;
        }
    }
}

// ---------------- group encoders via 3-split MFMA: LN(16) -> 16->128 (K pad 32) -> gelu -> 128->128 ----------------
__global__ __launch_bounds__(256) void k_genc_mfma(
        const float* __restrict__ feat,
        const float* __restrict__ gln_g, const float* __restrict__ gln_b,
        const short* __restrict__ W1h, const short* __restrict__ W1m, const short* __restrict__ W1l,
        const float* __restrict__ gb1,
        const short* __restrict__ W2h, const short* __restrict__ W2m, const short* __restrict__ W2l,
        const float* __restrict__ gb2,
        float* __restrict__ g_enc) {
    const int n0 = blockIdx.x * 32;
    const int tid = threadIdx.x;
    const int wave = tid >> 6, lane = tid & 63;
    const int quad = lane >> 4, lm = lane & 15;
    const int mt = wave & 1;
    const int ngb = (wave >> 1) * 4;

    __shared__ short A1h[32][132], A1m[32][132], A1l[32][132];
    __shared__ short A2h[32][132], A2m[32][132], A2l[32][132];

    for (int half = 0; half < 2; half++) {
        __syncthreads();   // protect previous half's A1 reads
        {
            // LN + split stage: thread -> (token t, group gl, elem-half eo)
            int t = tid >> 3, sub = tid & 7, gl = sub >> 1, eo = sub & 1;
            int g = half * 4 + gl;
            const float* fr = feat + (size_t)(n0 + t) * FDIM + g * FG;
            float xv[FG];
            float mean = 0.f;
#pragma unroll
            for (int i = 0; i < FG; i++) { xv[i] = fr[i]; mean += xv[i]; }
            mean *= (1.0f / FG);
            float var = 0.f;
#pragma unroll
            for (int i = 0; i < FG; i++) { float d = xv[i] - mean; var += d * d; }
            var *= (1.0f / FG);
            float rs = rsqrtf(var + LN_EPS);
            for (int i = eo * 8; i < eo * 8 + 8; i++) {
                float xn = (xv[i] - mean) * rs * gln_g[g * FG + i] + gln_b[g * FG + i];
                short h, m, l; split3(xn, h, m, l);
                A1h[t][gl * 32 + i] = h; A1m[t][gl * 32 + i] = m; A1l[t][gl * 32 + i] = l;
                A1h[t][gl * 32 + 16 + i] = 0; A1m[t][gl * 32 + 16 + i] = 0; A1l[t][gl * 32 + 16 + i] = 0;
            }
        }
        __syncthreads();
        for (int gl = 0; gl < 4; gl++) {
            int g = half * 4 + gl;
            // layer-1: K=32 (padded), one kb at kloc=gl
            bf16x8 ah = *(const bf16x8*)&A1h[mt * 16 + lm][gl * 32 + quad * 8];
            bf16x8 am = *(const bf16x8*)&A1m[mt * 16 + lm][gl * 32 + quad * 8];
            bf16x8 al = *(const bf16x8*)&A1l[mt * 16 + lm][gl * 32 + quad * 8];
            f32x4 acc[4];
#pragma unroll
            for (int i = 0; i < 4; i++) acc[i] = (f32x4)(0.f);
#pragma unroll
            for (int nt = 0; nt < 4; nt++) {
                size_t bi = (((size_t)g * 8 + ngb + nt) * 64 + lane) * 8;  // KB=1 per mat
                bf16x8 bh = *(const bf16x8*)&W1h[bi];
                bf16x8 bm = *(const bf16x8*)&W1m[bi];
                bf16x8 bl = *(const bf16x8*)&W1l[bi];
                acc[nt] = MFMA16(al, bh, acc[nt]);
                acc[nt] = MFMA16(am, bm, acc[nt]);
                acc[nt] = MFMA16(ah, bl, acc[nt]);
                acc[nt] = MFMA16(am, bh, acc[nt]);
                acc[nt] = MFMA16(ah, bm, acc[nt]);
                acc[nt] = MFMA16(ah, bh, acc[nt]);
            }
            __syncthreads();   // protect previous group's A2 reads
#pragma unroll
            for (int nt = 0; nt < 4; nt++) {
                int col = (ngb + nt) * 16 + lm;
                float b1 = gb1[g * DH + col];
#pragma unroll
                for (int r = 0; r < 4; r++) {
                    int row = mt * 16 + quad * 4 + r;
                    short h, m, l; split3(gelu_t(acc[nt][r] + b1), h, m, l);
                    A2h[row][col] = h; A2m[row][col] = m; A2l[row][col] = l;
                }
            }
            __syncthreads();
            // layer-2: K=128, 4 kb, per-mat W2 (KB=4)
            f32x4 acc2[4];
#pragma unroll
            for (int i = 0; i < 4; i++) acc2[i] = (f32x4)(0.f);
#pragma unroll
            for (int kb = 0; kb < 4; kb++) {
                bf16x8 a2h = *(const bf16x8*)&A2h[mt * 16 + lm][kb * 32 + quad * 8];
                bf16x8 a2m = *(const bf16x8*)&A2m[mt * 16 + lm][kb * 32 + quad * 8];
                bf16x8 a2l = *(const bf16x8*)&A2l[mt * 16 + lm][kb * 32 + quad * 8];
#pragma unroll
                for (int nt = 0; nt < 4; nt++) {
                    size_t bi = ((((size_t)g * 4 + kb) * 8 + ngb + nt) * 64 + lane) * 8;
                    bf16x8 bh = *(const bf16x8*)&W2h[bi];
                    bf16x8 bm = *(const bf16x8*)&W2m[bi];
                    bf16x8 bl = *(const bf16x8*)&W2l[bi];
                    acc2[nt] = MFMA16(a2l, bh, acc2[nt]);
                    acc2[nt] = MFMA16(a2m, bm, acc2[nt]);
                    acc2[nt] = MFMA16(a2h, bl, acc2[nt]);
                    acc2[nt] = MFMA16(a2m, bh, acc2[nt]);
                    acc2[nt] = MFMA16(a2h, bm, acc2[nt]);
                    acc2[nt] = MFMA16(a2h, bh, acc2[nt]);
                }
            }
#pragma unroll
            for (int nt = 0; nt < 4; nt++) {
                int col = (ngb + nt) * 16 + lm;
                float b2 = gb2[g * DH + col];
#pragma unroll
                for (int r = 0; r < 4; r++) {
                    int row = mt * 16 + quad * 4 + r;
                    g_enc[((size_t)(n0 + row) * G + g) * DH + col] = acc2[nt][r] + b2;
                }
            }
        }
    }
}

// ---------------- stage A-fragments (3-way split bf16) for router layer-1 ----------------
__global__ void k_stage_hs(const float* __restrict__ h_enc, const float* __restrict__ s_enc,
                           short* __restrict__ Ah, short* __restrict__ Am, short* __restrict__ Al) {
    int T16 = blockIdx.x;
    for (int slot = threadIdx.x; slot < 512; slot += 256) {
        int kb = slot >> 6, lane = slot & 63;
        int quad = lane >> 4, lm = lane & 15;
        int n = T16 * 16 + lm;
        int c0 = kb * 32 + quad * 8; // 0..255
        const float* src = (c0 < 128) ? (h_enc + (size_t)n * DH + c0)
                                      : (s_enc + (size_t)n * DH + (c0 - 128));
        float4 x0 = *(const float4*)src;
        float4 x1 = *(const float4*)(src + 4);
        float xv[8] = {x0.x, x0.y, x0.z, x0.w, x1.x, x1.y, x1.z, x1.w};
        union { short sh[8]; uint4 v; } hi, mi, lo;
#pragma unroll
        for (int j = 0; j < 8; j++) split3(xv[j], hi.sh[j], mi.sh[j], lo.sh[j]);
        size_t base = ((size_t)T16 * 512 + slot) * 8;
        *(uint4*)&Ah[base] = hi.v;
        *(uint4*)&Am[base] = mi.v;
        *(uint4*)&Al[base] = lo.v;
    }
}

__global__ void k_stage_g(const float* __restrict__ h_enc, const float* __restrict__ g_enc,
                          short* __restrict__ Ah, short* __restrict__ Am, short* __restrict__ Al,
                          int g0) {
    int T16 = blockIdx.x, gl = blockIdx.y;
    int g = g0 + gl;
    for (int slot = threadIdx.x; slot < 512; slot += 256) {
        int kb = slot >> 6, lane = slot & 63;
        int quad = lane >> 4, lm = lane & 15;
        int n = T16 * 16 + lm;
        int c0 = kb * 32 + quad * 8; // 0..255
        float xv[8];
        if (c0 < 128) {
            const float* gs = g_enc + ((size_t)n * G + g) * DH + c0;
            float4 x0 = *(const float4*)gs, x1 = *(const float4*)(gs + 4);
            xv[0]=x0.x; xv[1]=x0.y; xv[2]=x0.z; xv[3]=x0.w;
            xv[4]=x1.x; xv[5]=x1.y; xv[6]=x1.z; xv[7]=x1.w;
        } else {
            int c = c0 - 128;
            const float* gs = g_enc + ((size_t)n * G + g) * DH + c;
            const float* hs = h_enc + (size_t)n * DH + c;
            float4 g0v = *(const float4*)gs, g1v = *(const float4*)(gs + 4);
            float4 h0v = *(const float4*)hs, h1v = *(const float4*)(hs + 4);
            xv[0]=h0v.x*g0v.x; xv[1]=h0v.y*g0v.y; xv[2]=h0v.z*g0v.z; xv[3]=h0v.w*g0v.w;
            xv[4]=h1v.x*g1v.x; xv[5]=h1v.y*g1v.y; xv[6]=h1v.z*g1v.z; xv[7]=h1v.w*g1v.w;
        }
        union { short sh[8]; uint4 v; } hi, mi, lo;
#pragma unroll
        for (int j = 0; j < 8; j++) split3(xv[j], hi.sh[j], mi.sh[j], lo.sh[j]);
        size_t base = (((size_t)T16 * GP + gl) * 512 + slot) * 8;
        *(uint4*)&Ah[base] = hi.v;
        *(uint4*)&Am[base] = mi.v;
        *(uint4*)&Al[base] = lo.v;
    }
}

// ---------------- MFMA router: 32 tokens x 1 group per block, 3-split bf16 layer1 (6 MFMA terms) ----------------
__global__ __launch_bounds__(256) void k_router_mfma(
        const short* __restrict__ AhsH, const short* __restrict__ AhsM, const short* __restrict__ AhsL,
        const short* __restrict__ AgH,  const short* __restrict__ AgM,  const short* __restrict__ AgL,
        const short* __restrict__ BpgH, const short* __restrict__ BpgM, const short* __restrict__ BpgL,
        const short* __restrict__ BirH, const short* __restrict__ BirM, const short* __restrict__ BirL,
        const float* __restrict__ pb1, const float* __restrict__ pw2, const float* __restrict__ pb2,
        const float* __restrict__ ib1, const float* __restrict__ iw2, const float* __restrict__ ib2,
        float* __restrict__ glog, float* __restrict__ ilog, int g0) {
    const int bx = blockIdx.x;      // 32-token tile
    const int gl = blockIdx.y;
    const int g = g0 + gl;
    const int tid = threadIdx.x;
    const int wave = tid >> 6, lane = tid & 63;
    const int quad = lane >> 4, lm = lane & 15;
    const bool is_pg = wave < 2;
    const int nbase = (wave & 1) * 4;          // 4 n-tiles per wave
    const short* Bh = is_pg ? BpgH : (BirH + (size_t)g * 65536);
    const short* Bm = is_pg ? BpgM : (BirM + (size_t)g * 65536);
    const short* Bl = is_pg ? BpgL : (BirL + (size_t)g * 65536);

    f32x4 acc[2][4];
#pragma unroll
    for (int mt = 0; mt < 2; mt++)
#pragma unroll
        for (int nt = 0; nt < 4; nt++) acc[mt][nt] = (f32x4)(0.f);

    for (int kb = 0; kb < 16; kb++) {
        bf16x8 Ahf[2], Amf[2], Alf[2];
#pragma unroll
        for (int mt = 0; mt < 2; mt++) {
            size_t ai;
            const short *ah, *am, *al;
            if (kb < 8) {
                ai = (((size_t)(2 * bx + mt) * 8 + kb) * 64 + lane) * 8;
                ah = AhsH; am = AhsM; al = AhsL;
            } else {
                ai = ((((size_t)(2 * bx + mt) * GP + gl) * 8 + (kb - 8)) * 64 + lane) * 8;
                ah = AgH; am = AgM; al = AgL;
            }
            Ahf[mt] = *(const bf16x8*)&ah[ai];
            Amf[mt] = *(const bf16x8*)&am[ai];
            Alf[mt] = *(const bf16x8*)&al[ai];
        }
#pragma unroll
        for (int nt = 0; nt < 4; nt++) {
            int nb = nbase + nt;
            size_t bi = (((size_t)kb * 8 + nb) * 64 + lane) * 8;
            bf16x8 bh = *(const bf16x8*)&Bh[bi];
            bf16x8 bm = *(const bf16x8*)&Bm[bi];
            bf16x8 bl = *(const bf16x8*)&Bl[bi];
#pragma unroll
            for (int mt = 0; mt < 2; mt++) {
                acc[mt][nt] = MFMA16(Alf[mt], bh, acc[mt][nt]);
                acc[mt][nt] = MFMA16(Amf[mt], bm, acc[mt][nt]);
                acc[mt][nt] = MFMA16(Ahf[mt], bl, acc[mt][nt]);
                acc[mt][nt] = MFMA16(Amf[mt], bh, acc[mt][nt]);
                acc[mt][nt] = MFMA16(Ahf[mt], bm, acc[mt][nt]);
                acc[mt][nt] = MFMA16(Ahf[mt], bh, acc[mt][nt]);
            }
        }
    }

    __shared__ float ph[32][129];   // odd stride: conflict-free column reads
    __shared__ float ih[32][129];
    float* dst = is_pg ? &ph[0][0] : &ih[0][0];
#pragma unroll
    for (int mt = 0; mt < 2; mt++)
#pragma unroll
    for (int nt = 0; nt < 4; nt++) {
        int col = (wave & 1) * 64 + nt * 16 + lm;
        float b1 = is_pg ? pb1[col] : ib1[g * DH + col];
#pragma unroll
        for (int r = 0; r < 4; r++) {
            int row = mt * 16 + quad * 4 + r;
            dst[row * 129 + col] = gelu_t(acc[mt][nt][r] + b1);
        }
    }
    __syncthreads();

    int n0 = bx * 32;
    if (tid < 32) {
        float s = pb2[0];
        for (int i = 0; i < DH; i++) s += ph[tid][i] * pw2[i];
        glog[(size_t)(n0 + tid) * G + g] = s; // TEMP = 1.0
    } else if (tid >= 128) {
        int t = (tid - 128) >> 2, e = (tid - 128) & 3;
        float s = ib2[g * ES + e];
        const float* w = iw2 + (size_t)g * DH * ES;
        for (int i = 0; i < DH; i++) s += ih[t][i] * w[i * ES + e];
        ilog[((size_t)(n0 + t) * G + g) * ES + e] = s;
    }
}

// ---------------- top-k softmax + dispatch to per-expert lists ----------------
__global__ void k_topk(const float* __restrict__ glog, const float* __restrict__ ilog,
                       int* __restrict__ cnt, int* __restrict__ toks, float* __restrict__ wgts) {
    int n = blockIdx.x * blockDim.x + threadIdx.x;
    if (n >= N_TOK) return;
    float gl[G];
#pragma unroll
    for (int g = 0; g < G; g++) gl[g] = glog[(size_t)n * G + g];
    int i1 = 0; float v1 = gl[0];
#pragma unroll
    for (int g = 1; g < G; g++) if (gl[g] > v1) { v1 = gl[g]; i1 = g; }
    int i2 = -1; float v2 = -1e30f;
#pragma unroll
    for (int g = 0; g < G; g++) if (g != i1 && gl[g] > v2) { v2 = gl[g]; i2 = g; }
    float eg = expf(v2 - v1);
    float den = 1.0f / (1.0f + eg);
    float gw_sel[2] = { den, eg * den };
    int g_sel[2] = { i1, i2 };
#pragma unroll
    for (int s = 0; s < 2; s++) {
        int g = g_sel[s]; float gw = gw_sel[s];
        float il[ES];
#pragma unroll
        for (int e = 0; e < ES; e++) il[e] = ilog[((size_t)n * G + g) * ES + e];
        int j1 = 0; float u1 = il[0];
#pragma unroll
        for (int e = 1; e < ES; e++) if (il[e] > u1) { u1 = il[e]; j1 = e; }
        int j2 = -1; float u2 = -1e30f;
#pragma unroll
        for (int e = 0; e < ES; e++) if (e != j1 && il[e] > u2) { u2 = il[e]; j2 = e; }
        float ei = expf(u2 - u1);
        float d2 = 1.0f / (1.0f + ei);
        int ex1 = g * ES + j1, ex2 = g * ES + j2;
        int p1 = atomicAdd(&cnt[ex1], 1);
        toks[(size_t)ex1 * N_TOK + p1] = n * 4 + s * 2;     wgts[(size_t)ex1 * N_TOK + p1] = gw * d2;
        int p2 = atomicAdd(&cnt[ex2], 1);
        toks[(size_t)ex2 * N_TOK + p2] = n * 4 + s * 2 + 1; wgts[(size_t)ex2 * N_TOK + p2] = gw * ei * d2;
    }
}

// ---------------- weight re-tiling to MFMA B-fragment layout, plain bf16 (experts) ----------------
__global__ void k_conv_w(const float* __restrict__ src, short* __restrict__ dst, int KB, int NB) {
    int e = blockIdx.x / KB, kb = blockIdx.x % KB;
    const float* s = src + (size_t)e * (size_t)(KB * 32) * (NB * 16);
    short* d = dst + (size_t)blockIdx.x * NB * 512;
    int ncols = NB * 16;
    for (int p = threadIdx.x; p < NB * 64; p += 256) {
        int nb = p >> 6, lane = p & 63;
        int row0 = kb * 32 + ((lane >> 4) << 3);
        int col = nb * 16 + (lane & 15);
        union { short sh[8]; uint4 v; } tmp;
#pragma unroll
        for (int j = 0; j < 8; j++) tmp.sh[j] = f2bf(s[(size_t)(row0 + j) * ncols + col]);
        *(uint4*)&d[(size_t)p * 8] = tmp.v;
    }
}

// ---------------- sparse expert MLPs via bf16 MFMA, 8 waves/block for latency hiding ----------------
__global__ __launch_bounds__(512) void k_expert_mfma(
        const __hip_bfloat16* __restrict__ h_normb,
        const short* __restrict__ wB1, const float* __restrict__ eb1,
        const short* __restrict__ wB2, const float* __restrict__ eb2,
        const int* __restrict__ cnt, const int* __restrict__ toks,
        const float* __restrict__ wgts, float* __restrict__ part) {
    const int e = blockIdx.y;
    const int c = cnt[e];
    const int start = blockIdx.x * BT;
    if (start >= c) return;
    const int m = min(BT, c - start);

    __shared__ short hs[BT][520];
    __shared__ short es[BT][264];
    __shared__ int   tok_s[BT];
    __shared__ float w_s[BT];

    const int tid = threadIdx.x;
    if (tid < BT) {
        bool ok = tid < m;
        tok_s[tid] = ok ? toks[(size_t)e * N_TOK + start + tid] : 0;
        w_s[tid]   = ok ? wgts[(size_t)e * N_TOK + start + tid] : 0.f;
    }
    __syncthreads();
    for (int idx = tid; idx < BT * 64; idx += 512) {
        int t = idx >> 6, ch = idx & 63;
        uint4 v = make_uint4(0, 0, 0, 0);
        if (t < m) v = *((const uint4*)(h_normb + (size_t)(tok_s[t] >> 2) * DM) + ch);
        *(uint4*)&hs[t][ch * 8] = v;
    }
    __syncthreads();

    const int wave = tid >> 6, lane = tid & 63;
    const int quad = lane >> 4, lm = lane & 15;
    const int mt = wave & 1;

    // ---- phase 1: es = gelu(hs @ W1 + b1), 32x256; 8 waves x 4 n-tiles ----
    {
        const int ng = (wave >> 1) * 4;
        f32x4 acc[4];
#pragma unroll
        for (int i = 0; i < 4; i++) acc[i] = (f32x4)(0.f);
        const short* w1e = wB1 + (size_t)e * DM * DE;
        for (int kb = 0; kb < 16; kb++) {
            bf16x8 a = *(const bf16x8*)&hs[mt * 16 + lm][kb * 32 + quad * 8];
            const short* wp = w1e + ((size_t)kb * 16 + ng) * 512 + lane * 8;
#pragma unroll
            for (int nt = 0; nt < 4; nt++) {
                bf16x8 b = *(const bf16x8*)(wp + nt * 512);
                acc[nt] = MFMA16(a, b, acc[nt]);
            }
        }
#pragma unroll
        for (int nt = 0; nt < 4; nt++) {
            int col = (ng + nt) * 16 + lm;
            float b1 = eb1[e * DE + col];
#pragma unroll
            for (int r = 0; r < 4; r++) {
                int row = mt * 16 + quad * 4 + r;
                es[row][col] = f2bf(gelu_t(acc[nt][r] + b1));
            }
        }
    }
    __syncthreads();

    // ---- phase 2: part[tok] = w * (es @ W2 + b2), 32x512; 8 waves x 8 n-tiles ----
    {
        const int ng2 = (wave >> 1) * 8;
        f32x4 acc[8];
#pragma unroll
        for (int i = 0; i < 8; i++) acc[i] = (f32x4)(0.f);
        const short* w2e = wB2 + (size_t)e * DE * DM;
        for (int kb = 0; kb < 8; kb++) {
            bf16x8 a = *(const bf16x8*)&es[mt * 16 + lm][kb * 32 + quad * 8];
            const short* wp = w2e + ((size_t)kb * 32 + ng2) * 512 + lane * 8;
#pragma unroll
            for (int nt = 0; nt < 8; nt++) {
                bf16x8 b = *(const bf16x8*)(wp + nt * 512);
                acc[nt] = MFMA16(a, b, acc[nt]);
            }
        }
        const float* b2 = eb2 + (size_t)e * DM;
#pragma unroll
        for (int r = 0; r < 4; r++) {
            int row = mt * 16 + quad * 4 + r;
            if (row < m) {
                float w = w_s[row];
                float* prow = part + (size_t)tok_s[row] * DM;
#pragma unroll
                for (int nt = 0; nt < 8; nt++) {
                    int col = (ng2 + nt) * 16 + lm;
                    prow[col] = w * (acc[nt][r] + b2[col]);
                }
            }
        }
    }
}

// ---------------- final reduce: out[n] = sum_s part[n*4+s] ----------------
__global__ void k_reduce(const float* __restrict__ part, float* __restrict__ out) {
    int n = blockIdx.x;
    int j = threadIdx.x; // 0..127
    const float4* p = (const float4*)(part + (size_t)n * 4 * DM);
    float4 a = p[j], b = p[128 + j], c = p[256 + j], d = p[384 + j];
    float4 r = make_float4(a.x + b.x + c.x + d.x, a.y + b.y + c.y + d.y,
                           a.z + b.z + c.z + d.z, a.w + b.w + c.w + d.w);
    ((float4*)(out + (size_t)n * DM))[j] = r;
}

extern "C" void kernel_launch(void* const* d_in, const int* in_sizes, int n_in,
                              void* d_out, int out_size, void* d_ws, size_t ws_size,
                              hipStream_t stream) {
    const float* hidden  = (const float*)d_in[0];
    const float* feat    = (const float*)d_in[1];
    const float* pre_g   = (const float*)d_in[2];
    const float* pre_b   = (const float*)d_in[3];
    const float* rh_g    = (const float*)d_in[4];
    const float* rh_b    = (const float*)d_in[5];
    const float* rh_w1   = (const float*)d_in[6];
    const float* rh_b1   = (const float*)d_in[7];
    const float* rh_w2   = (const float*)d_in[8];
    const float* rh_b2   = (const float*)d_in[9];
    const float* sf_g    = (const float*)d_in[10];
    const float* sf_b    = (const float*)d_in[11];
    const float* sf_w1   = (const float*)d_in[12];
    const float* sf_b1   = (const float*)d_in[13];
    const float* sf_w2   = (const float*)d_in[14];
    const float* sf_b2   = (const float*)d_in[15];
    const float* gln_g   = (const float*)d_in[16];
    const float* gln_b   = (const float*)d_in[17];
    const float* gf_w1   = (const float*)d_in[18];
    const float* gf_b1   = (const float*)d_in[19];
    const float* gf_w2   = (const float*)d_in[20];
    const float* gf_b2   = (const float*)d_in[21];
    const float* pgs_w1  = (const float*)d_in[22];
    const float* pgs_b1  = (const float*)d_in[23];
    const float* pgs_w2  = (const float*)d_in[24];
    const float* pgs_b2  = (const float*)d_in[25];
    const float* ir_w1   = (const float*)d_in[26];
    const float* ir_b1   = (const float*)d_in[27];
    const float* ir_w2   = (const float*)d_in[28];
    const float* ir_b2   = (const float*)d_in[29];
    const float* ex_w1   = (const float*)d_in[30];
    const float* ex_b1   = (const float*)d_in[31];
    const float* ex_w2   = (const float*)d_in[32];
    const float* ex_b2   = (const float*)d_in[33];
    float* out = (float*)d_out;

    // workspace carving (256B-aligned)
    char* w = (char*)d_ws;
    auto alloc = [&](size_t bytes) { void* r = (void*)w; w += (bytes + 255) & ~(size_t)255; return r; };
    __hip_bfloat16* h_normb = (__hip_bfloat16*)alloc((size_t)N_TOK * DM * 2);
    float* sL    = (float*)alloc((size_t)N_TOK * FDIM * 4);
    float* h_enc = (float*)alloc((size_t)N_TOK * DH * 4);
    float* s_enc = (float*)alloc((size_t)N_TOK * DH * 4);
    float* g_enc = (float*)alloc((size_t)N_TOK * G * DH * 4);
    float* glog  = (float*)alloc((size_t)N_TOK * G * 4);
    float* ilog  = (float*)alloc((size_t)N_TOK * G * ES * 4);
    float* wgts  = (float*)alloc((size_t)E_EXP * N_TOK * 4);
    short* wB1   = (short*)alloc((size_t)E_EXP * DM * DE * 2);
    short* wB2   = (short*)alloc((size_t)E_EXP * DE * DM * 2);
    short* AhsH  = (short*)alloc((size_t)N_TOK * 256 * 2);
    short* AhsM  = (short*)alloc((size_t)N_TOK * 256 * 2);
    short* AhsL  = (short*)alloc((size_t)N_TOK * 256 * 2);
    short* BpgH  = (short*)alloc((size_t)16 * 8 * 512 * 2);
    short* BpgM  = (short*)alloc((size_t)16 * 8 * 512 * 2);
    short* BpgL  = (short*)alloc((size_t)16 * 8 * 512 * 2);
    short* BirH  = (short*)alloc((size_t)G * 16 * 8 * 512 * 2);
    short* BirM  = (short*)alloc((size_t)G * 16 * 8 * 512 * 2);
    short* BirL  = (short*)alloc((size_t)G * 16 * 8 * 512 * 2);
    // encoder weight splits (small)
    short* Brh1H = (short*)alloc((size_t)16 * 8 * 512 * 2);
    short* Brh1M = (short*)alloc((size_t)16 * 8 * 512 * 2);
    short* Brh1L = (short*)alloc((size_t)16 * 8 * 512 * 2);
    short* Brh2H = (short*)alloc((size_t)4 * 8 * 512 * 2);
    short* Brh2M = (short*)alloc((size_t)4 * 8 * 512 * 2);
    short* Brh2L = (short*)alloc((size_t)4 * 8 * 512 * 2);
    short* Bsf1H = (short*)alloc((size_t)4 * 8 * 512 * 2);
    short* Bsf1M = (short*)alloc((size_t)4 * 8 * 512 * 2);
    short* Bsf1L = (short*)alloc((size_t)4 * 8 * 512 * 2);
    short* Bsf2H = (short*)alloc((size_t)4 * 8 * 512 * 2);
    short* Bsf2M = (short*)alloc((size_t)4 * 8 * 512 * 2);
    short* Bsf2L = (short*)alloc((size_t)4 * 8 * 512 * 2);
    short* Bgf1H = (short*)alloc((size_t)G * 1 * 8 * 512 * 2);
    short* Bgf1M = (short*)alloc((size_t)G * 1 * 8 * 512 * 2);
    short* Bgf1L = (short*)alloc((size_t)G * 1 * 8 * 512 * 2);
    short* Bgf2H = (short*)alloc((size_t)G * 4 * 8 * 512 * 2);
    short* Bgf2M = (short*)alloc((size_t)G * 4 * 8 * 512 * 2);
    short* Bgf2L = (short*)alloc((size_t)G * 4 * 8 * 512 * 2);
    int* cnt     = (int*)alloc(E_EXP * 4);
    int* toks    = (int*)alloc((size_t)E_EXP * N_TOK * 4);
    // union region (disjoint live ranges, stream-ordered):
    //   hL   [k_ln_hidden -> k_enc2<16>]           8.4 MB
    //   Ag3  [k_stage_g(p) -> k_router_mfma(p)]   25.2 MB per pass
    //   part [k_expert_mfma -> k_reduce]          33.6 MB
    size_t agsz = (size_t)N_TOK * GP * 256 * 2;   // 8.39 MB per split
    char* uni   = (char*)alloc((size_t)N_TOK * 4 * DM * 4); // 33.6 MB = max
    float* hL   = (float*)uni;
    short* AgH  = (short*)uni;
    short* AgM  = (short*)(uni + agsz);
    short* AgL  = (short*)(uni + 2 * agsz);
    float* part = (float*)uni;

    hipMemsetAsync(cnt, 0, E_EXP * sizeof(int), stream);

    // weight conversions (independent of token pipeline)
    k_conv_w<<<E_EXP * 16, 256, 0, stream>>>(ex_w1, wB1, 16, 16);
    k_conv_w<<<E_EXP * 8, 256, 0, stream>>>(ex_w2, wB2, 8, 32);
    k_conv_b3<<<16, 256, 0, stream>>>(pgs_w1, BpgH, BpgM, BpgL, 16, 8, 512);
    k_conv_b3<<<G * 16, 256, 0, stream>>>(ir_w1, BirH, BirM, BirL, 16, 8, 512);
    k_conv_b3<<<16, 256, 0, stream>>>(rh_w1, Brh1H, Brh1M, Brh1L, 16, 8, 512);
    k_conv_b3<<<4, 256, 0, stream>>>(rh_w2, Brh2H, Brh2M, Brh2L, 4, 8, 128);
    k_conv_b3<<<4, 256, 0, stream>>>(sf_w1, Bsf1H, Bsf1M, Bsf1L, 4, 8, 128);
    k_conv_b3<<<4, 256, 0, stream>>>(sf_w2, Bsf2H, Bsf2M, Bsf2L, 4, 8, 128);
    k_conv_b3<<<G * 1, 256, 0, stream>>>(gf_w1, Bgf1H, Bgf1M, Bgf1L, 1, 8, 16);
    k_conv_b3<<<G * 4, 256, 0, stream>>>(gf_w2, Bgf2H, Bgf2M, Bgf2L, 4, 8, 128);

    k_ln_hidden<<<N_TOK, 256, 0, stream>>>(hidden, pre_g, pre_b, rh_g, rh_b, h_normb, hL);
    k_ln_feat<<<N_TOK, 128, 0, stream>>>(feat, sf_g, sf_b, sL);

    // encoder MLPs via 3-split MFMA
    k_enc2_mfma<16><<<N_TOK / 32, 256, 0, stream>>>(hL, Brh1H, Brh1M, Brh1L, rh_b1,
                                                    Brh2H, Brh2M, Brh2L, rh_b2, h_enc);
    k_enc2_mfma<4><<<N_TOK / 32, 256, 0, stream>>>(sL, Bsf1H, Bsf1M, Bsf1L, sf_b1,
                                                   Bsf2H, Bsf2M, Bsf2L, sf_b2, s_enc);
    k_genc_mfma<<<N_TOK / 32, 256, 0, stream>>>(feat, gln_g, gln_b,
                                                Bgf1H, Bgf1M, Bgf1L, gf_b1,
                                                Bgf2H, Bgf2M, Bgf2L, gf_b2, g_enc);

    k_stage_hs<<<N_TOK / 16, 256, 0, stream>>>(h_enc, s_enc, AhsH, AhsM, AhsL);

    // router in two passes of GP=4 groups (bounds Ag workspace)
    for (int g0 = 0; g0 < G; g0 += GP) {
        dim3 sgrid(N_TOK / 16, GP);
        k_stage_g<<<sgrid, 256, 0, stream>>>(h_enc, g_enc, AgH, AgM, AgL, g0);
        dim3 rgrid(N_TOK / 32, GP);
        k_router_mfma<<<rgrid, 256, 0, stream>>>(AhsH, AhsM, AhsL, AgH, AgM, AgL,
                                                 BpgH, BpgM, BpgL, BirH, BirM, BirL,
                                                 pgs_b1, pgs_w2, pgs_b2, ir_b1, ir_w2, ir_b2,
                                                 glog, ilog, g0);
    }

    k_topk<<<N_TOK / 256, 256, 0, stream>>>(glog, ilog, cnt, toks, wgts);
    dim3 egrid(N_TOK / BT, E_EXP);
    k_expert_mfma<<<egrid, 512, 0, stream>>>(h_normb, wB1, ex_b1, wB2, ex_b2, cnt, toks, wgts, part);
    k_reduce<<<N_TOK, 128, 0, stream>>>(part, out);
}

// Round 6
// 433.972 us; speedup vs baseline: 2.5525x; 1.1044x over previous
//
#include <hip/hip_runtime.h>
#include <hip/hip_bf16.h>
#include <math.h>

#define N_TOK 4096
#define DM 512
#define FDIM 128
#define G 8
#define FG 16
#define DH 128
#define DE 256
#define ES 4
#define E_EXP 32
#define LN_EPS 1e-5f
#define BT 32   // expert token tile (MFMA)

typedef __attribute__((ext_vector_type(8))) short bf16x8;  // 8 bf16 = 4 VGPRs
typedef __attribute__((ext_vector_type(4))) float f32x4;

#define MFMA16(a, b, c) __builtin_amdgcn_mfma_f32_16x16x32_bf16((a), (b), (c), 0, 0, 0)

__device__ __forceinline__ float gelu_t(float x) {
    const float c = 0.7978845608028654f; // sqrt(2/pi)
    float x3 = x * x * x;
    return 0.5f * x * (1.0f + tanhf(c * (x + 0.044715f * x3)));
}

__device__ __forceinline__ short f2bf(float f) {
    __hip_bfloat16 h = __float2bfloat16(f);
    return *reinterpret_cast<short*>(&h);
}
__device__ __forceinline__ float bf2f(short s) {
    __hip_bfloat16 h = *reinterpret_cast<__hip_bfloat16*>(&s);
    return __bfloat162float(h);
}
// exact 3-way split: x == bf2f(h)+bf2f(m)+bf2f(l) bit-exactly for fp32 x
__device__ __forceinline__ void split3(float x, short& h, short& m, short& l) {
    h = f2bf(x);
    float r = x - bf2f(h);   // exact in fp32
    m = f2bf(r);
    float r2 = r - bf2f(m);  // exact; <=6 significant bits remain
    l = f2bf(r2);            // exact
}

// ---------------- LN of hidden: pre_ln -> h_norm (bf16) and rh_ln -> hL (fp32) ----------------
__global__ void k_ln_hidden(const float* __restrict__ hidden,
                            const float* __restrict__ pg, const float* __restrict__ pb,
                            const float* __restrict__ rg, const float* __restrict__ rb,
                            __hip_bfloat16* __restrict__ h_normb, float* __restrict__ hL) {
    int n = blockIdx.x;
    int j = threadIdx.x; // 0..255
    const float* x = hidden + (size_t)n * DM;
    float v0 = x[j], v1 = x[j + 256];
    float s = v0 + v1, q = v0 * v0 + v1 * v1;
#pragma unroll
    for (int o = 32; o; o >>= 1) { s += __shfl_down(s, o); q += __shfl_down(q, o); }
    __shared__ float red[8];
    int w = j >> 6;
    if ((j & 63) == 0) { red[w] = s; red[4 + w] = q; }
    __syncthreads();
    float sum = red[0] + red[1] + red[2] + red[3];
    float sq  = red[4] + red[5] + red[6] + red[7];
    float m = sum * (1.0f / DM);
    float var = sq * (1.0f / DM) - m * m;
    float rs = rsqrtf(var + LN_EPS);
    float t0 = (v0 - m) * rs, t1 = (v1 - m) * rs;
    size_t base = (size_t)n * DM;
    h_normb[base + j]       = __float2bfloat16(t0 * pg[j]       + pb[j]);
    h_normb[base + j + 256] = __float2bfloat16(t1 * pg[j + 256] + pb[j + 256]);
    hL[base + j]           = t0 * rg[j]       + rb[j];
    hL[base + j + 256]     = t1 * rg[j + 256] + rb[j + 256];
}

// ---------------- LN of feat (sf_ln) -> sL ----------------
__global__ void k_ln_feat(const float* __restrict__ feat,
                          const float* __restrict__ g, const float* __restrict__ b,
                          float* __restrict__ sL) {
    int n = blockIdx.x;
    int j = threadIdx.x; // 0..127
    float v = feat[(size_t)n * FDIM + j];
    float s = v, q = v * v;
#pragma unroll
    for (int o = 32; o; o >>= 1) { s += __shfl_down(s, o); q += __shfl_down(q, o); }
    __shared__ float red[4];
    int w = j >> 6;
    if ((j & 63) == 0) { red[w] = s; red[2 + w] = q; }
    __syncthreads();
    float sum = red[0] + red[1], sq = red[2] + red[3];
    float m = sum * (1.0f / FDIM);
    float var = sq * (1.0f / FDIM) - m * m;
    float rs = rsqrtf(var + LN_EPS);
    sL[(size_t)n * FDIM + j] = (v - m) * rs * g[j] + b[j];
}

// ---------------- unified weight conversion: plain bf16 or 3-way split, K zero-pad ----------------
struct ConvJob { const float* src; short* dh; short* dm; short* dl;
                 int KB, NB, Kreal, plain, blk0; };
struct ConvJobs { ConvJob j[10]; };

__global__ void k_conv_all(ConvJobs J) {
    int b = blockIdx.x;
    int ji = 0;
#pragma unroll
    for (int i = 1; i < 10; i++) if (b >= J.j[i].blk0) ji = i;
    const ConvJob jb = J.j[ji];
    int rel = b - jb.blk0;
    int mat = rel / jb.KB, kb = rel % jb.KB;
    int ncols = jb.NB * 16;
    const float* s = jb.src + (size_t)mat * jb.Kreal * ncols;
    size_t dbase = ((size_t)mat * jb.KB + kb) * jb.NB * 512;
    for (int p = threadIdx.x; p < jb.NB * 64; p += 256) {
        int nb = p >> 6, lane = p & 63;
        int row0 = kb * 32 + ((lane >> 4) << 3);
        int col = nb * 16 + (lane & 15);
        if (jb.plain) {
            union { short sh[8]; uint4 v; } t;
#pragma unroll
            for (int j = 0; j < 8; j++) {
                float x = (row0 + j < jb.Kreal) ? s[(size_t)(row0 + j) * ncols + col] : 0.f;
                t.sh[j] = f2bf(x);
            }
            *(uint4*)&jb.dh[dbase + (size_t)p * 8] = t.v;
        } else {
            union { short sh[8]; uint4 v; } hi, mi, lo;
#pragma unroll
            for (int j = 0; j < 8; j++) {
                float x = (row0 + j < jb.Kreal) ? s[(size_t)(row0 + j) * ncols + col] : 0.f;
                split3(x, hi.sh[j], mi.sh[j], lo.sh[j]);
            }
            *(uint4*)&jb.dh[dbase + (size_t)p * 8] = hi.v;
            *(uint4*)&jb.dm[dbase + (size_t)p * 8] = mi.v;
            *(uint4*)&jb.dl[dbase + (size_t)p * 8] = lo.v;
        }
    }
}

// ---------------- 2-layer MLP via 3-split MFMA: Y = gelu(X@W1+b1)@W2+b2 ----------------
template <int KB_TOT>
__global__ __launch_bounds__(256) void k_enc2_mfma(
        const float* __restrict__ X,
        const short* __restrict__ W1h, const short* __restrict__ W1m, const short* __restrict__ W1l,
        const float* __restrict__ B1,
        const short* __restrict__ W2h, const short* __restrict__ W2m, const short* __restrict__ W2l,
        const float* __restrict__ B2,
        float* __restrict__ Y) {
    constexpr int K = KB_TOT * 32;
    constexpr int NCHUNK = KB_TOT / 4;
    const int n0 = blockIdx.x * 32;
    const int tid = threadIdx.x;
    const int wave = tid >> 6, lane = tid & 63;
    const int quad = lane >> 4, lm = lane & 15;
    const int mt = wave & 1;
    const int ngb = (wave >> 1) * 4;   // 4 n-tiles per wave

    __shared__ short Ah[32][132], Am[32][132], Al[32][132];

    f32x4 acc[4];
#pragma unroll
    for (int i = 0; i < 4; i++) acc[i] = (f32x4)(0.f);

    for (int ch = 0; ch < NCHUNK; ch++) {
        __syncthreads();
        for (int idx = tid; idx < 1024; idx += 256) {
            int row = idx >> 5, c4 = (idx & 31) * 4;
            float4 v = *(const float4*)&X[(size_t)(n0 + row) * K + ch * 128 + c4];
            float xv[4] = {v.x, v.y, v.z, v.w};
#pragma unroll
            for (int j = 0; j < 4; j++) {
                short h, m, l; split3(xv[j], h, m, l);
                Ah[row][c4 + j] = h; Am[row][c4 + j] = m; Al[row][c4 + j] = l;
            }
        }
        __syncthreads();
#pragma unroll
        for (int kb = 0; kb < 4; kb++) {
            int kbg = ch * 4 + kb;
            bf16x8 ah = *(const bf16x8*)&Ah[mt * 16 + lm][kb * 32 + quad * 8];
            bf16x8 am = *(const bf16x8*)&Am[mt * 16 + lm][kb * 32 + quad * 8];
            bf16x8 al = *(const bf16x8*)&Al[mt * 16 + lm][kb * 32 + quad * 8];
#pragma unroll
            for (int nt = 0; nt < 4; nt++) {
                size_t bi = (((size_t)kbg * 8 + ngb + nt) * 64 + lane) * 8;
                bf16x8 bh = *(const bf16x8*)&W1h[bi];
                bf16x8 bm = *(const bf16x8*)&W1m[bi];
                bf16x8 bl = *(const bf16x8*)&W1l[bi];
                acc[nt] = MFMA16(al, bh, acc[nt]);
                acc[nt] = MFMA16(am, bm, acc[nt]);
                acc[nt] = MFMA16(ah, bl, acc[nt]);
                acc[nt] = MFMA16(am, bh, acc[nt]);
                acc[nt] = MFMA16(ah, bm, acc[nt]);
                acc[nt] = MFMA16(ah, bh, acc[nt]);
            }
        }
    }
    __syncthreads();
#pragma unroll
    for (int nt = 0; nt < 4; nt++) {
        int col = (ngb + nt) * 16 + lm;
        float b1 = B1[col];
#pragma unroll
        for (int r = 0; r < 4; r++) {
            int row = mt * 16 + quad * 4 + r;
            short h, m, l; split3(gelu_t(acc[nt][r] + b1), h, m, l);
            Ah[row][col] = h; Am[row][col] = m; Al[row][col] = l;
        }
    }
    __syncthreads();
    f32x4 acc2[4];
#pragma unroll
    for (int i = 0; i < 4; i++) acc2[i] = (f32x4)(0.f);
#pragma unroll
    for (int kb = 0; kb < 4; kb++) {
        bf16x8 ah = *(const bf16x8*)&Ah[mt * 16 + lm][kb * 32 + quad * 8];
        bf16x8 am = *(const bf16x8*)&Am[mt * 16 + lm][kb * 32 + quad * 8];
        bf16x8 al = *(const bf16x8*)&Al[mt * 16 + lm][kb * 32 + quad * 8];
#pragma unroll
        for (int nt = 0; nt < 4; nt++) {
            size_t bi = (((size_t)kb * 8 + ngb + nt) * 64 + lane) * 8;
            bf16x8 bh = *(const bf16x8*)&W2h[bi];
            bf16x8 bm = *(const bf16x8*)&W2m[bi];
            bf16x8 bl = *(const bf16x8*)&W2l[bi];
            acc2[nt] = MFMA16(al, bh, acc2[nt]);
            acc2[nt] = MFMA16(am, bm, acc2[nt]);
            acc2[nt] = MFMA16(ah, bl, acc2[nt]);
            acc2[nt] = MFMA16(am, bh, acc2[nt]);
            acc2[nt] = MFMA16(ah, bm, acc2[nt]);
            acc2[nt] = MFMA16(ah, bh, acc2[nt]);
        }
    }
#pragma unroll
    for (int nt = 0; nt < 4; nt++) {
        int col = (ngb + nt) * 16 + lm;
        float b2 = B2[col];
#pragma unroll
        for (int r = 0; r < 4; r++) {
            int row = mt * 16 + quad * 4 + r;
            Y[(size_t)(n0 + row) * DH + col] = acc2[nt][r] + b2;
        }
    }
}

// ---------------- group encoders via 3-split MFMA ----------------
__global__ __launch_bounds__(256) void k_genc_mfma(
        const float* __restrict__ feat,
        const float* __restrict__ gln_g, const float* __restrict__ gln_b,
        const short* __restrict__ W1h, const short* __restrict__ W1m, const short* __restrict__ W1l,
        const float* __restrict__ gb1,
        const short* __restrict__ W2h, const short* __restrict__ W2m, const short* __restrict__ W2l,
        const float* __restrict__ gb2,
        float* __restrict__ g_enc) {
    const int n0 = blockIdx.x * 32;
    const int tid = threadIdx.x;
    const int wave = tid >> 6, lane = tid & 63;
    const int quad = lane >> 4, lm = lane & 15;
    const int mt = wave & 1;
    const int ngb = (wave >> 1) * 4;

    __shared__ short A1h[32][132], A1m[32][132], A1l[32][132];
    __shared__ short A2h[32][132], A2m[32][132], A2l[32][132];

    for (int half = 0; half < 2; half++) {
        __syncthreads();
        {
            int t = tid >> 3, sub = tid & 7, gl = sub >> 1, eo = sub & 1;
            int g = half * 4 + gl;
            const float* fr = feat + (size_t)(n0 + t) * FDIM + g * FG;
            float xv[FG];
            float mean = 0.f;
#pragma unroll
            for (int i = 0; i < FG; i++) { xv[i] = fr[i]; mean += xv[i]; }
            mean *= (1.0f / FG);
            float var = 0.f;
#pragma unroll
            for (int i = 0; i < FG; i++) { float d = xv[i] - mean; var += d * d; }
            var *= (1.0f / FG);
            float rs = rsqrtf(var + LN_EPS);
            for (int i = eo * 8; i < eo * 8 + 8; i++) {
                float xn = (xv[i] - mean) * rs * gln_g[g * FG + i] + gln_b[g * FG + i];
                short h, m, l; split3(xn, h, m, l);
                A1h[t][gl * 32 + i] = h; A1m[t][gl * 32 + i] = m; A1l[t][gl * 32 + i] = l;
                A1h[t][gl * 32 + 16 + i] = 0; A1m[t][gl * 32 + 16 + i] = 0; A1l[t][gl * 32 + 16 + i] = 0;
            }
        }
        __syncthreads();
        for (int gl = 0; gl < 4; gl++) {
            int g = half * 4 + gl;
            bf16x8 ah = *(const bf16x8*)&A1h[mt * 16 + lm][gl * 32 + quad * 8];
            bf16x8 am = *(const bf16x8*)&A1m[mt * 16 + lm][gl * 32 + quad * 8];
            bf16x8 al = *(const bf16x8*)&A1l[mt * 16 + lm][gl * 32 + quad * 8];
            f32x4 acc[4];
#pragma unroll
            for (int i = 0; i < 4; i++) acc[i] = (f32x4)(0.f);
#pragma unroll
            for (int nt = 0; nt < 4; nt++) {
                size_t bi = (((size_t)g * 8 + ngb + nt) * 64 + lane) * 8;
                bf16x8 bh = *(const bf16x8*)&W1h[bi];
                bf16x8 bm = *(const bf16x8*)&W1m[bi];
                bf16x8 bl = *(const bf16x8*)&W1l[bi];
                acc[nt] = MFMA16(al, bh, acc[nt]);
                acc[nt] = MFMA16(am, bm, acc[nt]);
                acc[nt] = MFMA16(ah, bl, acc[nt]);
                acc[nt] = MFMA16(am, bh, acc[nt]);
                acc[nt] = MFMA16(ah, bm, acc[nt]);
                acc[nt] = MFMA16(ah, bh, acc[nt]);
            }
            __syncthreads();
#pragma unroll
            for (int nt = 0; nt < 4; nt++) {
                int col = (ngb + nt) * 16 + lm;
                float b1 = gb1[g * DH + col];
#pragma unroll
                for (int r = 0; r < 4; r++) {
                    int row = mt * 16 + quad * 4 + r;
                    short h, m, l; split3(gelu_t(acc[nt][r] + b1), h, m, l);
                    A2h[row][col] = h; A2m[row][col] = m; A2l[row][col] = l;
                }
            }
            __syncthreads();
            f32x4 acc2[4];
#pragma unroll
            for (int i = 0; i < 4; i++) acc2[i] = (f32x4)(0.f);
#pragma unroll
            for (int kb = 0; kb < 4; kb++) {
                bf16x8 a2h = *(const bf16x8*)&A2h[mt * 16 + lm][kb * 32 + quad * 8];
                bf16x8 a2m = *(const bf16x8*)&A2m[mt * 16 + lm][kb * 32 + quad * 8];
                bf16x8 a2l = *(const bf16x8*)&A2l[mt * 16 + lm][kb * 32 + quad * 8];
#pragma unroll
                for (int nt = 0; nt < 4; nt++) {
                    size_t bi = ((((size_t)g * 4 + kb) * 8 + ngb + nt) * 64 + lane) * 8;
                    bf16x8 bh = *(const bf16x8*)&W2h[bi];
                    bf16x8 bm = *(const bf16x8*)&W2m[bi];
                    bf16x8 bl = *(const bf16x8*)&W2l[bi];
                    acc2[nt] = MFMA16(a2l, bh, acc2[nt]);
                    acc2[nt] = MFMA16(a2m, bm, acc2[nt]);
                    acc2[nt] = MFMA16(a2h, bl, acc2[nt]);
                    acc2[nt] = MFMA16(a2m, bh, acc2[nt]);
                    acc2[nt] = MFMA16(a2h, bm, acc2[nt]);
                    acc2[nt] = MFMA16(a2h, bh, acc2[nt]);
                }
            }
#pragma unroll
            for (int nt = 0; nt < 4; nt++) {
                int col = (ngb + nt) * 16 + lm;
                float b2 = gb2[g * DH + col];
#pragma unroll
                for (int r = 0; r < 4; r++) {
                    int row = mt * 16 + quad * 4 + r;
                    g_enc[((size_t)(n0 + row) * G + g) * DH + col] = acc2[nt][r] + b2;
                }
            }
        }
    }
}

// ---------------- stage A-fragments (3-way split bf16) for router k<256 (h|s) ----------------
__global__ void k_stage_hs(const float* __restrict__ h_enc, const float* __restrict__ s_enc,
                           short* __restrict__ Ah, short* __restrict__ Am, short* __restrict__ Al) {
    int T16 = blockIdx.x;
    for (int slot = threadIdx.x; slot < 512; slot += 256) {
        int kb = slot >> 6, lane = slot & 63;
        int quad = lane >> 4, lm = lane & 15;
        int n = T16 * 16 + lm;
        int c0 = kb * 32 + quad * 8; // 0..255
        const float* src = (c0 < 128) ? (h_enc + (size_t)n * DH + c0)
                                      : (s_enc + (size_t)n * DH + (c0 - 128));
        float4 x0 = *(const float4*)src;
        float4 x1 = *(const float4*)(src + 4);
        float xv[8] = {x0.x, x0.y, x0.z, x0.w, x1.x, x1.y, x1.z, x1.w};
        union { short sh[8]; uint4 v; } hi, mi, lo;
#pragma unroll
        for (int j = 0; j < 8; j++) split3(xv[j], hi.sh[j], mi.sh[j], lo.sh[j]);
        size_t base = ((size_t)T16 * 512 + slot) * 8;
        *(uint4*)&Ah[base] = hi.v;
        *(uint4*)&Am[base] = mi.v;
        *(uint4*)&Al[base] = lo.v;
    }
}

// ---------------- MFMA router (single pass, all 8 groups): in-kernel g-part staging ----------------
__global__ __launch_bounds__(256) void k_router_mfma(
        const short* __restrict__ AhsH, const short* __restrict__ AhsM, const short* __restrict__ AhsL,
        const float* __restrict__ h_enc, const float* __restrict__ g_enc,
        const short* __restrict__ BpgH, const short* __restrict__ BpgM, const short* __restrict__ BpgL,
        const short* __restrict__ BirH, const short* __restrict__ BirM, const short* __restrict__ BirL,
        const float* __restrict__ pb1, const float* __restrict__ pw2, const float* __restrict__ pb2,
        const float* __restrict__ ib1, const float* __restrict__ iw2, const float* __restrict__ ib2,
        float* __restrict__ glog, float* __restrict__ ilog) {
    const int bx = blockIdx.x;      // 32-token tile
    const int g = blockIdx.y;
    const int tid = threadIdx.x;
    const int wave = tid >> 6, lane = tid & 63;
    const int quad = lane >> 4, lm = lane & 15;
    const bool is_pg = wave < 2;
    const int nbase = (wave & 1) * 4;          // 4 n-tiles per wave
    const short* Bh = is_pg ? BpgH : (BirH + (size_t)g * 65536);
    const short* Bm = is_pg ? BpgM : (BirM + (size_t)g * 65536);
    const short* Bl = is_pg ? BpgL : (BirL + (size_t)g * 65536);
    const int n0 = bx * 32;

    // LDS union: g-part 3-split staging (50688 B) then ph/ih epilogue (33024 B)
    __shared__ __align__(16) char smem[3 * 32 * 264 * 2];
    short (*Sh)[264] = (short(*)[264])smem;
    short (*Sm)[264] = (short(*)[264])(smem + 32 * 264 * 2);
    short (*Sl)[264] = (short(*)[264])(smem + 2 * 32 * 264 * 2);
    float (*ph)[129] = (float(*)[129])smem;
    float (*ih)[129] = (float(*)[129])(smem + 32 * 129 * 4);

    // stage g-part: k in [0,256) = [g_enc | h_enc*g_enc], split3 into LDS
    for (int idx = tid; idx < 32 * 64; idx += 256) {
        int row = idx >> 6, c4 = (idx & 63) * 4;
        int n = n0 + row;
        float4 v;
        if (c4 < 128) {
            v = *(const float4*)&g_enc[((size_t)n * G + g) * DH + c4];
        } else {
            int c = c4 - 128;
            float4 gv = *(const float4*)&g_enc[((size_t)n * G + g) * DH + c];
            float4 hv = *(const float4*)&h_enc[(size_t)n * DH + c];
            v = make_float4(gv.x * hv.x, gv.y * hv.y, gv.z * hv.z, gv.w * hv.w);
        }
        float xv[4] = {v.x, v.y, v.z, v.w};
        union { short sh[4]; uint2 u; } hi, mi, lo;
#pragma unroll
        for (int j = 0; j < 4; j++) split3(xv[j], hi.sh[j], mi.sh[j], lo.sh[j]);
        *(uint2*)&Sh[row][c4] = hi.u;
        *(uint2*)&Sm[row][c4] = mi.u;
        *(uint2*)&Sl[row][c4] = lo.u;
    }
    __syncthreads();

    f32x4 acc[2][4];
#pragma unroll
    for (int mt = 0; mt < 2; mt++)
#pragma unroll
        for (int nt = 0; nt < 4; nt++) acc[mt][nt] = (f32x4)(0.f);

    for (int kb = 0; kb < 16; kb++) {
        bf16x8 Ahf[2], Amf[2], Alf[2];
#pragma unroll
        for (int mt = 0; mt < 2; mt++) {
            if (kb < 8) {
                size_t ai = (((size_t)(2 * bx + mt) * 8 + kb) * 64 + lane) * 8;
                Ahf[mt] = *(const bf16x8*)&AhsH[ai];
                Amf[mt] = *(const bf16x8*)&AhsM[ai];
                Alf[mt] = *(const bf16x8*)&AhsL[ai];
            } else {
                int row = mt * 16 + lm, c = (kb - 8) * 32 + quad * 8;
                Ahf[mt] = *(const bf16x8*)&Sh[row][c];
                Amf[mt] = *(const bf16x8*)&Sm[row][c];
                Alf[mt] = *(const bf16x8*)&Sl[row][c];
            }
        }
#pragma unroll
        for (int nt = 0; nt < 4; nt++) {
            int nb = nbase + nt;
            size_t bi = (((size_t)kb * 8 + nb) * 64 + lane) * 8;
            bf16x8 bh = *(const bf16x8*)&Bh[bi];
            bf16x8 bm = *(const bf16x8*)&Bm[bi];
            bf16x8 bl = *(const bf16x8*)&Bl[bi];
#pragma unroll
            for (int mt = 0; mt < 2; mt++) {
                acc[mt][nt] = MFMA16(Alf[mt], bh, acc[mt][nt]);
                acc[mt][nt] = MFMA16(Amf[mt], bm, acc[mt][nt]);
                acc[mt][nt] = MFMA16(Ahf[mt], bl, acc[mt][nt]);
                acc[mt][nt] = MFMA16(Amf[mt], bh, acc[mt][nt]);
                acc[mt][nt] = MFMA16(Ahf[mt], bm, acc[mt][nt]);
                acc[mt][nt] = MFMA16(Ahf[mt], bh, acc[mt][nt]);
            }
        }
    }
    __syncthreads();   // all waves done reading S before ph/ih overwrite

    float* dst = is_pg ? &ph[0][0] : &ih[0][0];
#pragma unroll
    for (int mt = 0; mt < 2; mt++)
#pragma unroll
    for (int nt = 0; nt < 4; nt++) {
        int col = (wave & 1) * 64 + nt * 16 + lm;
        float b1 = is_pg ? pb1[col] : ib1[g * DH + col];
#pragma unroll
        for (int r = 0; r < 4; r++) {
            int row = mt * 16 + quad * 4 + r;
            dst[row * 129 + col] = gelu_t(acc[mt][nt][r] + b1);
        }
    }
    __syncthreads();

    if (tid < 32) {
        float s = pb2[0];
        for (int i = 0; i < DH; i++) s += ph[tid][i] * pw2[i];
        glog[(size_t)(n0 + tid) * G + g] = s; // TEMP = 1.0
    } else if (tid >= 128) {
        int t = (tid - 128) >> 2, e = (tid - 128) & 3;
        float s = ib2[g * ES + e];
        const float* w = iw2 + (size_t)g * DH * ES;
        for (int i = 0; i < DH; i++) s += ih[t][i] * w[i * ES + e];
        ilog[((size_t)(n0 + t) * G + g) * ES + e] = s;
    }
}

// ---------------- top-k softmax + dispatch to per-expert lists ----------------
__global__ void k_topk(const float* __restrict__ glog, const float* __restrict__ ilog,
                       int* __restrict__ cnt, int* __restrict__ toks, float* __restrict__ wgts) {
    int n = blockIdx.x * blockDim.x + threadIdx.x;
    if (n >= N_TOK) return;
    float gl[G];
#pragma unroll
    for (int g = 0; g < G; g++) gl[g] = glog[(size_t)n * G + g];
    int i1 = 0; float v1 = gl[0];
#pragma unroll
    for (int g = 1; g < G; g++) if (gl[g] > v1) { v1 = gl[g]; i1 = g; }
    int i2 = -1; float v2 = -1e30f;
#pragma unroll
    for (int g = 0; g < G; g++) if (g != i1 && gl[g] > v2) { v2 = gl[g]; i2 = g; }
    float eg = expf(v2 - v1);
    float den = 1.0f / (1.0f + eg);
    float gw_sel[2] = { den, eg * den };
    int g_sel[2] = { i1, i2 };
#pragma unroll
    for (int s = 0; s < 2; s++) {
        int g = g_sel[s]; float gw = gw_sel[s];
        float il[ES];
#pragma unroll
        for (int e = 0; e < ES; e++) il[e] = ilog[((size_t)n * G + g) * ES + e];
        int j1 = 0; float u1 = il[0];
#pragma unroll
        for (int e = 1; e < ES; e++) if (il[e] > u1) { u1 = il[e]; j1 = e; }
        int j2 = -1; float u2 = -1e30f;
#pragma unroll
        for (int e = 0; e < ES; e++) if (e != j1 && il[e] > u2) { u2 = il[e]; j2 = e; }
        float ei = expf(u2 - u1);
        float d2 = 1.0f / (1.0f + ei);
        int ex1 = g * ES + j1, ex2 = g * ES + j2;
        int p1 = atomicAdd(&cnt[ex1], 1);
        toks[(size_t)ex1 * N_TOK + p1] = n * 4 + s * 2;     wgts[(size_t)ex1 * N_TOK + p1] = gw * d2;
        int p2 = atomicAdd(&cnt[ex2], 1);
        toks[(size_t)ex2 * N_TOK + p2] = n * 4 + s * 2 + 1; wgts[(size_t)ex2 * N_TOK + p2] = gw * ei * d2;
    }
}

// ---------------- sparse expert MLPs via bf16 MFMA; XCD-swizzled 1D grid ----------------
// bid = slot*32 + e  =>  bid % 8 == e % 8: all blocks of expert e land on one XCD,
// per-XCD weight working set = 4 experts x 512KB = 2MB < 4MB L2.
__global__ __launch_bounds__(512) void k_expert_mfma(
        const __hip_bfloat16* __restrict__ h_normb,
        const short* __restrict__ wB1, const float* __restrict__ eb1,
        const short* __restrict__ wB2, const float* __restrict__ eb2,
        const int* __restrict__ cnt, const int* __restrict__ toks,
        const float* __restrict__ wgts, float* __restrict__ part) {
    const int e = blockIdx.x & 31;
    const int slot = blockIdx.x >> 5;
    const int c = cnt[e];
    const int start = slot * BT;
    if (start >= c) return;
    const int m = min(BT, c - start);

    __shared__ short hs[BT][520];
    __shared__ short es[BT][264];
    __shared__ int   tok_s[BT];
    __shared__ float w_s[BT];

    const int tid = threadIdx.x;
    if (tid < BT) {
        bool ok = tid < m;
        tok_s[tid] = ok ? toks[(size_t)e * N_TOK + start + tid] : 0;
        w_s[tid]   = ok ? wgts[(size_t)e * N_TOK + start + tid] : 0.f;
    }
    __syncthreads();
    for (int idx = tid; idx < BT * 64; idx += 512) {
        int t = idx >> 6, ch = idx & 63;
        uint4 v = make_uint4(0, 0, 0, 0);
        if (t < m) v = *((const uint4*)(h_normb + (size_t)(tok_s[t] >> 2) * DM) + ch);
        *(uint4*)&hs[t][ch * 8] = v;
    }
    __syncthreads();

    const int wave = tid >> 6, lane = tid & 63;
    const int quad = lane >> 4, lm = lane & 15;
    const int mt = wave & 1;

    // ---- phase 1: es = gelu(hs @ W1 + b1), 32x256; 8 waves x 4 n-tiles ----
    {
        const int ng = (wave >> 1) * 4;
        f32x4 acc[4];
#pragma unroll
        for (int i = 0; i < 4; i++) acc[i] = (f32x4)(0.f);
        const short* w1e = wB1 + (size_t)e * DM * DE;
        for (int kb = 0; kb < 16; kb++) {
            bf16x8 a = *(const bf16x8*)&hs[mt * 16 + lm][kb * 32 + quad * 8];
            const short* wp = w1e + ((size_t)kb * 16 + ng) * 512 + lane * 8;
#pragma unroll
            for (int nt = 0; nt < 4; nt++) {
                bf16x8 b = *(const bf16x8*)(wp + nt * 512);
                acc[nt] = MFMA16(a, b, acc[nt]);
            }
        }
#pragma unroll
        for (int nt = 0; nt < 4; nt++) {
            int col = (ng + nt) * 16 + lm;
            float b1 = eb1[e * DE + col];
#pragma unroll
            for (int r = 0; r < 4; r++) {
                int row = mt * 16 + quad * 4 + r;
                es[row][col] = f2bf(gelu_t(acc[nt][r] + b1));
            }
        }
    }
    __syncthreads();

    // ---- phase 2: part[tok] = w * (es @ W2 + b2), 32x512; 8 waves x 8 n-tiles ----
    {
        const int ng2 = (wave >> 1) * 8;
        f32x4 acc[8];
#pragma unroll
        for (int i = 0; i < 8; i++) acc[i] = (f32x4)(0.f);
        const short* w2e = wB2 + (size_t)e * DE * DM;
        for (int kb = 0; kb < 8; kb++) {
            bf16x8 a = *(const bf16x8*)&es[mt * 16 + lm][kb * 32 + quad * 8];
            const short* wp = w2e + ((size_t)kb * 32 + ng2) * 512 + lane * 8;
#pragma unroll
            for (int nt = 0; nt < 8; nt++) {
                bf16x8 b = *(const bf16x8*)(wp + nt * 512);
                acc[nt] = MFMA16(a, b, acc[nt]);
            }
        }
        const float* b2 = eb2 + (size_t)e * DM;
#pragma unroll
        for (int r = 0; r < 4; r++) {
            int row = mt * 16 + quad * 4 + r;
            if (row < m) {
                float w = w_s[row];
                float* prow = part + (size_t)tok_s[row] * DM;
#pragma unroll
                for (int nt = 0; nt < 8; nt++) {
                    int col = (ng2 + nt) * 16 + lm;
                    prow[col] = w * (acc[nt][r] + b2[col]);
                }
            }
        }
    }
}

// ---------------- final reduce: out[n] = sum_s part[n*4+s] ----------------
__global__ void k_reduce(const float* __restrict__ part, float* __restrict__ out) {
    int n = blockIdx.x;
    int j = threadIdx.x; // 0..127
    const float4* p = (const float4*)(part + (size_t)n * 4 * DM);
    float4 a = p[j], b = p[128 + j], c = p[256 + j], d = p[384 + j];
    float4 r = make_float4(a.x + b.x + c.x + d.x, a.y + b.y + c.y + d.y,
                           a.z + b.z + c.z + d.z, a.w + b.w + c.w + d.w);
    ((float4*)(out + (size_t)n * DM))[j] = r;
}

extern "C" void kernel_launch(void* const* d_in, const int* in_sizes, int n_in,
                              void* d_out, int out_size, void* d_ws, size_t ws_size,
                              hipStream_t stream) {
    const float* hidden  = (const float*)d_in[0];
    const float* feat    = (const float*)d_in[1];
    const float* pre_g   = (const float*)d_in[2];
    const float* pre_b   = (const float*)d_in[3];
    const float* rh_g    = (const float*)d_in[4];
    const float* rh_b    = (const float*)d_in[5];
    const float* rh_w1   = (const float*)d_in[6];
    const float* rh_b1   = (const float*)d_in[7];
    const float* rh_w2   = (const float*)d_in[8];
    const float* rh_b2   = (const float*)d_in[9];
    const float* sf_g    = (const float*)d_in[10];
    const float* sf_b    = (const float*)d_in[11];
    const float* sf_w1   = (const float*)d_in[12];
    const float* sf_b1   = (const float*)d_in[13];
    const float* sf_w2   = (const float*)d_in[14];
    const float* sf_b2   = (const float*)d_in[15];
    const float* gln_g   = (const float*)d_in[16];
    const float* gln_b   = (const float*)d_in[17];
    const float* gf_w1   = (const float*)d_in[18];
    const float* gf_b1   = (const float*)d_in[19];
    const float* gf_w2   = (const float*)d_in[20];
    const float* gf_b2   = (const float*)d_in[21];
    const float* pgs_w1  = (const float*)d_in[22];
    const float* pgs_b1  = (const float*)d_in[23];
    const float* pgs_w2  = (const float*)d_in[24];
    const float* pgs_b2  = (const float*)d_in[25];
    const float* ir_w1   = (const float*)d_in[26];
    const float* ir_b1   = (const float*)d_in[27];
    const float* ir_w2   = (const float*)d_in[28];
    const float* ir_b2   = (const float*)d_in[29];
    const float* ex_w1   = (const float*)d_in[30];
    const float* ex_b1   = (const float*)d_in[31];
    const float* ex_w2   = (const float*)d_in[32];
    const float* ex_b2   = (const float*)d_in[33];
    float* out = (float*)d_out;

    // workspace carving (256B-aligned)
    char* w = (char*)d_ws;
    auto alloc = [&](size_t bytes) { void* r = (void*)w; w += (bytes + 255) & ~(size_t)255; return r; };
    __hip_bfloat16* h_normb = (__hip_bfloat16*)alloc((size_t)N_TOK * DM * 2);
    float* sL    = (float*)alloc((size_t)N_TOK * FDIM * 4);
    float* h_enc = (float*)alloc((size_t)N_TOK * DH * 4);
    float* s_enc = (float*)alloc((size_t)N_TOK * DH * 4);
    float* g_enc = (float*)alloc((size_t)N_TOK * G * DH * 4);
    float* glog  = (float*)alloc((size_t)N_TOK * G * 4);
    float* ilog  = (float*)alloc((size_t)N_TOK * G * ES * 4);
    float* wgts  = (float*)alloc((size_t)E_EXP * N_TOK * 4);
    short* wB1   = (short*)alloc((size_t)E_EXP * DM * DE * 2);
    short* wB2   = (short*)alloc((size_t)E_EXP * DE * DM * 2);
    short* AhsH  = (short*)alloc((size_t)N_TOK * 256 * 2);
    short* AhsM  = (short*)alloc((size_t)N_TOK * 256 * 2);
    short* AhsL  = (short*)alloc((size_t)N_TOK * 256 * 2);
    short* BpgH  = (short*)alloc((size_t)16 * 8 * 512 * 2);
    short* BpgM  = (short*)alloc((size_t)16 * 8 * 512 * 2);
    short* BpgL  = (short*)alloc((size_t)16 * 8 * 512 * 2);
    short* BirH  = (short*)alloc((size_t)G * 16 * 8 * 512 * 2);
    short* BirM  = (short*)alloc((size_t)G * 16 * 8 * 512 * 2);
    short* BirL  = (short*)alloc((size_t)G * 16 * 8 * 512 * 2);
    short* Brh1H = (short*)alloc((size_t)16 * 8 * 512 * 2);
    short* Brh1M = (short*)alloc((size_t)16 * 8 * 512 * 2);
    short* Brh1L = (short*)alloc((size_t)16 * 8 * 512 * 2);
    short* Brh2H = (short*)alloc((size_t)4 * 8 * 512 * 2);
    short* Brh2M = (short*)alloc((size_t)4 * 8 * 512 * 2);
    short* Brh2L = (short*)alloc((size_t)4 * 8 * 512 * 2);
    short* Bsf1H = (short*)alloc((size_t)4 * 8 * 512 * 2);
    short* Bsf1M = (short*)alloc((size_t)4 * 8 * 512 * 2);
    short* Bsf1L = (short*)alloc((size_t)4 * 8 * 512 * 2);
    short* Bsf2H = (short*)alloc((size_t)4 * 8 * 512 * 2);
    short* Bsf2M = (short*)alloc((size_t)4 * 8 * 512 * 2);
    short* Bsf2L = (short*)alloc((size_t)4 * 8 * 512 * 2);
    short* Bgf1H = (short*)alloc((size_t)G * 1 * 8 * 512 * 2);
    short* Bgf1M = (short*)alloc((size_t)G * 1 * 8 * 512 * 2);
    short* Bgf1L = (short*)alloc((size_t)G * 1 * 8 * 512 * 2);
    short* Bgf2H = (short*)alloc((size_t)G * 4 * 8 * 512 * 2);
    short* Bgf2M = (short*)alloc((size_t)G * 4 * 8 * 512 * 2);
    short* Bgf2L = (short*)alloc((size_t)G * 4 * 8 * 512 * 2);
    int* cnt     = (int*)alloc(E_EXP * 4);
    int* toks    = (int*)alloc((size_t)E_EXP * N_TOK * 4);
    // union region (disjoint live ranges, stream-ordered):
    //   hL   [k_ln_hidden -> k_enc2<16>]   8.4 MB
    //   part [k_expert_mfma -> k_reduce]  33.6 MB
    char* uni   = (char*)alloc((size_t)N_TOK * 4 * DM * 4); // 33.6 MB = max
    float* hL   = (float*)uni;
    float* part = (float*)uni;

    hipMemsetAsync(cnt, 0, E_EXP * sizeof(int), stream);

    // single fused weight-conversion launch (10 jobs)
    ConvJobs J;
    int b0 = 0;
    auto mkjob = [&](int i, const float* s, short* dh, short* dm, short* dl,
                     int KB, int NB, int Kreal, int plain, int nmat) {
        J.j[i] = ConvJob{s, dh, dm, dl, KB, NB, Kreal, plain, b0};
        b0 += KB * nmat;
    };
    mkjob(0, ex_w1, wB1, nullptr, nullptr, 16, 16, 512, 1, E_EXP);
    mkjob(1, ex_w2, wB2, nullptr, nullptr, 8, 32, 256, 1, E_EXP);
    mkjob(2, pgs_w1, BpgH, BpgM, BpgL, 16, 8, 512, 0, 1);
    mkjob(3, ir_w1, BirH, BirM, BirL, 16, 8, 512, 0, G);
    mkjob(4, rh_w1, Brh1H, Brh1M, Brh1L, 16, 8, 512, 0, 1);
    mkjob(5, rh_w2, Brh2H, Brh2M, Brh2L, 4, 8, 128, 0, 1);
    mkjob(6, sf_w1, Bsf1H, Bsf1M, Bsf1L, 4, 8, 128, 0, 1);
    mkjob(7, sf_w2, Bsf2H, Bsf2M, Bsf2L, 4, 8, 128, 0, 1);
    mkjob(8, gf_w1, Bgf1H, Bgf1M, Bgf1L, 1, 8, 16, 0, G);
    mkjob(9, gf_w2, Bgf2H, Bgf2M, Bgf2L, 4, 8, 128, 0, G);
    k_conv_all<<<b0, 256, 0, stream>>>(J);

    k_ln_hidden<<<N_TOK, 256, 0, stream>>>(hidden, pre_g, pre_b, rh_g, rh_b, h_normb, hL);
    k_ln_feat<<<N_TOK, 128, 0, stream>>>(feat, sf_g, sf_b, sL);

    // encoder MLPs via 3-split MFMA
    k_enc2_mfma<16><<<N_TOK / 32, 256, 0, stream>>>(hL, Brh1H, Brh1M, Brh1L, rh_b1,
                                                    Brh2H, Brh2M, Brh2L, rh_b2, h_enc);
    k_enc2_mfma<4><<<N_TOK / 32, 256, 0, stream>>>(sL, Bsf1H, Bsf1M, Bsf1L, sf_b1,
                                                   Bsf2H, Bsf2M, Bsf2L, sf_b2, s_enc);
    k_genc_mfma<<<N_TOK / 32, 256, 0, stream>>>(feat, gln_g, gln_b,
                                                Bgf1H, Bgf1M, Bgf1L, gf_b1,
                                                Bgf2H, Bgf2M, Bgf2L, gf_b2, g_enc);

    k_stage_hs<<<N_TOK / 16, 256, 0, stream>>>(h_enc, s_enc, AhsH, AhsM, AhsL);

    // router: single pass, all 8 groups; g-part staged in-kernel
    dim3 rgrid(N_TOK / 32, G);
    k_router_mfma<<<rgrid, 256, 0, stream>>>(AhsH, AhsM, AhsL, h_enc, g_enc,
                                             BpgH, BpgM, BpgL, BirH, BirM, BirL,
                                             pgs_b1, pgs_w2, pgs_b2, ir_b1, ir_w2, ir_b2,
                                             glog, ilog);

    k_topk<<<N_TOK / 256, 256, 0, stream>>>(glog, ilog, cnt, toks, wgts);
    // XCD-swizzled 1D expert grid: bid = slot*32 + e
    k_expert_mfma<<<(N_TOK / BT) * E_EXP, 512, 0, stream>>>(h_normb, wB1, ex_b1, wB2, ex_b2,
                                                            cnt, toks, wgts, part);
    k_reduce<<<N_TOK, 128, 0, stream>>>(part, out);
}

// Round 7
// 422.502 us; speedup vs baseline: 2.6218x; 1.0271x over previous
//
#include <hip/hip_runtime.h>
#include <hip/hip_bf16.h>
#include <math.h>

#define N_TOK 4096
#define DM 512
#define FDIM 128
#define G 8
#define FG 16
#define DH 128
#define DE 256
#define ES 4
#define E_EXP 32
#define LN_EPS 1e-5f
#define BT 32   // expert token tile (MFMA)

typedef __attribute__((ext_vector_type(8))) short bf16x8;  // 8 bf16 = 4 VGPRs
typedef __attribute__((ext_vector_type(4))) float f32x4;

#define MFMA16(a, b, c) __builtin_amdgcn_mfma_f32_16x16x32_bf16((a), (b), (c), 0, 0, 0)

__device__ __forceinline__ float gelu_t(float x) {
    const float c = 0.7978845608028654f; // sqrt(2/pi)
    float x3 = x * x * x;
    return 0.5f * x * (1.0f + tanhf(c * (x + 0.044715f * x3)));
}

__device__ __forceinline__ short f2bf(float f) {
    __hip_bfloat16 h = __float2bfloat16(f);
    return *reinterpret_cast<short*>(&h);
}
__device__ __forceinline__ float bf2f(short s) {
    __hip_bfloat16 h = *reinterpret_cast<__hip_bfloat16*>(&s);
    return __bfloat162float(h);
}
// exact 3-way split: x == bf2f(h)+bf2f(m)+bf2f(l) bit-exactly for fp32 x
__device__ __forceinline__ void split3(float x, short& h, short& m, short& l) {
    h = f2bf(x);
    float r = x - bf2f(h);   // exact in fp32
    m = f2bf(r);
    float r2 = r - bf2f(m);  // exact; <=6 significant bits remain
    l = f2bf(r2);            // exact
}

// ---------------- LN of hidden: pre_ln -> h_norm (bf16) and rh_ln -> hL (fp32) ----------------
__global__ void k_ln_hidden(const float* __restrict__ hidden,
                            const float* __restrict__ pg, const float* __restrict__ pb,
                            const float* __restrict__ rg, const float* __restrict__ rb,
                            __hip_bfloat16* __restrict__ h_normb, float* __restrict__ hL) {
    int n = blockIdx.x;
    int j = threadIdx.x; // 0..255
    const float* x = hidden + (size_t)n * DM;
    float v0 = x[j], v1 = x[j + 256];
    float s = v0 + v1, q = v0 * v0 + v1 * v1;
#pragma unroll
    for (int o = 32; o; o >>= 1) { s += __shfl_down(s, o); q += __shfl_down(q, o); }
    __shared__ float red[8];
    int w = j >> 6;
    if ((j & 63) == 0) { red[w] = s; red[4 + w] = q; }
    __syncthreads();
    float sum = red[0] + red[1] + red[2] + red[3];
    float sq  = red[4] + red[5] + red[6] + red[7];
    float m = sum * (1.0f / DM);
    float var = sq * (1.0f / DM) - m * m;
    float rs = rsqrtf(var + LN_EPS);
    float t0 = (v0 - m) * rs, t1 = (v1 - m) * rs;
    size_t base = (size_t)n * DM;
    h_normb[base + j]       = __float2bfloat16(t0 * pg[j]       + pb[j]);
    h_normb[base + j + 256] = __float2bfloat16(t1 * pg[j + 256] + pb[j + 256]);
    hL[base + j]           = t0 * rg[j]       + rb[j];
    hL[base + j + 256]     = t1 * rg[j + 256] + rb[j + 256];
}

// ---------------- unified weight conversion: plain bf16 or 3-way split, K zero-pad ----------------
struct ConvJob { const float* src; short* dh; short* dm; short* dl;
                 int KB, NB, Kreal, plain, blk0; };
struct ConvJobs { ConvJob j[10]; };

__global__ void k_conv_all(ConvJobs J) {
    int b = blockIdx.x;
    int ji = 0;
#pragma unroll
    for (int i = 1; i < 10; i++) if (b >= J.j[i].blk0) ji = i;
    const ConvJob jb = J.j[ji];
    int rel = b - jb.blk0;
    int mat = rel / jb.KB, kb = rel % jb.KB;
    int ncols = jb.NB * 16;
    const float* s = jb.src + (size_t)mat * jb.Kreal * ncols;
    size_t dbase = ((size_t)mat * jb.KB + kb) * jb.NB * 512;
    for (int p = threadIdx.x; p < jb.NB * 64; p += 256) {
        int nb = p >> 6, lane = p & 63;
        int row0 = kb * 32 + ((lane >> 4) << 3);
        int col = nb * 16 + (lane & 15);
        if (jb.plain) {
            union { short sh[8]; uint4 v; } t;
#pragma unroll
            for (int j = 0; j < 8; j++) {
                float x = (row0 + j < jb.Kreal) ? s[(size_t)(row0 + j) * ncols + col] : 0.f;
                t.sh[j] = f2bf(x);
            }
            *(uint4*)&jb.dh[dbase + (size_t)p * 8] = t.v;
        } else {
            union { short sh[8]; uint4 v; } hi, mi, lo;
#pragma unroll
            for (int j = 0; j < 8; j++) {
                float x = (row0 + j < jb.Kreal) ? s[(size_t)(row0 + j) * ncols + col] : 0.f;
                split3(x, hi.sh[j], mi.sh[j], lo.sh[j]);
            }
            *(uint4*)&jb.dh[dbase + (size_t)p * 8] = hi.v;
            *(uint4*)&jb.dm[dbase + (size_t)p * 8] = mi.v;
            *(uint4*)&jb.dl[dbase + (size_t)p * 8] = lo.v;
        }
    }
}

// ---------------- 2-layer MLP via 3-split MFMA: Y = gelu(LN?(X)@W1+b1)@W2+b2 ----------------
// DO_LN (requires KB_TOT==4, K=128): apply LayerNorm(lng,lnb) to each row during staging.
template <int KB_TOT, bool DO_LN>
__global__ __launch_bounds__(256) void k_enc2_mfma(
        const float* __restrict__ X,
        const float* __restrict__ lng, const float* __restrict__ lnb,
        const short* __restrict__ W1h, const short* __restrict__ W1m, const short* __restrict__ W1l,
        const float* __restrict__ B1,
        const short* __restrict__ W2h, const short* __restrict__ W2m, const short* __restrict__ W2l,
        const float* __restrict__ B2,
        float* __restrict__ Y) {
    constexpr int K = KB_TOT * 32;
    constexpr int NCHUNK = KB_TOT / 4;
    const int n0 = blockIdx.x * 32;
    const int tid = threadIdx.x;
    const int wave = tid >> 6, lane = tid & 63;
    const int quad = lane >> 4, lm = lane & 15;
    const int mt = wave & 1;
    const int ngb = (wave >> 1) * 4;   // 4 n-tiles per wave

    __shared__ short Ah[32][132], Am[32][132], Al[32][132];

    f32x4 acc[4];
#pragma unroll
    for (int i = 0; i < 4; i++) acc[i] = (f32x4)(0.f);

    for (int ch = 0; ch < NCHUNK; ch++) {
        __syncthreads();
        for (int idx = tid; idx < 1024; idx += 256) {
            int row = idx >> 5, c4 = (idx & 31) * 4;
            float4 v = *(const float4*)&X[(size_t)(n0 + row) * K + ch * 128 + c4];
            if (DO_LN) {
                // 32 contiguous tids own one row (half-wave); reduce within 32 lanes
                float s = v.x + v.y + v.z + v.w;
                float q = v.x * v.x + v.y * v.y + v.z * v.z + v.w * v.w;
#pragma unroll
                for (int o = 16; o; o >>= 1) { s += __shfl_xor(s, o); q += __shfl_xor(q, o); }
                float mean = s * (1.0f / 128.0f);
                float var = q * (1.0f / 128.0f) - mean * mean;
                float rs = rsqrtf(var + LN_EPS);
                v.x = (v.x - mean) * rs * lng[c4 + 0] + lnb[c4 + 0];
                v.y = (v.y - mean) * rs * lng[c4 + 1] + lnb[c4 + 1];
                v.z = (v.z - mean) * rs * lng[c4 + 2] + lnb[c4 + 2];
                v.w = (v.w - mean) * rs * lng[c4 + 3] + lnb[c4 + 3];
            }
            float xv[4] = {v.x, v.y, v.z, v.w};
#pragma unroll
            for (int j = 0; j < 4; j++) {
                short h, m, l; split3(xv[j], h, m, l);
                Ah[row][c4 + j] = h; Am[row][c4 + j] = m; Al[row][c4 + j] = l;
            }
        }
        __syncthreads();
#pragma unroll
        for (int kb = 0; kb < 4; kb++) {
            int kbg = ch * 4 + kb;
            bf16x8 ah = *(const bf16x8*)&Ah[mt * 16 + lm][kb * 32 + quad * 8];
            bf16x8 am = *(const bf16x8*)&Am[mt * 16 + lm][kb * 32 + quad * 8];
            bf16x8 al = *(const bf16x8*)&Al[mt * 16 + lm][kb * 32 + quad * 8];
#pragma unroll
            for (int nt = 0; nt < 4; nt++) {
                size_t bi = (((size_t)kbg * 8 + ngb + nt) * 64 + lane) * 8;
                bf16x8 bh = *(const bf16x8*)&W1h[bi];
                bf16x8 bm = *(const bf16x8*)&W1m[bi];
                bf16x8 bl = *(const bf16x8*)&W1l[bi];
                acc[nt] = MFMA16(al, bh, acc[nt]);
                acc[nt] = MFMA16(am, bm, acc[nt]);
                acc[nt] = MFMA16(ah, bl, acc[nt]);
                acc[nt] = MFMA16(am, bh, acc[nt]);
                acc[nt] = MFMA16(ah, bm, acc[nt]);
                acc[nt] = MFMA16(ah, bh, acc[nt]);
            }
        }
    }
    __syncthreads();
#pragma unroll
    for (int nt = 0; nt < 4; nt++) {
        int col = (ngb + nt) * 16 + lm;
        float b1 = B1[col];
#pragma unroll
        for (int r = 0; r < 4; r++) {
            int row = mt * 16 + quad * 4 + r;
            short h, m, l; split3(gelu_t(acc[nt][r] + b1), h, m, l);
            Ah[row][col] = h; Am[row][col] = m; Al[row][col] = l;
        }
    }
    __syncthreads();
    f32x4 acc2[4];
#pragma unroll
    for (int i = 0; i < 4; i++) acc2[i] = (f32x4)(0.f);
#pragma unroll
    for (int kb = 0; kb < 4; kb++) {
        bf16x8 ah = *(const bf16x8*)&Ah[mt * 16 + lm][kb * 32 + quad * 8];
        bf16x8 am = *(const bf16x8*)&Am[mt * 16 + lm][kb * 32 + quad * 8];
        bf16x8 al = *(const bf16x8*)&Al[mt * 16 + lm][kb * 32 + quad * 8];
#pragma unroll
        for (int nt = 0; nt < 4; nt++) {
            size_t bi = (((size_t)kb * 8 + ngb + nt) * 64 + lane) * 8;
            bf16x8 bh = *(const bf16x8*)&W2h[bi];
            bf16x8 bm = *(const bf16x8*)&W2m[bi];
            bf16x8 bl = *(const bf16x8*)&W2l[bi];
            acc2[nt] = MFMA16(al, bh, acc2[nt]);
            acc2[nt] = MFMA16(am, bm, acc2[nt]);
            acc2[nt] = MFMA16(ah, bl, acc2[nt]);
            acc2[nt] = MFMA16(am, bh, acc2[nt]);
            acc2[nt] = MFMA16(ah, bm, acc2[nt]);
            acc2[nt] = MFMA16(ah, bh, acc2[nt]);
        }
    }
#pragma unroll
    for (int nt = 0; nt < 4; nt++) {
        int col = (ngb + nt) * 16 + lm;
        float b2 = B2[col];
#pragma unroll
        for (int r = 0; r < 4; r++) {
            int row = mt * 16 + quad * 4 + r;
            Y[(size_t)(n0 + row) * DH + col] = acc2[nt][r] + b2;
        }
    }
}

// ---------------- group encoders via 3-split MFMA ----------------
__global__ __launch_bounds__(256) void k_genc_mfma(
        const float* __restrict__ feat,
        const float* __restrict__ gln_g, const float* __restrict__ gln_b,
        const short* __restrict__ W1h, const short* __restrict__ W1m, const short* __restrict__ W1l,
        const float* __restrict__ gb1,
        const short* __restrict__ W2h, const short* __restrict__ W2m, const short* __restrict__ W2l,
        const float* __restrict__ gb2,
        float* __restrict__ g_enc) {
    const int n0 = blockIdx.x * 32;
    const int tid = threadIdx.x;
    const int wave = tid >> 6, lane = tid & 63;
    const int quad = lane >> 4, lm = lane & 15;
    const int mt = wave & 1;
    const int ngb = (wave >> 1) * 4;

    __shared__ short A1h[32][132], A1m[32][132], A1l[32][132];
    __shared__ short A2h[32][132], A2m[32][132], A2l[32][132];

    for (int half = 0; half < 2; half++) {
        __syncthreads();
        {
            int t = tid >> 3, sub = tid & 7, gl = sub >> 1, eo = sub & 1;
            int g = half * 4 + gl;
            const float* fr = feat + (size_t)(n0 + t) * FDIM + g * FG;
            float xv[FG];
            float mean = 0.f;
#pragma unroll
            for (int i = 0; i < FG; i++) { xv[i] = fr[i]; mean += xv[i]; }
            mean *= (1.0f / FG);
            float var = 0.f;
#pragma unroll
            for (int i = 0; i < FG; i++) { float d = xv[i] - mean; var += d * d; }
            var *= (1.0f / FG);
            float rs = rsqrtf(var + LN_EPS);
            for (int i = eo * 8; i < eo * 8 + 8; i++) {
                float xn = (xv[i] - mean) * rs * gln_g[g * FG + i] + gln_b[g * FG + i];
                short h, m, l; split3(xn, h, m, l);
                A1h[t][gl * 32 + i] = h; A1m[t][gl * 32 + i] = m; A1l[t][gl * 32 + i] = l;
                A1h[t][gl * 32 + 16 + i] = 0; A1m[t][gl * 32 + 16 + i] = 0; A1l[t][gl * 32 + 16 + i] = 0;
            }
        }
        __syncthreads();
        for (int gl = 0; gl < 4; gl++) {
            int g = half * 4 + gl;
            bf16x8 ah = *(const bf16x8*)&A1h[mt * 16 + lm][gl * 32 + quad * 8];
            bf16x8 am = *(const bf16x8*)&A1m[mt * 16 + lm][gl * 32 + quad * 8];
            bf16x8 al = *(const bf16x8*)&A1l[mt * 16 + lm][gl * 32 + quad * 8];
            f32x4 acc[4];
#pragma unroll
            for (int i = 0; i < 4; i++) acc[i] = (f32x4)(0.f);
#pragma unroll
            for (int nt = 0; nt < 4; nt++) {
                size_t bi = (((size_t)g * 8 + ngb + nt) * 64 + lane) * 8;
                bf16x8 bh = *(const bf16x8*)&W1h[bi];
                bf16x8 bm = *(const bf16x8*)&W1m[bi];
                bf16x8 bl = *(const bf16x8*)&W1l[bi];
                acc[nt] = MFMA16(al, bh, acc[nt]);
                acc[nt] = MFMA16(am, bm, acc[nt]);
                acc[nt] = MFMA16(ah, bl, acc[nt]);
                acc[nt] = MFMA16(am, bh, acc[nt]);
                acc[nt] = MFMA16(ah, bm, acc[nt]);
                acc[nt] = MFMA16(ah, bh, acc[nt]);
            }
            __syncthreads();
#pragma unroll
            for (int nt = 0; nt < 4; nt++) {
                int col = (ngb + nt) * 16 + lm;
                float b1 = gb1[g * DH + col];
#pragma unroll
                for (int r = 0; r < 4; r++) {
                    int row = mt * 16 + quad * 4 + r;
                    short h, m, l; split3(gelu_t(acc[nt][r] + b1), h, m, l);
                    A2h[row][col] = h; A2m[row][col] = m; A2l[row][col] = l;
                }
            }
            __syncthreads();
            f32x4 acc2[4];
#pragma unroll
            for (int i = 0; i < 4; i++) acc2[i] = (f32x4)(0.f);
#pragma unroll
            for (int kb = 0; kb < 4; kb++) {
                bf16x8 a2h = *(const bf16x8*)&A2h[mt * 16 + lm][kb * 32 + quad * 8];
                bf16x8 a2m = *(const bf16x8*)&A2m[mt * 16 + lm][kb * 32 + quad * 8];
                bf16x8 a2l = *(const bf16x8*)&A2l[mt * 16 + lm][kb * 32 + quad * 8];
#pragma unroll
                for (int nt = 0; nt < 4; nt++) {
                    size_t bi = ((((size_t)g * 4 + kb) * 8 + ngb + nt) * 64 + lane) * 8;
                    bf16x8 bh = *(const bf16x8*)&W2h[bi];
                    bf16x8 bm = *(const bf16x8*)&W2m[bi];
                    bf16x8 bl = *(const bf16x8*)&W2l[bi];
                    acc2[nt] = MFMA16(a2l, bh, acc2[nt]);
                    acc2[nt] = MFMA16(a2m, bm, acc2[nt]);
                    acc2[nt] = MFMA16(a2h, bl, acc2[nt]);
                    acc2[nt] = MFMA16(a2m, bh, acc2[nt]);
                    acc2[nt] = MFMA16(a2h, bm, acc2[nt]);
                    acc2[nt] = MFMA16(a2h, bh, acc2[nt]);
                }
            }
#pragma unroll
            for (int nt = 0; nt < 4; nt++) {
                int col = (ngb + nt) * 16 + lm;
                float b2 = gb2[g * DH + col];
#pragma unroll
                for (int r = 0; r < 4; r++) {
                    int row = mt * 16 + quad * 4 + r;
                    g_enc[((size_t)(n0 + row) * G + g) * DH + col] = acc2[nt][r] + b2;
                }
            }
        }
    }
}

// ---------------- stage A-fragments (3-way split bf16) for router k<256 (h|s) ----------------
__global__ void k_stage_hs(const float* __restrict__ h_enc, const float* __restrict__ s_enc,
                           short* __restrict__ Ah, short* __restrict__ Am, short* __restrict__ Al) {
    int T16 = blockIdx.x;
    for (int slot = threadIdx.x; slot < 512; slot += 256) {
        int kb = slot >> 6, lane = slot & 63;
        int quad = lane >> 4, lm = lane & 15;
        int n = T16 * 16 + lm;
        int c0 = kb * 32 + quad * 8; // 0..255
        const float* src = (c0 < 128) ? (h_enc + (size_t)n * DH + c0)
                                      : (s_enc + (size_t)n * DH + (c0 - 128));
        float4 x0 = *(const float4*)src;
        float4 x1 = *(const float4*)(src + 4);
        float xv[8] = {x0.x, x0.y, x0.z, x0.w, x1.x, x1.y, x1.z, x1.w};
        union { short sh[8]; uint4 v; } hi, mi, lo;
#pragma unroll
        for (int j = 0; j < 8; j++) split3(xv[j], hi.sh[j], mi.sh[j], lo.sh[j]);
        size_t base = ((size_t)T16 * 512 + slot) * 8;
        *(uint4*)&Ah[base] = hi.v;
        *(uint4*)&Am[base] = mi.v;
        *(uint4*)&Al[base] = lo.v;
    }
}

// ---------------- MFMA router: XCD-swizzled 1D grid (g = bid & 7 -> one group per XCD) ----------------
__global__ __launch_bounds__(256) void k_router_mfma(
        const short* __restrict__ AhsH, const short* __restrict__ AhsM, const short* __restrict__ AhsL,
        const float* __restrict__ h_enc, const float* __restrict__ g_enc,
        const short* __restrict__ BpgH, const short* __restrict__ BpgM, const short* __restrict__ BpgL,
        const short* __restrict__ BirH, const short* __restrict__ BirM, const short* __restrict__ BirL,
        const float* __restrict__ pb1, const float* __restrict__ pw2, const float* __restrict__ pb2,
        const float* __restrict__ ib1, const float* __restrict__ iw2, const float* __restrict__ ib2,
        float* __restrict__ glog, float* __restrict__ ilog) {
    const int g = blockIdx.x & 7;       // XCD id: all blocks of group g share one XCD's L2
    const int bx = blockIdx.x >> 3;     // 32-token tile
    const int tid = threadIdx.x;
    const int wave = tid >> 6, lane = tid & 63;
    const int quad = lane >> 4, lm = lane & 15;
    const bool is_pg = wave < 2;
    const int nbase = (wave & 1) * 4;          // 4 n-tiles per wave
    const short* Bh = is_pg ? BpgH : (BirH + (size_t)g * 65536);
    const short* Bm = is_pg ? BpgM : (BirM + (size_t)g * 65536);
    const short* Bl = is_pg ? BpgL : (BirL + (size_t)g * 65536);
    const int n0 = bx * 32;

    // LDS union: g-part 3-split staging (50688 B) then ph/ih epilogue (33024 B)
    __shared__ __align__(16) char smem[3 * 32 * 264 * 2];
    short (*Sh)[264] = (short(*)[264])smem;
    short (*Sm)[264] = (short(*)[264])(smem + 32 * 264 * 2);
    short (*Sl)[264] = (short(*)[264])(smem + 2 * 32 * 264 * 2);
    float (*ph)[129] = (float(*)[129])smem;
    float (*ih)[129] = (float(*)[129])(smem + 32 * 129 * 4);

    // stage g-part: k in [0,256) = [g_enc | h_enc*g_enc], split3 into LDS
    for (int idx = tid; idx < 32 * 64; idx += 256) {
        int row = idx >> 6, c4 = (idx & 63) * 4;
        int n = n0 + row;
        float4 v;
        if (c4 < 128) {
            v = *(const float4*)&g_enc[((size_t)n * G + g) * DH + c4];
        } else {
            int c = c4 - 128;
            float4 gv = *(const float4*)&g_enc[((size_t)n * G + g) * DH + c];
            float4 hv = *(const float4*)&h_enc[(size_t)n * DH + c];
            v = make_float4(gv.x * hv.x, gv.y * hv.y, gv.z * hv.z, gv.w * hv.w);
        }
        float xv[4] = {v.x, v.y, v.z, v.w};
        union { short sh[4]; uint2 u; } hi, mi, lo;
#pragma unroll
        for (int j = 0; j < 4; j++) split3(xv[j], hi.sh[j], mi.sh[j], lo.sh[j]);
        *(uint2*)&Sh[row][c4] = hi.u;
        *(uint2*)&Sm[row][c4] = mi.u;
        *(uint2*)&Sl[row][c4] = lo.u;
    }
    __syncthreads();

    f32x4 acc[2][4];
#pragma unroll
    for (int mt = 0; mt < 2; mt++)
#pragma unroll
        for (int nt = 0; nt < 4; nt++) acc[mt][nt] = (f32x4)(0.f);

    for (int kb = 0; kb < 16; kb++) {
        bf16x8 Ahf[2], Amf[2], Alf[2];
#pragma unroll
        for (int mt = 0; mt < 2; mt++) {
            if (kb < 8) {
                size_t ai = (((size_t)(2 * bx + mt) * 8 + kb) * 64 + lane) * 8;
                Ahf[mt] = *(const bf16x8*)&AhsH[ai];
                Amf[mt] = *(const bf16x8*)&AhsM[ai];
                Alf[mt] = *(const bf16x8*)&AhsL[ai];
            } else {
                int row = mt * 16 + lm, c = (kb - 8) * 32 + quad * 8;
                Ahf[mt] = *(const bf16x8*)&Sh[row][c];
                Amf[mt] = *(const bf16x8*)&Sm[row][c];
                Alf[mt] = *(const bf16x8*)&Sl[row][c];
            }
        }
#pragma unroll
        for (int nt = 0; nt < 4; nt++) {
            int nb = nbase + nt;
            size_t bi = (((size_t)kb * 8 + nb) * 64 + lane) * 8;
            bf16x8 bh = *(const bf16x8*)&Bh[bi];
            bf16x8 bm = *(const bf16x8*)&Bm[bi];
            bf16x8 bl = *(const bf16x8*)&Bl[bi];
#pragma unroll
            for (int mt = 0; mt < 2; mt++) {
                acc[mt][nt] = MFMA16(Alf[mt], bh, acc[mt][nt]);
                acc[mt][nt] = MFMA16(Amf[mt], bm, acc[mt][nt]);
                acc[mt][nt] = MFMA16(Ahf[mt], bl, acc[mt][nt]);
                acc[mt][nt] = MFMA16(Amf[mt], bh, acc[mt][nt]);
                acc[mt][nt] = MFMA16(Ahf[mt], bm, acc[mt][nt]);
                acc[mt][nt] = MFMA16(Ahf[mt], bh, acc[mt][nt]);
            }
        }
    }
    __syncthreads();   // all waves done reading S before ph/ih overwrite

    float* dst = is_pg ? &ph[0][0] : &ih[0][0];
#pragma unroll
    for (int mt = 0; mt < 2; mt++)
#pragma unroll
    for (int nt = 0; nt < 4; nt++) {
        int col = (wave & 1) * 64 + nt * 16 + lm;
        float b1 = is_pg ? pb1[col] : ib1[g * DH + col];
#pragma unroll
        for (int r = 0; r < 4; r++) {
            int row = mt * 16 + quad * 4 + r;
            dst[row * 129 + col] = gelu_t(acc[mt][nt][r] + b1);
        }
    }
    __syncthreads();

    if (tid < 32) {
        float s = pb2[0];
        for (int i = 0; i < DH; i++) s += ph[tid][i] * pw2[i];
        glog[(size_t)(n0 + tid) * G + g] = s; // TEMP = 1.0
    } else if (tid >= 128) {
        int t = (tid - 128) >> 2, e = (tid - 128) & 3;
        float s = ib2[g * ES + e];
        const float* w = iw2 + (size_t)g * DH * ES;
        for (int i = 0; i < DH; i++) s += ih[t][i] * w[i * ES + e];
        ilog[((size_t)(n0 + t) * G + g) * ES + e] = s;
    }
}

// ---------------- top-k softmax + dispatch to per-expert lists ----------------
__global__ void k_topk(const float* __restrict__ glog, const float* __restrict__ ilog,
                       int* __restrict__ cnt, int* __restrict__ toks, float* __restrict__ wgts) {
    int n = blockIdx.x * blockDim.x + threadIdx.x;
    if (n >= N_TOK) return;
    float gl[G];
#pragma unroll
    for (int g = 0; g < G; g++) gl[g] = glog[(size_t)n * G + g];
    int i1 = 0; float v1 = gl[0];
#pragma unroll
    for (int g = 1; g < G; g++) if (gl[g] > v1) { v1 = gl[g]; i1 = g; }
    int i2 = -1; float v2 = -1e30f;
#pragma unroll
    for (int g = 0; g < G; g++) if (g != i1 && gl[g] > v2) { v2 = gl[g]; i2 = g; }
    float eg = expf(v2 - v1);
    float den = 1.0f / (1.0f + eg);
    float gw_sel[2] = { den, eg * den };
    int g_sel[2] = { i1, i2 };
#pragma unroll
    for (int s = 0; s < 2; s++) {
        int g = g_sel[s]; float gw = gw_sel[s];
        float il[ES];
#pragma unroll
        for (int e = 0; e < ES; e++) il[e] = ilog[((size_t)n * G + g) * ES + e];
        int j1 = 0; float u1 = il[0];
#pragma unroll
        for (int e = 1; e < ES; e++) if (il[e] > u1) { u1 = il[e]; j1 = e; }
        int j2 = -1; float u2 = -1e30f;
#pragma unroll
        for (int e = 0; e < ES; e++) if (e != j1 && il[e] > u2) { u2 = il[e]; j2 = e; }
        float ei = expf(u2 - u1);
        float d2 = 1.0f / (1.0f + ei);
        int ex1 = g * ES + j1, ex2 = g * ES + j2;
        int p1 = atomicAdd(&cnt[ex1], 1);
        toks[(size_t)ex1 * N_TOK + p1] = n * 4 + s * 2;     wgts[(size_t)ex1 * N_TOK + p1] = gw * d2;
        int p2 = atomicAdd(&cnt[ex2], 1);
        toks[(size_t)ex2 * N_TOK + p2] = n * 4 + s * 2 + 1; wgts[(size_t)ex2 * N_TOK + p2] = gw * ei * d2;
    }
}

// ---------------- sparse expert MLPs via bf16 MFMA; XCD-swizzled, no duplicate B reads ----------------
// bid = slot*32 + e  =>  bid % 8 == e % 8: all blocks of expert e land on one XCD.
// Each wave covers both m-tiles in-register -> every B fragment loaded exactly once per block.
__global__ __launch_bounds__(512) void k_expert_mfma(
        const __hip_bfloat16* __restrict__ h_normb,
        const short* __restrict__ wB1, const float* __restrict__ eb1,
        const short* __restrict__ wB2, const float* __restrict__ eb2,
        const int* __restrict__ cnt, const int* __restrict__ toks,
        const float* __restrict__ wgts, float* __restrict__ part) {
    const int e = blockIdx.x & 31;
    const int slot = blockIdx.x >> 5;
    const int c = cnt[e];
    const int start = slot * BT;
    if (start >= c) return;
    const int m = min(BT, c - start);

    __shared__ short hs[BT][520];
    __shared__ short es[BT][264];
    __shared__ int   tok_s[BT];
    __shared__ float w_s[BT];

    const int tid = threadIdx.x;
    if (tid < BT) {
        bool ok = tid < m;
        tok_s[tid] = ok ? toks[(size_t)e * N_TOK + start + tid] : 0;
        w_s[tid]   = ok ? wgts[(size_t)e * N_TOK + start + tid] : 0.f;
    }
    __syncthreads();
    for (int idx = tid; idx < BT * 64; idx += 512) {
        int t = idx >> 6, ch = idx & 63;
        uint4 v = make_uint4(0, 0, 0, 0);
        if (t < m) v = *((const uint4*)(h_normb + (size_t)(tok_s[t] >> 2) * DM) + ch);
        *(uint4*)&hs[t][ch * 8] = v;
    }
    __syncthreads();

    const int wave = tid >> 6, lane = tid & 63;
    const int quad = lane >> 4, lm = lane & 15;

    // ---- phase 1: es = gelu(hs @ W1 + b1), 32x256; 8 waves x 2 n-tiles x both mt ----
    {
        const int ng = wave * 2;
        f32x4 acc[2][2];
#pragma unroll
        for (int a = 0; a < 2; a++)
#pragma unroll
            for (int b = 0; b < 2; b++) acc[a][b] = (f32x4)(0.f);
        const short* w1e = wB1 + (size_t)e * DM * DE;
        for (int kb = 0; kb < 16; kb++) {
            bf16x8 a0 = *(const bf16x8*)&hs[lm][kb * 32 + quad * 8];
            bf16x8 a1 = *(const bf16x8*)&hs[16 + lm][kb * 32 + quad * 8];
            const short* wp = w1e + ((size_t)kb * 16 + ng) * 512 + lane * 8;
#pragma unroll
            for (int nt = 0; nt < 2; nt++) {
                bf16x8 b = *(const bf16x8*)(wp + nt * 512);
                acc[0][nt] = MFMA16(a0, b, acc[0][nt]);
                acc[1][nt] = MFMA16(a1, b, acc[1][nt]);
            }
        }
#pragma unroll
        for (int nt = 0; nt < 2; nt++) {
            int col = (ng + nt) * 16 + lm;
            float b1 = eb1[e * DE + col];
#pragma unroll
            for (int mt = 0; mt < 2; mt++)
#pragma unroll
            for (int r = 0; r < 4; r++) {
                int row = mt * 16 + quad * 4 + r;
                es[row][col] = f2bf(gelu_t(acc[mt][nt][r] + b1));
            }
        }
    }
    __syncthreads();

    // ---- phase 2: part[tok] = w * (es @ W2 + b2), 32x512; 8 waves x 4 n-tiles x both mt ----
    {
        const int ng2 = wave * 4;
        f32x4 acc[2][4];
#pragma unroll
        for (int a = 0; a < 2; a++)
#pragma unroll
            for (int b = 0; b < 4; b++) acc[a][b] = (f32x4)(0.f);
        const short* w2e = wB2 + (size_t)e * DE * DM;
        for (int kb = 0; kb < 8; kb++) {
            bf16x8 a0 = *(const bf16x8*)&es[lm][kb * 32 + quad * 8];
            bf16x8 a1 = *(const bf16x8*)&es[16 + lm][kb * 32 + quad * 8];
            const short* wp = w2e + ((size_t)kb * 32 + ng2) * 512 + lane * 8;
#pragma unroll
            for (int nt = 0; nt < 4; nt++) {
                bf16x8 b = *(const bf16x8*)(wp + nt * 512);
                acc[0][nt] = MFMA16(a0, b, acc[0][nt]);
                acc[1][nt] = MFMA16(a1, b, acc[1][nt]);
            }
        }
        const float* b2 = eb2 + (size_t)e * DM;
#pragma unroll
        for (int mt = 0; mt < 2; mt++)
#pragma unroll
        for (int r = 0; r < 4; r++) {
            int row = mt * 16 + quad * 4 + r;
            if (row < m) {
                float w = w_s[row];
                float* prow = part + (size_t)tok_s[row] * DM;
#pragma unroll
                for (int nt = 0; nt < 4; nt++) {
                    int col = (ng2 + nt) * 16 + lm;
                    prow[col] = w * (acc[mt][nt][r] + b2[col]);
                }
            }
        }
    }
}

// ---------------- final reduce: out[n] = sum_s part[n*4+s] ----------------
__global__ void k_reduce(const float* __restrict__ part, float* __restrict__ out) {
    int n = blockIdx.x;
    int j = threadIdx.x; // 0..127
    const float4* p = (const float4*)(part + (size_t)n * 4 * DM);
    float4 a = p[j], b = p[128 + j], c = p[256 + j], d = p[384 + j];
    float4 r = make_float4(a.x + b.x + c.x + d.x, a.y + b.y + c.y + d.y,
                           a.z + b.z + c.z + d.z, a.w + b.w + c.w + d.w);
    ((float4*)(out + (size_t)n * DM))[j] = r;
}

extern "C" void kernel_launch(void* const* d_in, const int* in_sizes, int n_in,
                              void* d_out, int out_size, void* d_ws, size_t ws_size,
                              hipStream_t stream) {
    const float* hidden  = (const float*)d_in[0];
    const float* feat    = (const float*)d_in[1];
    const float* pre_g   = (const float*)d_in[2];
    const float* pre_b   = (const float*)d_in[3];
    const float* rh_g    = (const float*)d_in[4];
    const float* rh_b    = (const float*)d_in[5];
    const float* rh_w1   = (const float*)d_in[6];
    const float* rh_b1   = (const float*)d_in[7];
    const float* rh_w2   = (const float*)d_in[8];
    const float* rh_b2   = (const float*)d_in[9];
    const float* sf_g    = (const float*)d_in[10];
    const float* sf_b    = (const float*)d_in[11];
    const float* sf_w1   = (const float*)d_in[12];
    const float* sf_b1   = (const float*)d_in[13];
    const float* sf_w2   = (const float*)d_in[14];
    const float* sf_b2   = (const float*)d_in[15];
    const float* gln_g   = (const float*)d_in[16];
    const float* gln_b   = (const float*)d_in[17];
    const float* gf_w1   = (const float*)d_in[18];
    const float* gf_b1   = (const float*)d_in[19];
    const float* gf_w2   = (const float*)d_in[20];
    const float* gf_b2   = (const float*)d_in[21];
    const float* pgs_w1  = (const float*)d_in[22];
    const float* pgs_b1  = (const float*)d_in[23];
    const float* pgs_w2  = (const float*)d_in[24];
    const float* pgs_b2  = (const float*)d_in[25];
    const float* ir_w1   = (const float*)d_in[26];
    const float* ir_b1   = (const float*)d_in[27];
    const float* ir_w2   = (const float*)d_in[28];
    const float* ir_b2   = (const float*)d_in[29];
    const float* ex_w1   = (const float*)d_in[30];
    const float* ex_b1   = (const float*)d_in[31];
    const float* ex_w2   = (const float*)d_in[32];
    const float* ex_b2   = (const float*)d_in[33];
    float* out = (float*)d_out;

    // workspace carving (256B-aligned)
    char* w = (char*)d_ws;
    auto alloc = [&](size_t bytes) { void* r = (void*)w; w += (bytes + 255) & ~(size_t)255; return r; };
    __hip_bfloat16* h_normb = (__hip_bfloat16*)alloc((size_t)N_TOK * DM * 2);
    float* h_enc = (float*)alloc((size_t)N_TOK * DH * 4);
    float* s_enc = (float*)alloc((size_t)N_TOK * DH * 4);
    float* g_enc = (float*)alloc((size_t)N_TOK * G * DH * 4);
    float* glog  = (float*)alloc((size_t)N_TOK * G * 4);
    float* ilog  = (float*)alloc((size_t)N_TOK * G * ES * 4);
    float* wgts  = (float*)alloc((size_t)E_EXP * N_TOK * 4);
    short* wB1   = (short*)alloc((size_t)E_EXP * DM * DE * 2);
    short* wB2   = (short*)alloc((size_t)E_EXP * DE * DM * 2);
    short* AhsH  = (short*)alloc((size_t)N_TOK * 256 * 2);
    short* AhsM  = (short*)alloc((size_t)N_TOK * 256 * 2);
    short* AhsL  = (short*)alloc((size_t)N_TOK * 256 * 2);
    short* BpgH  = (short*)alloc((size_t)16 * 8 * 512 * 2);
    short* BpgM  = (short*)alloc((size_t)16 * 8 * 512 * 2);
    short* BpgL  = (short*)alloc((size_t)16 * 8 * 512 * 2);
    short* BirH  = (short*)alloc((size_t)G * 16 * 8 * 512 * 2);
    short* BirM  = (short*)alloc((size_t)G * 16 * 8 * 512 * 2);
    short* BirL  = (short*)alloc((size_t)G * 16 * 8 * 512 * 2);
    short* Brh1H = (short*)alloc((size_t)16 * 8 * 512 * 2);
    short* Brh1M = (short*)alloc((size_t)16 * 8 * 512 * 2);
    short* Brh1L = (short*)alloc((size_t)16 * 8 * 512 * 2);
    short* Brh2H = (short*)alloc((size_t)4 * 8 * 512 * 2);
    short* Brh2M = (short*)alloc((size_t)4 * 8 * 512 * 2);
    short* Brh2L = (short*)alloc((size_t)4 * 8 * 512 * 2);
    short* Bsf1H = (short*)alloc((size_t)4 * 8 * 512 * 2);
    short* Bsf1M = (short*)alloc((size_t)4 * 8 * 512 * 2);
    short* Bsf1L = (short*)alloc((size_t)4 * 8 * 512 * 2);
    short* Bsf2H = (short*)alloc((size_t)4 * 8 * 512 * 2);
    short* Bsf2M = (short*)alloc((size_t)4 * 8 * 512 * 2);
    short* Bsf2L = (short*)alloc((size_t)4 * 8 * 512 * 2);
    short* Bgf1H = (short*)alloc((size_t)G * 1 * 8 * 512 * 2);
    short* Bgf1M = (short*)alloc((size_t)G * 1 * 8 * 512 * 2);
    short* Bgf1L = (short*)alloc((size_t)G * 1 * 8 * 512 * 2);
    short* Bgf2H = (short*)alloc((size_t)G * 4 * 8 * 512 * 2);
    short* Bgf2M = (short*)alloc((size_t)G * 4 * 8 * 512 * 2);
    short* Bgf2L = (short*)alloc((size_t)G * 4 * 8 * 512 * 2);
    int* cnt     = (int*)alloc(E_EXP * 4);
    int* toks    = (int*)alloc((size_t)E_EXP * N_TOK * 4);
    // union region (disjoint live ranges, stream-ordered):
    //   hL   [k_ln_hidden -> k_enc2<16>]   8.4 MB
    //   part [k_expert_mfma -> k_reduce]  33.6 MB
    char* uni   = (char*)alloc((size_t)N_TOK * 4 * DM * 4); // 33.6 MB = max
    float* hL   = (float*)uni;
    float* part = (float*)uni;

    hipMemsetAsync(cnt, 0, E_EXP * sizeof(int), stream);

    // single fused weight-conversion launch (10 jobs)
    ConvJobs J;
    int b0 = 0;
    auto mkjob = [&](int i, const float* s, short* dh, short* dm, short* dl,
                     int KB, int NB, int Kreal, int plain, int nmat) {
        J.j[i] = ConvJob{s, dh, dm, dl, KB, NB, Kreal, plain, b0};
        b0 += KB * nmat;
    };
    mkjob(0, ex_w1, wB1, nullptr, nullptr, 16, 16, 512, 1, E_EXP);
    mkjob(1, ex_w2, wB2, nullptr, nullptr, 8, 32, 256, 1, E_EXP);
    mkjob(2, pgs_w1, BpgH, BpgM, BpgL, 16, 8, 512, 0, 1);
    mkjob(3, ir_w1, BirH, BirM, BirL, 16, 8, 512, 0, G);
    mkjob(4, rh_w1, Brh1H, Brh1M, Brh1L, 16, 8, 512, 0, 1);
    mkjob(5, rh_w2, Brh2H, Brh2M, Brh2L, 4, 8, 128, 0, 1);
    mkjob(6, sf_w1, Bsf1H, Bsf1M, Bsf1L, 4, 8, 128, 0, 1);
    mkjob(7, sf_w2, Bsf2H, Bsf2M, Bsf2L, 4, 8, 128, 0, 1);
    mkjob(8, gf_w1, Bgf1H, Bgf1M, Bgf1L, 1, 8, 16, 0, G);
    mkjob(9, gf_w2, Bgf2H, Bgf2M, Bgf2L, 4, 8, 128, 0, G);
    k_conv_all<<<b0, 256, 0, stream>>>(J);

    k_ln_hidden<<<N_TOK, 256, 0, stream>>>(hidden, pre_g, pre_b, rh_g, rh_b, h_normb, hL);

    // encoder MLPs via 3-split MFMA (sf path: LN fused in-kernel)
    k_enc2_mfma<16, false><<<N_TOK / 32, 256, 0, stream>>>(hL, nullptr, nullptr,
                                                    Brh1H, Brh1M, Brh1L, rh_b1,
                                                    Brh2H, Brh2M, Brh2L, rh_b2, h_enc);
    k_enc2_mfma<4, true><<<N_TOK / 32, 256, 0, stream>>>(feat, sf_g, sf_b,
                                                   Bsf1H, Bsf1M, Bsf1L, sf_b1,
                                                   Bsf2H, Bsf2M, Bsf2L, sf_b2, s_enc);
    k_genc_mfma<<<N_TOK / 32, 256, 0, stream>>>(feat, gln_g, gln_b,
                                                Bgf1H, Bgf1M, Bgf1L, gf_b1,
                                                Bgf2H, Bgf2M, Bgf2L, gf_b2, g_enc);

    k_stage_hs<<<N_TOK / 16, 256, 0, stream>>>(h_enc, s_enc, AhsH, AhsM, AhsL);

    // router: XCD-swizzled 1D grid (bid&7 = group = XCD)
    k_router_mfma<<<(N_TOK / 32) * G, 256, 0, stream>>>(AhsH, AhsM, AhsL, h_enc, g_enc,
                                             BpgH, BpgM, BpgL, BirH, BirM, BirL,
                                             pgs_b1, pgs_w2, pgs_b2, ir_b1, ir_w2, ir_b2,
                                             glog, ilog);

    k_topk<<<N_TOK / 256, 256, 0, stream>>>(glog, ilog, cnt, toks, wgts);
    // XCD-swizzled 1D expert grid: bid = slot*32 + e
    k_expert_mfma<<<(N_TOK / BT) * E_EXP, 512, 0, stream>>>(h_normb, wB1, ex_b1, wB2, ex_b2,
                                                            cnt, toks, wgts, part);
    k_reduce<<<N_TOK, 128, 0, stream>>>(part, out);
}

// Round 8
// 390.169 us; speedup vs baseline: 2.8390x; 1.0829x over previous
//
#include <hip/hip_runtime.h>
#include <hip/hip_bf16.h>
#include <math.h>

#define N_TOK 4096
#define DM 512
#define FDIM 128
#define G 8
#define FG 16
#define DH 128
#define DE 256
#define ES 4
#define E_EXP 32
#define LN_EPS 1e-5f
#define BT 32   // expert token tile (MFMA)

typedef __attribute__((ext_vector_type(8))) short bf16x8;  // 8 bf16 = 4 VGPRs
typedef __attribute__((ext_vector_type(4))) float f32x4;

#define MFMA16(a, b, c) __builtin_amdgcn_mfma_f32_16x16x32_bf16((a), (b), (c), 0, 0, 0)

__device__ __forceinline__ float gelu_t(float x) {
    const float c = 0.7978845608028654f; // sqrt(2/pi)
    float x3 = x * x * x;
    return 0.5f * x * (1.0f + tanhf(c * (x + 0.044715f * x3)));
}

__device__ __forceinline__ short f2bf(float f) {
    __hip_bfloat16 h = __float2bfloat16(f);
    return *reinterpret_cast<short*>(&h);
}
__device__ __forceinline__ float bf2f(short s) {
    __hip_bfloat16 h = *reinterpret_cast<__hip_bfloat16*>(&s);
    return __bfloat162float(h);
}
// exact 3-way split: x == bf2f(h)+bf2f(m)+bf2f(l) bit-exactly for fp32 x
__device__ __forceinline__ void split3(float x, short& h, short& m, short& l) {
    h = f2bf(x);
    float r = x - bf2f(h);   // exact in fp32
    m = f2bf(r);
    float r2 = r - bf2f(m);  // exact; <=6 significant bits remain
    l = f2bf(r2);            // exact
}

// ---------------- LN of hidden: pre_ln -> h_norm (bf16) and rh_ln -> hL (fp32) ----------------
__global__ void k_ln_hidden(const float* __restrict__ hidden,
                            const float* __restrict__ pg, const float* __restrict__ pb,
                            const float* __restrict__ rg, const float* __restrict__ rb,
                            __hip_bfloat16* __restrict__ h_normb, float* __restrict__ hL) {
    int n = blockIdx.x;
    int j = threadIdx.x; // 0..255
    const float* x = hidden + (size_t)n * DM;
    float v0 = x[j], v1 = x[j + 256];
    float s = v0 + v1, q = v0 * v0 + v1 * v1;
#pragma unroll
    for (int o = 32; o; o >>= 1) { s += __shfl_down(s, o); q += __shfl_down(q, o); }
    __shared__ float red[8];
    int w = j >> 6;
    if ((j & 63) == 0) { red[w] = s; red[4 + w] = q; }
    __syncthreads();
    float sum = red[0] + red[1] + red[2] + red[3];
    float sq  = red[4] + red[5] + red[6] + red[7];
    float m = sum * (1.0f / DM);
    float var = sq * (1.0f / DM) - m * m;
    float rs = rsqrtf(var + LN_EPS);
    float t0 = (v0 - m) * rs, t1 = (v1 - m) * rs;
    size_t base = (size_t)n * DM;
    h_normb[base + j]       = __float2bfloat16(t0 * pg[j]       + pb[j]);
    h_normb[base + j + 256] = __float2bfloat16(t1 * pg[j + 256] + pb[j + 256]);
    hL[base + j]           = t0 * rg[j]       + rb[j];
    hL[base + j + 256]     = t1 * rg[j + 256] + rb[j + 256];
}

// ---------------- unified weight conversion: plain bf16 or 3-way split, K zero-pad ----------------
struct ConvJob { const float* src; short* dh; short* dm; short* dl;
                 int KB, NB, Kreal, plain, blk0; };
struct ConvJobs { ConvJob j[10]; };

__global__ void k_conv_all(ConvJobs J) {
    int b = blockIdx.x;
    int ji = 0;
#pragma unroll
    for (int i = 1; i < 10; i++) if (b >= J.j[i].blk0) ji = i;
    const ConvJob jb = J.j[ji];
    int rel = b - jb.blk0;
    int mat = rel / jb.KB, kb = rel % jb.KB;
    int ncols = jb.NB * 16;
    const float* s = jb.src + (size_t)mat * jb.Kreal * ncols;
    size_t dbase = ((size_t)mat * jb.KB + kb) * jb.NB * 512;
    for (int p = threadIdx.x; p < jb.NB * 64; p += 256) {
        int nb = p >> 6, lane = p & 63;
        int row0 = kb * 32 + ((lane >> 4) << 3);
        int col = nb * 16 + (lane & 15);
        if (jb.plain) {
            union { short sh[8]; uint4 v; } t;
#pragma unroll
            for (int j = 0; j < 8; j++) {
                float x = (row0 + j < jb.Kreal) ? s[(size_t)(row0 + j) * ncols + col] : 0.f;
                t.sh[j] = f2bf(x);
            }
            *(uint4*)&jb.dh[dbase + (size_t)p * 8] = t.v;
        } else {
            union { short sh[8]; uint4 v; } hi, mi, lo;
#pragma unroll
            for (int j = 0; j < 8; j++) {
                float x = (row0 + j < jb.Kreal) ? s[(size_t)(row0 + j) * ncols + col] : 0.f;
                split3(x, hi.sh[j], mi.sh[j], lo.sh[j]);
            }
            *(uint4*)&jb.dh[dbase + (size_t)p * 8] = hi.v;
            *(uint4*)&jb.dm[dbase + (size_t)p * 8] = mi.v;
            *(uint4*)&jb.dl[dbase + (size_t)p * 8] = lo.v;
        }
    }
}

// ---------------- 2-layer MLP body via 3-split MFMA: Y = gelu(LN?(X)@W1+b1)@W2+b2 ----------------
// !DO_LN: layer-1 A-frags built in-register from X (no LDS staging — zero reuse there).
// DO_LN (KB_TOT==4): LDS staging with fused LayerNorm.
template <int KB_TOT, bool DO_LN>
__device__ __forceinline__ void enc2_body(
        int bx, char* smem,
        const float* __restrict__ X,
        const float* __restrict__ lng, const float* __restrict__ lnb,
        const short* __restrict__ W1h, const short* __restrict__ W1m, const short* __restrict__ W1l,
        const float* __restrict__ B1,
        const short* __restrict__ W2h, const short* __restrict__ W2m, const short* __restrict__ W2l,
        const float* __restrict__ B2,
        float* __restrict__ Y) {
    constexpr int K = KB_TOT * 32;
    const int n0 = bx * 32;
    const int tid = threadIdx.x;
    const int wave = tid >> 6, lane = tid & 63;
    const int quad = lane >> 4, lm = lane & 15;
    const int mt = wave & 1;
    const int ngb = (wave >> 1) * 4;   // 4 n-tiles per wave

    short (*Ah)[132] = (short(*)[132])smem;
    short (*Am)[132] = (short(*)[132])(smem + 32 * 132 * 2);
    short (*Al)[132] = (short(*)[132])(smem + 2 * 32 * 132 * 2);

    f32x4 acc[4];
#pragma unroll
    for (int i = 0; i < 4; i++) acc[i] = (f32x4)(0.f);

    if (DO_LN) {
        // single-chunk LDS staging with fused LN (K == 128)
        for (int idx = tid; idx < 1024; idx += 256) {
            int row = idx >> 5, c4 = (idx & 31) * 4;
            float4 v = *(const float4*)&X[(size_t)(n0 + row) * K + c4];
            float s = v.x + v.y + v.z + v.w;
            float q = v.x * v.x + v.y * v.y + v.z * v.z + v.w * v.w;
#pragma unroll
            for (int o = 16; o; o >>= 1) { s += __shfl_xor(s, o); q += __shfl_xor(q, o); }
            float mean = s * (1.0f / 128.0f);
            float var = q * (1.0f / 128.0f) - mean * mean;
            float rs = rsqrtf(var + LN_EPS);
            float xv[4] = {(v.x - mean) * rs * lng[c4 + 0] + lnb[c4 + 0],
                           (v.y - mean) * rs * lng[c4 + 1] + lnb[c4 + 1],
                           (v.z - mean) * rs * lng[c4 + 2] + lnb[c4 + 2],
                           (v.w - mean) * rs * lng[c4 + 3] + lnb[c4 + 3]};
#pragma unroll
            for (int j = 0; j < 4; j++) {
                short h, m, l; split3(xv[j], h, m, l);
                Ah[row][c4 + j] = h; Am[row][c4 + j] = m; Al[row][c4 + j] = l;
            }
        }
        __syncthreads();
#pragma unroll
        for (int kb = 0; kb < KB_TOT; kb++) {
            bf16x8 ah = *(const bf16x8*)&Ah[mt * 16 + lm][kb * 32 + quad * 8];
            bf16x8 am = *(const bf16x8*)&Am[mt * 16 + lm][kb * 32 + quad * 8];
            bf16x8 al = *(const bf16x8*)&Al[mt * 16 + lm][kb * 32 + quad * 8];
#pragma unroll
            for (int nt = 0; nt < 4; nt++) {
                size_t bi = (((size_t)kb * 8 + ngb + nt) * 64 + lane) * 8;
                bf16x8 bh = *(const bf16x8*)&W1h[bi];
                bf16x8 bm = *(const bf16x8*)&W1m[bi];
                bf16x8 bl = *(const bf16x8*)&W1l[bi];
                acc[nt] = MFMA16(al, bh, acc[nt]);
                acc[nt] = MFMA16(am, bm, acc[nt]);
                acc[nt] = MFMA16(ah, bl, acc[nt]);
                acc[nt] = MFMA16(am, bh, acc[nt]);
                acc[nt] = MFMA16(ah, bm, acc[nt]);
                acc[nt] = MFMA16(ah, bh, acc[nt]);
            }
        }
    } else {
        for (int kb = 0; kb < KB_TOT; kb++) {
            // in-register A frag: this lane's 8 contiguous X values, split3'd locally
            const float* xs = X + (size_t)(n0 + mt * 16 + lm) * K + kb * 32 + quad * 8;
            float4 x0 = *(const float4*)xs, x1 = *(const float4*)(xs + 4);
            float xv[8] = {x0.x, x0.y, x0.z, x0.w, x1.x, x1.y, x1.z, x1.w};
            bf16x8 ah, am, al;
#pragma unroll
            for (int j = 0; j < 8; j++) {
                short h, m, l; split3(xv[j], h, m, l);
                ah[j] = h; am[j] = m; al[j] = l;
            }
#pragma unroll
            for (int nt = 0; nt < 4; nt++) {
                size_t bi = (((size_t)kb * 8 + ngb + nt) * 64 + lane) * 8;
                bf16x8 bh = *(const bf16x8*)&W1h[bi];
                bf16x8 bm = *(const bf16x8*)&W1m[bi];
                bf16x8 bl = *(const bf16x8*)&W1l[bi];
                acc[nt] = MFMA16(al, bh, acc[nt]);
                acc[nt] = MFMA16(am, bm, acc[nt]);
                acc[nt] = MFMA16(ah, bl, acc[nt]);
                acc[nt] = MFMA16(am, bh, acc[nt]);
                acc[nt] = MFMA16(ah, bm, acc[nt]);
                acc[nt] = MFMA16(ah, bh, acc[nt]);
            }
        }
    }
    __syncthreads();
    // layer-1 epilogue: +b1, gelu, split -> A2 frags (reuse Ah/Am/Al)
#pragma unroll
    for (int nt = 0; nt < 4; nt++) {
        int col = (ngb + nt) * 16 + lm;
        float b1 = B1[col];
#pragma unroll
        for (int r = 0; r < 4; r++) {
            int row = mt * 16 + quad * 4 + r;
            short h, m, l; split3(gelu_t(acc[nt][r] + b1), h, m, l);
            Ah[row][col] = h; Am[row][col] = m; Al[row][col] = l;
        }
    }
    __syncthreads();
    f32x4 acc2[4];
#pragma unroll
    for (int i = 0; i < 4; i++) acc2[i] = (f32x4)(0.f);
#pragma unroll
    for (int kb = 0; kb < 4; kb++) {
        bf16x8 ah = *(const bf16x8*)&Ah[mt * 16 + lm][kb * 32 + quad * 8];
        bf16x8 am = *(const bf16x8*)&Am[mt * 16 + lm][kb * 32 + quad * 8];
        bf16x8 al = *(const bf16x8*)&Al[mt * 16 + lm][kb * 32 + quad * 8];
#pragma unroll
        for (int nt = 0; nt < 4; nt++) {
            size_t bi = (((size_t)kb * 8 + ngb + nt) * 64 + lane) * 8;
            bf16x8 bh = *(const bf16x8*)&W2h[bi];
            bf16x8 bm = *(const bf16x8*)&W2m[bi];
            bf16x8 bl = *(const bf16x8*)&W2l[bi];
            acc2[nt] = MFMA16(al, bh, acc2[nt]);
            acc2[nt] = MFMA16(am, bm, acc2[nt]);
            acc2[nt] = MFMA16(ah, bl, acc2[nt]);
            acc2[nt] = MFMA16(am, bh, acc2[nt]);
            acc2[nt] = MFMA16(ah, bm, acc2[nt]);
            acc2[nt] = MFMA16(ah, bh, acc2[nt]);
        }
    }
#pragma unroll
    for (int nt = 0; nt < 4; nt++) {
        int col = (ngb + nt) * 16 + lm;
        float b2 = B2[col];
#pragma unroll
        for (int r = 0; r < 4; r++) {
            int row = mt * 16 + quad * 4 + r;
            Y[(size_t)(n0 + row) * DH + col] = acc2[nt][r] + b2;
        }
    }
}

// ---------------- group encoders body via 3-split MFMA ----------------
__device__ __forceinline__ void genc_body(
        int bx, char* smem,
        const float* __restrict__ feat,
        const float* __restrict__ gln_g, const float* __restrict__ gln_b,
        const short* __restrict__ W1h, const short* __restrict__ W1m, const short* __restrict__ W1l,
        const float* __restrict__ gb1,
        const short* __restrict__ W2h, const short* __restrict__ W2m, const short* __restrict__ W2l,
        const float* __restrict__ gb2,
        float* __restrict__ g_enc) {
    const int n0 = bx * 32;
    const int tid = threadIdx.x;
    const int wave = tid >> 6, lane = tid & 63;
    const int quad = lane >> 4, lm = lane & 15;
    const int mt = wave & 1;
    const int ngb = (wave >> 1) * 4;

    short (*A1h)[132] = (short(*)[132])smem;
    short (*A1m)[132] = (short(*)[132])(smem + 8448);
    short (*A1l)[132] = (short(*)[132])(smem + 2 * 8448);
    short (*A2h)[132] = (short(*)[132])(smem + 3 * 8448);
    short (*A2m)[132] = (short(*)[132])(smem + 4 * 8448);
    short (*A2l)[132] = (short(*)[132])(smem + 5 * 8448);

    for (int half = 0; half < 2; half++) {
        __syncthreads();
        {
            int t = tid >> 3, sub = tid & 7, gl = sub >> 1, eo = sub & 1;
            int g = half * 4 + gl;
            const float* fr = feat + (size_t)(n0 + t) * FDIM + g * FG;
            float xv[FG];
            float mean = 0.f;
#pragma unroll
            for (int i = 0; i < FG; i++) { xv[i] = fr[i]; mean += xv[i]; }
            mean *= (1.0f / FG);
            float var = 0.f;
#pragma unroll
            for (int i = 0; i < FG; i++) { float d = xv[i] - mean; var += d * d; }
            var *= (1.0f / FG);
            float rs = rsqrtf(var + LN_EPS);
            for (int i = eo * 8; i < eo * 8 + 8; i++) {
                float xn = (xv[i] - mean) * rs * gln_g[g * FG + i] + gln_b[g * FG + i];
                short h, m, l; split3(xn, h, m, l);
                A1h[t][gl * 32 + i] = h; A1m[t][gl * 32 + i] = m; A1l[t][gl * 32 + i] = l;
                A1h[t][gl * 32 + 16 + i] = 0; A1m[t][gl * 32 + 16 + i] = 0; A1l[t][gl * 32 + 16 + i] = 0;
            }
        }
        __syncthreads();
        for (int gl = 0; gl < 4; gl++) {
            int g = half * 4 + gl;
            bf16x8 ah = *(const bf16x8*)&A1h[mt * 16 + lm][gl * 32 + quad * 8];
            bf16x8 am = *(const bf16x8*)&A1m[mt * 16 + lm][gl * 32 + quad * 8];
            bf16x8 al = *(const bf16x8*)&A1l[mt * 16 + lm][gl * 32 + quad * 8];
            f32x4 acc[4];
#pragma unroll
            for (int i = 0; i < 4; i++) acc[i] = (f32x4)(0.f);
#pragma unroll
            for (int nt = 0; nt < 4; nt++) {
                size_t bi = (((size_t)g * 8 + ngb + nt) * 64 + lane) * 8;
                bf16x8 bh = *(const bf16x8*)&W1h[bi];
                bf16x8 bm = *(const bf16x8*)&W1m[bi];
                bf16x8 bl = *(const bf16x8*)&W1l[bi];
                acc[nt] = MFMA16(al, bh, acc[nt]);
                acc[nt] = MFMA16(am, bm, acc[nt]);
                acc[nt] = MFMA16(ah, bl, acc[nt]);
                acc[nt] = MFMA16(am, bh, acc[nt]);
                acc[nt] = MFMA16(ah, bm, acc[nt]);
                acc[nt] = MFMA16(ah, bh, acc[nt]);
            }
            __syncthreads();
#pragma unroll
            for (int nt = 0; nt < 4; nt++) {
                int col = (ngb + nt) * 16 + lm;
                float b1 = gb1[g * DH + col];
#pragma unroll
                for (int r = 0; r < 4; r++) {
                    int row = mt * 16 + quad * 4 + r;
                    short h, m, l; split3(gelu_t(acc[nt][r] + b1), h, m, l);
                    A2h[row][col] = h; A2m[row][col] = m; A2l[row][col] = l;
                }
            }
            __syncthreads();
            f32x4 acc2[4];
#pragma unroll
            for (int i = 0; i < 4; i++) acc2[i] = (f32x4)(0.f);
#pragma unroll
            for (int kb = 0; kb < 4; kb++) {
                bf16x8 a2h = *(const bf16x8*)&A2h[mt * 16 + lm][kb * 32 + quad * 8];
                bf16x8 a2m = *(const bf16x8*)&A2m[mt * 16 + lm][kb * 32 + quad * 8];
                bf16x8 a2l = *(const bf16x8*)&A2l[mt * 16 + lm][kb * 32 + quad * 8];
#pragma unroll
                for (int nt = 0; nt < 4; nt++) {
                    size_t bi = ((((size_t)g * 4 + kb) * 8 + ngb + nt) * 64 + lane) * 8;
                    bf16x8 bh = *(const bf16x8*)&W2h[bi];
                    bf16x8 bm = *(const bf16x8*)&W2m[bi];
                    bf16x8 bl = *(const bf16x8*)&W2l[bi];
                    acc2[nt] = MFMA16(a2l, bh, acc2[nt]);
                    acc2[nt] = MFMA16(a2m, bm, acc2[nt]);
                    acc2[nt] = MFMA16(a2h, bl, acc2[nt]);
                    acc2[nt] = MFMA16(a2m, bh, acc2[nt]);
                    acc2[nt] = MFMA16(a2h, bm, acc2[nt]);
                    acc2[nt] = MFMA16(a2h, bh, acc2[nt]);
                }
            }
#pragma unroll
            for (int nt = 0; nt < 4; nt++) {
                int col = (ngb + nt) * 16 + lm;
                float b2 = gb2[g * DH + col];
#pragma unroll
                for (int r = 0; r < 4; r++) {
                    int row = mt * 16 + quad * 4 + r;
                    g_enc[((size_t)(n0 + row) * G + g) * DH + col] = acc2[nt][r] + b2;
                }
            }
        }
    }
}

// ---------------- fused encoder launch: rh / sf / group encoders in one grid ----------------
__global__ __launch_bounds__(256) void k_enc_all(
        const float* __restrict__ hL, const float* __restrict__ feat,
        const float* __restrict__ sf_g, const float* __restrict__ sf_b,
        const float* __restrict__ gln_g, const float* __restrict__ gln_b,
        const short* Brh1H, const short* Brh1M, const short* Brh1L, const float* rh_b1,
        const short* Brh2H, const short* Brh2M, const short* Brh2L, const float* rh_b2,
        const short* Bsf1H, const short* Bsf1M, const short* Bsf1L, const float* sf_b1,
        const short* Bsf2H, const short* Bsf2M, const short* Bsf2L, const float* sf_b2,
        const short* Bgf1H, const short* Bgf1M, const short* Bgf1L, const float* gf_b1,
        const short* Bgf2H, const short* Bgf2M, const short* Bgf2L, const float* gf_b2,
        float* __restrict__ h_enc, float* __restrict__ s_enc, float* __restrict__ g_enc) {
    __shared__ __align__(16) char smem[6 * 8448];
    int job = blockIdx.x % 3;   // interleave jobs across XCDs
    int bx = blockIdx.x / 3;
    if (job == 0)
        enc2_body<16, false>(bx, smem, hL, nullptr, nullptr,
                             Brh1H, Brh1M, Brh1L, rh_b1, Brh2H, Brh2M, Brh2L, rh_b2, h_enc);
    else if (job == 1)
        enc2_body<4, true>(bx, smem, feat, sf_g, sf_b,
                           Bsf1H, Bsf1M, Bsf1L, sf_b1, Bsf2H, Bsf2M, Bsf2L, sf_b2, s_enc);
    else
        genc_body(bx, smem, feat, gln_g, gln_b,
                  Bgf1H, Bgf1M, Bgf1L, gf_b1, Bgf2H, Bgf2M, Bgf2L, gf_b2, g_enc);
}

// ---------------- stage A-fragments (3-way split bf16) for router k<256 (h|s) ----------------
__global__ void k_stage_hs(const float* __restrict__ h_enc, const float* __restrict__ s_enc,
                           short* __restrict__ Ah, short* __restrict__ Am, short* __restrict__ Al) {
    int T16 = blockIdx.x;
    for (int slot = threadIdx.x; slot < 512; slot += 256) {
        int kb = slot >> 6, lane = slot & 63;
        int quad = lane >> 4, lm = lane & 15;
        int n = T16 * 16 + lm;
        int c0 = kb * 32 + quad * 8; // 0..255
        const float* src = (c0 < 128) ? (h_enc + (size_t)n * DH + c0)
                                      : (s_enc + (size_t)n * DH + (c0 - 128));
        float4 x0 = *(const float4*)src;
        float4 x1 = *(const float4*)(src + 4);
        float xv[8] = {x0.x, x0.y, x0.z, x0.w, x1.x, x1.y, x1.z, x1.w};
        union { short sh[8]; uint4 v; } hi, mi, lo;
#pragma unroll
        for (int j = 0; j < 8; j++) split3(xv[j], hi.sh[j], mi.sh[j], lo.sh[j]);
        size_t base = ((size_t)T16 * 512 + slot) * 8;
        *(uint4*)&Ah[base] = hi.v;
        *(uint4*)&Am[base] = mi.v;
        *(uint4*)&Al[base] = lo.v;
    }
}

// ---------------- MFMA router: in-register g-part staging (LDS = epilogue only, 33KB) ----------------
__global__ __launch_bounds__(256) void k_router_mfma(
        const short* __restrict__ AhsH, const short* __restrict__ AhsM, const short* __restrict__ AhsL,
        const float* __restrict__ h_enc, const float* __restrict__ g_enc,
        const short* __restrict__ BpgH, const short* __restrict__ BpgM, const short* __restrict__ BpgL,
        const short* __restrict__ BirH, const short* __restrict__ BirM, const short* __restrict__ BirL,
        const float* __restrict__ pb1, const float* __restrict__ pw2, const float* __restrict__ pb2,
        const float* __restrict__ ib1, const float* __restrict__ iw2, const float* __restrict__ ib2,
        float* __restrict__ glog, float* __restrict__ ilog) {
    const int g = blockIdx.x & 7;       // group -> XCD affinity for B
    const int bx = blockIdx.x >> 3;     // 32-token tile
    const int tid = threadIdx.x;
    const int wave = tid >> 6, lane = tid & 63;
    const int quad = lane >> 4, lm = lane & 15;
    const bool is_pg = wave < 2;
    const int nbase = (wave & 1) * 4;          // 4 n-tiles per wave
    const short* Bh = is_pg ? BpgH : (BirH + (size_t)g * 65536);
    const short* Bm = is_pg ? BpgM : (BirM + (size_t)g * 65536);
    const short* Bl = is_pg ? BpgL : (BirL + (size_t)g * 65536);
    const int n0 = bx * 32;

    __shared__ float ph[32][129];
    __shared__ float ih[32][129];

    f32x4 acc[2][4];
#pragma unroll
    for (int mt = 0; mt < 2; mt++)
#pragma unroll
        for (int nt = 0; nt < 4; nt++) acc[mt][nt] = (f32x4)(0.f);

    for (int kb = 0; kb < 16; kb++) {
        bf16x8 Ahf[2], Amf[2], Alf[2];
#pragma unroll
        for (int mt = 0; mt < 2; mt++) {
            if (kb < 8) {
                size_t ai = (((size_t)(2 * bx + mt) * 8 + kb) * 64 + lane) * 8;
                Ahf[mt] = *(const bf16x8*)&AhsH[ai];
                Amf[mt] = *(const bf16x8*)&AhsM[ai];
                Alf[mt] = *(const bf16x8*)&AhsL[ai];
            } else {
                // in-register g-part frag: k in [0,256) = [g_enc | h_enc*g_enc]
                int n = n0 + mt * 16 + lm;
                int c0 = (kb - 8) * 32 + quad * 8;
                float xv[8];
                if (c0 < 128) {
                    const float* gs = g_enc + ((size_t)n * G + g) * DH + c0;
                    float4 x0 = *(const float4*)gs, x1 = *(const float4*)(gs + 4);
                    xv[0]=x0.x; xv[1]=x0.y; xv[2]=x0.z; xv[3]=x0.w;
                    xv[4]=x1.x; xv[5]=x1.y; xv[6]=x1.z; xv[7]=x1.w;
                } else {
                    int c = c0 - 128;
                    const float* gs = g_enc + ((size_t)n * G + g) * DH + c;
                    const float* hsrc = h_enc + (size_t)n * DH + c;
                    float4 g0 = *(const float4*)gs, g1 = *(const float4*)(gs + 4);
                    float4 h0 = *(const float4*)hsrc, h1 = *(const float4*)(hsrc + 4);
                    xv[0]=h0.x*g0.x; xv[1]=h0.y*g0.y; xv[2]=h0.z*g0.z; xv[3]=h0.w*g0.w;
                    xv[4]=h1.x*g1.x; xv[5]=h1.y*g1.y; xv[6]=h1.z*g1.z; xv[7]=h1.w*g1.w;
                }
#pragma unroll
                for (int j = 0; j < 8; j++) {
                    short h, m, l; split3(xv[j], h, m, l);
                    Ahf[mt][j] = h; Amf[mt][j] = m; Alf[mt][j] = l;
                }
            }
        }
#pragma unroll
        for (int nt = 0; nt < 4; nt++) {
            int nb = nbase + nt;
            size_t bi = (((size_t)kb * 8 + nb) * 64 + lane) * 8;
            bf16x8 bh = *(const bf16x8*)&Bh[bi];
            bf16x8 bm = *(const bf16x8*)&Bm[bi];
            bf16x8 bl = *(const bf16x8*)&Bl[bi];
#pragma unroll
            for (int mt = 0; mt < 2; mt++) {
                acc[mt][nt] = MFMA16(Alf[mt], bh, acc[mt][nt]);
                acc[mt][nt] = MFMA16(Amf[mt], bm, acc[mt][nt]);
                acc[mt][nt] = MFMA16(Ahf[mt], bl, acc[mt][nt]);
                acc[mt][nt] = MFMA16(Amf[mt], bh, acc[mt][nt]);
                acc[mt][nt] = MFMA16(Ahf[mt], bm, acc[mt][nt]);
                acc[mt][nt] = MFMA16(Ahf[mt], bh, acc[mt][nt]);
            }
        }
    }

    float* dst = is_pg ? &ph[0][0] : &ih[0][0];
#pragma unroll
    for (int mt = 0; mt < 2; mt++)
#pragma unroll
    for (int nt = 0; nt < 4; nt++) {
        int col = (wave & 1) * 64 + nt * 16 + lm;
        float b1 = is_pg ? pb1[col] : ib1[g * DH + col];
#pragma unroll
        for (int r = 0; r < 4; r++) {
            int row = mt * 16 + quad * 4 + r;
            dst[row * 129 + col] = gelu_t(acc[mt][nt][r] + b1);
        }
    }
    __syncthreads();

    if (tid < 32) {
        float s = pb2[0];
        for (int i = 0; i < DH; i++) s += ph[tid][i] * pw2[i];
        glog[(size_t)(n0 + tid) * G + g] = s; // TEMP = 1.0
    } else if (tid >= 128) {
        int t = (tid - 128) >> 2, e = (tid - 128) & 3;
        float s = ib2[g * ES + e];
        const float* w = iw2 + (size_t)g * DH * ES;
        for (int i = 0; i < DH; i++) s += ih[t][i] * w[i * ES + e];
        ilog[((size_t)(n0 + t) * G + g) * ES + e] = s;
    }
}

// ---------------- top-k softmax + dispatch to per-expert lists ----------------
__global__ void k_topk(const float* __restrict__ glog, const float* __restrict__ ilog,
                       int* __restrict__ cnt, int* __restrict__ toks, float* __restrict__ wgts) {
    int n = blockIdx.x * blockDim.x + threadIdx.x;
    if (n >= N_TOK) return;
    float gl[G];
#pragma unroll
    for (int g = 0; g < G; g++) gl[g] = glog[(size_t)n * G + g];
    int i1 = 0; float v1 = gl[0];
#pragma unroll
    for (int g = 1; g < G; g++) if (gl[g] > v1) { v1 = gl[g]; i1 = g; }
    int i2 = -1; float v2 = -1e30f;
#pragma unroll
    for (int g = 0; g < G; g++) if (g != i1 && gl[g] > v2) { v2 = gl[g]; i2 = g; }
    float eg = expf(v2 - v1);
    float den = 1.0f / (1.0f + eg);
    float gw_sel[2] = { den, eg * den };
    int g_sel[2] = { i1, i2 };
#pragma unroll
    for (int s = 0; s < 2; s++) {
        int g = g_sel[s]; float gw = gw_sel[s];
        float il[ES];
#pragma unroll
        for (int e = 0; e < ES; e++) il[e] = ilog[((size_t)n * G + g) * ES + e];
        int j1 = 0; float u1 = il[0];
#pragma unroll
        for (int e = 1; e < ES; e++) if (il[e] > u1) { u1 = il[e]; j1 = e; }
        int j2 = -1; float u2 = -1e30f;
#pragma unroll
        for (int e = 0; e < ES; e++) if (e != j1 && il[e] > u2) { u2 = il[e]; j2 = e; }
        float ei = expf(u2 - u1);
        float d2 = 1.0f / (1.0f + ei);
        int ex1 = g * ES + j1, ex2 = g * ES + j2;
        int p1 = atomicAdd(&cnt[ex1], 1);
        toks[(size_t)ex1 * N_TOK + p1] = n * 4 + s * 2;     wgts[(size_t)ex1 * N_TOK + p1] = gw * d2;
        int p2 = atomicAdd(&cnt[ex2], 1);
        toks[(size_t)ex2 * N_TOK + p2] = n * 4 + s * 2 + 1; wgts[(size_t)ex2 * N_TOK + p2] = gw * ei * d2;
    }
}

// ---------------- sparse expert MLPs via bf16 MFMA; XCD-swizzled, no duplicate B reads ----------------
__global__ __launch_bounds__(512) void k_expert_mfma(
        const __hip_bfloat16* __restrict__ h_normb,
        const short* __restrict__ wB1, const float* __restrict__ eb1,
        const short* __restrict__ wB2, const float* __restrict__ eb2,
        const int* __restrict__ cnt, const int* __restrict__ toks,
        const float* __restrict__ wgts, float* __restrict__ part) {
    const int e = blockIdx.x & 31;
    const int slot = blockIdx.x >> 5;
    const int c = cnt[e];
    const int start = slot * BT;
    if (start >= c) return;
    const int m = min(BT, c - start);

    __shared__ short hs[BT][520];
    __shared__ short es[BT][264];
    __shared__ int   tok_s[BT];
    __shared__ float w_s[BT];

    const int tid = threadIdx.x;
    if (tid < BT) {
        bool ok = tid < m;
        tok_s[tid] = ok ? toks[(size_t)e * N_TOK + start + tid] : 0;
        w_s[tid]   = ok ? wgts[(size_t)e * N_TOK + start + tid] : 0.f;
    }
    __syncthreads();
    for (int idx = tid; idx < BT * 64; idx += 512) {
        int t = idx >> 6, ch = idx & 63;
        uint4 v = make_uint4(0, 0, 0, 0);
        if (t < m) v = *((const uint4*)(h_normb + (size_t)(tok_s[t] >> 2) * DM) + ch);
        *(uint4*)&hs[t][ch * 8] = v;
    }
    __syncthreads();

    const int wave = tid >> 6, lane = tid & 63;
    const int quad = lane >> 4, lm = lane & 15;

    {
        const int ng = wave * 2;
        f32x4 acc[2][2];
#pragma unroll
        for (int a = 0; a < 2; a++)
#pragma unroll
            for (int b = 0; b < 2; b++) acc[a][b] = (f32x4)(0.f);
        const short* w1e = wB1 + (size_t)e * DM * DE;
        for (int kb = 0; kb < 16; kb++) {
            bf16x8 a0 = *(const bf16x8*)&hs[lm][kb * 32 + quad * 8];
            bf16x8 a1 = *(const bf16x8*)&hs[16 + lm][kb * 32 + quad * 8];
            const short* wp = w1e + ((size_t)kb * 16 + ng) * 512 + lane * 8;
#pragma unroll
            for (int nt = 0; nt < 2; nt++) {
                bf16x8 b = *(const bf16x8*)(wp + nt * 512);
                acc[0][nt] = MFMA16(a0, b, acc[0][nt]);
                acc[1][nt] = MFMA16(a1, b, acc[1][nt]);
            }
        }
#pragma unroll
        for (int nt = 0; nt < 2; nt++) {
            int col = (ng + nt) * 16 + lm;
            float b1 = eb1[e * DE + col];
#pragma unroll
            for (int mt = 0; mt < 2; mt++)
#pragma unroll
            for (int r = 0; r < 4; r++) {
                int row = mt * 16 + quad * 4 + r;
                es[row][col] = f2bf(gelu_t(acc[mt][nt][r] + b1));
            }
        }
    }
    __syncthreads();

    {
        const int ng2 = wave * 4;
        f32x4 acc[2][4];
#pragma unroll
        for (int a = 0; a < 2; a++)
#pragma unroll
            for (int b = 0; b < 4; b++) acc[a][b] = (f32x4)(0.f);
        const short* w2e = wB2 + (size_t)e * DE * DM;
        for (int kb = 0; kb < 8; kb++) {
            bf16x8 a0 = *(const bf16x8*)&es[lm][kb * 32 + quad * 8];
            bf16x8 a1 = *(const bf16x8*)&es[16 + lm][kb * 32 + quad * 8];
            const short* wp = w2e + ((size_t)kb * 32 + ng2) * 512 + lane * 8;
#pragma unroll
            for (int nt = 0; nt < 4; nt++) {
                bf16x8 b = *(const bf16x8*)(wp + nt * 512);
                acc[0][nt] = MFMA16(a0, b, acc[0][nt]);
                acc[1][nt] = MFMA16(a1, b, acc[1][nt]);
            }
        }
        const float* b2 = eb2 + (size_t)e * DM;
#pragma unroll
        for (int mt = 0; mt < 2; mt++)
#pragma unroll
        for (int r = 0; r < 4; r++) {
            int row = mt * 16 + quad * 4 + r;
            if (row < m) {
                float w = w_s[row];
                float* prow = part + (size_t)tok_s[row] * DM;
#pragma unroll
                for (int nt = 0; nt < 4; nt++) {
                    int col = (ng2 + nt) * 16 + lm;
                    prow[col] = w * (acc[mt][nt][r] + b2[col]);
                }
            }
        }
    }
}

// ---------------- final reduce: out[n] = sum_s part[n*4+s] ----------------
__global__ void k_reduce(const float* __restrict__ part, float* __restrict__ out) {
    int n = blockIdx.x;
    int j = threadIdx.x; // 0..127
    const float4* p = (const float4*)(part + (size_t)n * 4 * DM);
    float4 a = p[j], b = p[128 + j], c = p[256 + j], d = p[384 + j];
    float4 r = make_float4(a.x + b.x + c.x + d.x, a.y + b.y + c.y + d.y,
                           a.z + b.z + c.z + d.z, a.w + b.w + c.w + d.w);
    ((float4*)(out + (size_t)n * DM))[j] = r;
}

extern "C" void kernel_launch(void* const* d_in, const int* in_sizes, int n_in,
                              void* d_out, int out_size, void* d_ws, size_t ws_size,
                              hipStream_t stream) {
    const float* hidden  = (const float*)d_in[0];
    const float* feat    = (const float*)d_in[1];
    const float* pre_g   = (const float*)d_in[2];
    const float* pre_b   = (const float*)d_in[3];
    const float* rh_g    = (const float*)d_in[4];
    const float* rh_b    = (const float*)d_in[5];
    const float* rh_w1   = (const float*)d_in[6];
    const float* rh_b1   = (const float*)d_in[7];
    const float* rh_w2   = (const float*)d_in[8];
    const float* rh_b2   = (const float*)d_in[9];
    const float* sf_g    = (const float*)d_in[10];
    const float* sf_b    = (const float*)d_in[11];
    const float* sf_w1   = (const float*)d_in[12];
    const float* sf_b1   = (const float*)d_in[13];
    const float* sf_w2   = (const float*)d_in[14];
    const float* sf_b2   = (const float*)d_in[15];
    const float* gln_g   = (const float*)d_in[16];
    const float* gln_b   = (const float*)d_in[17];
    const float* gf_w1   = (const float*)d_in[18];
    const float* gf_b1   = (const float*)d_in[19];
    const float* gf_w2   = (const float*)d_in[20];
    const float* gf_b2   = (const float*)d_in[21];
    const float* pgs_w1  = (const float*)d_in[22];
    const float* pgs_b1  = (const float*)d_in[23];
    const float* pgs_w2  = (const float*)d_in[24];
    const float* pgs_b2  = (const float*)d_in[25];
    const float* ir_w1   = (const float*)d_in[26];
    const float* ir_b1   = (const float*)d_in[27];
    const float* ir_w2   = (const float*)d_in[28];
    const float* ir_b2   = (const float*)d_in[29];
    const float* ex_w1   = (const float*)d_in[30];
    const float* ex_b1   = (const float*)d_in[31];
    const float* ex_w2   = (const float*)d_in[32];
    const float* ex_b2   = (const float*)d_in[33];
    float* out = (float*)d_out;

    // workspace carving (256B-aligned)
    char* w = (char*)d_ws;
    auto alloc = [&](size_t bytes) { void* r = (void*)w; w += (bytes + 255) & ~(size_t)255; return r; };
    __hip_bfloat16* h_normb = (__hip_bfloat16*)alloc((size_t)N_TOK * DM * 2);
    float* h_enc = (float*)alloc((size_t)N_TOK * DH * 4);
    float* s_enc = (float*)alloc((size_t)N_TOK * DH * 4);
    float* g_enc = (float*)alloc((size_t)N_TOK * G * DH * 4);
    float* glog  = (float*)alloc((size_t)N_TOK * G * 4);
    float* ilog  = (float*)alloc((size_t)N_TOK * G * ES * 4);
    float* wgts  = (float*)alloc((size_t)E_EXP * N_TOK * 4);
    short* wB1   = (short*)alloc((size_t)E_EXP * DM * DE * 2);
    short* wB2   = (short*)alloc((size_t)E_EXP * DE * DM * 2);
    short* AhsH  = (short*)alloc((size_t)N_TOK * 256 * 2);
    short* AhsM  = (short*)alloc((size_t)N_TOK * 256 * 2);
    short* AhsL  = (short*)alloc((size_t)N_TOK * 256 * 2);
    short* BpgH  = (short*)alloc((size_t)16 * 8 * 512 * 2);
    short* BpgM  = (short*)alloc((size_t)16 * 8 * 512 * 2);
    short* BpgL  = (short*)alloc((size_t)16 * 8 * 512 * 2);
    short* BirH  = (short*)alloc((size_t)G * 16 * 8 * 512 * 2);
    short* BirM  = (short*)alloc((size_t)G * 16 * 8 * 512 * 2);
    short* BirL  = (short*)alloc((size_t)G * 16 * 8 * 512 * 2);
    short* Brh1H = (short*)alloc((size_t)16 * 8 * 512 * 2);
    short* Brh1M = (short*)alloc((size_t)16 * 8 * 512 * 2);
    short* Brh1L = (short*)alloc((size_t)16 * 8 * 512 * 2);
    short* Brh2H = (short*)alloc((size_t)4 * 8 * 512 * 2);
    short* Brh2M = (short*)alloc((size_t)4 * 8 * 512 * 2);
    short* Brh2L = (short*)alloc((size_t)4 * 8 * 512 * 2);
    short* Bsf1H = (short*)alloc((size_t)4 * 8 * 512 * 2);
    short* Bsf1M = (short*)alloc((size_t)4 * 8 * 512 * 2);
    short* Bsf1L = (short*)alloc((size_t)4 * 8 * 512 * 2);
    short* Bsf2H = (short*)alloc((size_t)4 * 8 * 512 * 2);
    short* Bsf2M = (short*)alloc((size_t)4 * 8 * 512 * 2);
    short* Bsf2L = (short*)alloc((size_t)4 * 8 * 512 * 2);
    short* Bgf1H = (short*)alloc((size_t)G * 1 * 8 * 512 * 2);
    short* Bgf1M = (short*)alloc((size_t)G * 1 * 8 * 512 * 2);
    short* Bgf1L = (short*)alloc((size_t)G * 1 * 8 * 512 * 2);
    short* Bgf2H = (short*)alloc((size_t)G * 4 * 8 * 512 * 2);
    short* Bgf2M = (short*)alloc((size_t)G * 4 * 8 * 512 * 2);
    short* Bgf2L = (short*)alloc((size_t)G * 4 * 8 * 512 * 2);
    int* cnt     = (int*)alloc(E_EXP * 4);
    int* toks    = (int*)alloc((size_t)E_EXP * N_TOK * 4);
    // union region (disjoint live ranges, stream-ordered):
    //   hL   [k_ln_hidden -> k_enc_all]    8.4 MB
    //   part [k_expert_mfma -> k_reduce]  33.6 MB
    char* uni   = (char*)alloc((size_t)N_TOK * 4 * DM * 4); // 33.6 MB = max
    float* hL   = (float*)uni;
    float* part = (float*)uni;

    hipMemsetAsync(cnt, 0, E_EXP * sizeof(int), stream);

    // single fused weight-conversion launch (10 jobs)
    ConvJobs J;
    int b0 = 0;
    auto mkjob = [&](int i, const float* s, short* dh, short* dm, short* dl,
                     int KB, int NB, int Kreal, int plain, int nmat) {
        J.j[i] = ConvJob{s, dh, dm, dl, KB, NB, Kreal, plain, b0};
        b0 += KB * nmat;
    };
    mkjob(0, ex_w1, wB1, nullptr, nullptr, 16, 16, 512, 1, E_EXP);
    mkjob(1, ex_w2, wB2, nullptr, nullptr, 8, 32, 256, 1, E_EXP);
    mkjob(2, pgs_w1, BpgH, BpgM, BpgL, 16, 8, 512, 0, 1);
    mkjob(3, ir_w1, BirH, BirM, BirL, 16, 8, 512, 0, G);
    mkjob(4, rh_w1, Brh1H, Brh1M, Brh1L, 16, 8, 512, 0, 1);
    mkjob(5, rh_w2, Brh2H, Brh2M, Brh2L, 4, 8, 128, 0, 1);
    mkjob(6, sf_w1, Bsf1H, Bsf1M, Bsf1L, 4, 8, 128, 0, 1);
    mkjob(7, sf_w2, Bsf2H, Bsf2M, Bsf2L, 4, 8, 128, 0, 1);
    mkjob(8, gf_w1, Bgf1H, Bgf1M, Bgf1L, 1, 8, 16, 0, G);
    mkjob(9, gf_w2, Bgf2H, Bgf2M, Bgf2L, 4, 8, 128, 0, G);
    k_conv_all<<<b0, 256, 0, stream>>>(J);

    k_ln_hidden<<<N_TOK, 256, 0, stream>>>(hidden, pre_g, pre_b, rh_g, rh_b, h_normb, hL);

    // fused encoders: rh / sf / group, one launch (384 blocks)
    k_enc_all<<<3 * (N_TOK / 32), 256, 0, stream>>>(
        hL, feat, sf_g, sf_b, gln_g, gln_b,
        Brh1H, Brh1M, Brh1L, rh_b1, Brh2H, Brh2M, Brh2L, rh_b2,
        Bsf1H, Bsf1M, Bsf1L, sf_b1, Bsf2H, Bsf2M, Bsf2L, sf_b2,
        Bgf1H, Bgf1M, Bgf1L, gf_b1, Bgf2H, Bgf2M, Bgf2L, gf_b2,
        h_enc, s_enc, g_enc);

    k_stage_hs<<<N_TOK / 16, 256, 0, stream>>>(h_enc, s_enc, AhsH, AhsM, AhsL);

    // router: XCD-swizzled 1D grid (bid&7 = group), g-part staged in-register
    k_router_mfma<<<(N_TOK / 32) * G, 256, 0, stream>>>(AhsH, AhsM, AhsL, h_enc, g_enc,
                                             BpgH, BpgM, BpgL, BirH, BirM, BirL,
                                             pgs_b1, pgs_w2, pgs_b2, ir_b1, ir_w2, ir_b2,
                                             glog, ilog);

    k_topk<<<N_TOK / 256, 256, 0, stream>>>(glog, ilog, cnt, toks, wgts);
    // XCD-swizzled 1D expert grid: bid = slot*32 + e
    k_expert_mfma<<<(N_TOK / BT) * E_EXP, 512, 0, stream>>>(h_normb, wB1, ex_b1, wB2, ex_b2,
                                                            cnt, toks, wgts, part);
    k_reduce<<<N_TOK, 128, 0, stream>>>(part, out);
}

// Round 9
// 346.128 us; speedup vs baseline: 3.2003x; 1.1272x over previous
//
#include <hip/hip_runtime.h>
#include <hip/hip_bf16.h>
#include <math.h>

#define N_TOK 4096
#define DM 512
#define FDIM 128
#define G 8
#define FG 16
#define DH 128
#define DE 256
#define ES 4
#define E_EXP 32
#define LN_EPS 1e-5f
#define BT 32   // expert token tile (MFMA)

typedef __attribute__((ext_vector_type(8))) short bf16x8;  // 8 bf16 = 4 VGPRs
typedef __attribute__((ext_vector_type(4))) float f32x4;

#define MFMA16(a, b, c) __builtin_amdgcn_mfma_f32_16x16x32_bf16((a), (b), (c), 0, 0, 0)

__device__ __forceinline__ float gelu_t(float x) {
    const float c = 0.7978845608028654f; // sqrt(2/pi)
    float x3 = x * x * x;
    return 0.5f * x * (1.0f + tanhf(c * (x + 0.044715f * x3)));
}

__device__ __forceinline__ short f2bf(float f) {
    __hip_bfloat16 h = __float2bfloat16(f);
    return *reinterpret_cast<short*>(&h);
}
__device__ __forceinline__ float bf2f(short s) {
    __hip_bfloat16 h = *reinterpret_cast<__hip_bfloat16*>(&s);
    return __bfloat162float(h);
}
// exact 3-way split: x == bf2f(h)+bf2f(m)+bf2f(l) bit-exactly for fp32 x
__device__ __forceinline__ void split3(float x, short& h, short& m, short& l) {
    h = f2bf(x);
    float r = x - bf2f(h);   // exact in fp32
    m = f2bf(r);
    float r2 = r - bf2f(m);  // exact; <=6 significant bits remain
    l = f2bf(r2);            // exact
}

// ---------------- LN of hidden: pre_ln -> h_norm (bf16) and rh_ln -> hL (fp32) ----------------
__global__ void k_ln_hidden(const float* __restrict__ hidden,
                            const float* __restrict__ pg, const float* __restrict__ pb,
                            const float* __restrict__ rg, const float* __restrict__ rb,
                            __hip_bfloat16* __restrict__ h_normb, float* __restrict__ hL) {
    int n = blockIdx.x;
    int j = threadIdx.x; // 0..255
    const float* x = hidden + (size_t)n * DM;
    float v0 = x[j], v1 = x[j + 256];
    float s = v0 + v1, q = v0 * v0 + v1 * v1;
#pragma unroll
    for (int o = 32; o; o >>= 1) { s += __shfl_down(s, o); q += __shfl_down(q, o); }
    __shared__ float red[8];
    int w = j >> 6;
    if ((j & 63) == 0) { red[w] = s; red[4 + w] = q; }
    __syncthreads();
    float sum = red[0] + red[1] + red[2] + red[3];
    float sq  = red[4] + red[5] + red[6] + red[7];
    float m = sum * (1.0f / DM);
    float var = sq * (1.0f / DM) - m * m;
    float rs = rsqrtf(var + LN_EPS);
    float t0 = (v0 - m) * rs, t1 = (v1 - m) * rs;
    size_t base = (size_t)n * DM;
    h_normb[base + j]       = __float2bfloat16(t0 * pg[j]       + pb[j]);
    h_normb[base + j + 256] = __float2bfloat16(t1 * pg[j + 256] + pb[j + 256]);
    hL[base + j]           = t0 * rg[j]       + rb[j];
    hL[base + j + 256]     = t1 * rg[j + 256] + rb[j + 256];
}

// ---------------- unified weight conversion: plain bf16 or 3-way split, K zero-pad ----------------
struct ConvJob { const float* src; short* dh; short* dm; short* dl;
                 int KB, NB, Kreal, plain, blk0; };
struct ConvJobs { ConvJob j[10]; };

__global__ void k_conv_all(ConvJobs J) {
    int b = blockIdx.x;
    int ji = 0;
#pragma unroll
    for (int i = 1; i < 10; i++) if (b >= J.j[i].blk0) ji = i;
    const ConvJob jb = J.j[ji];
    int rel = b - jb.blk0;
    int mat = rel / jb.KB, kb = rel % jb.KB;
    int ncols = jb.NB * 16;
    const float* s = jb.src + (size_t)mat * jb.Kreal * ncols;
    size_t dbase = ((size_t)mat * jb.KB + kb) * jb.NB * 512;
    for (int p = threadIdx.x; p < jb.NB * 64; p += 256) {
        int nb = p >> 6, lane = p & 63;
        int row0 = kb * 32 + ((lane >> 4) << 3);
        int col = nb * 16 + (lane & 15);
        if (jb.plain) {
            union { short sh[8]; uint4 v; } t;
#pragma unroll
            for (int j = 0; j < 8; j++) {
                float x = (row0 + j < jb.Kreal) ? s[(size_t)(row0 + j) * ncols + col] : 0.f;
                t.sh[j] = f2bf(x);
            }
            *(uint4*)&jb.dh[dbase + (size_t)p * 8] = t.v;
        } else {
            union { short sh[8]; uint4 v; } hi, mi, lo;
#pragma unroll
            for (int j = 0; j < 8; j++) {
                float x = (row0 + j < jb.Kreal) ? s[(size_t)(row0 + j) * ncols + col] : 0.f;
                split3(x, hi.sh[j], mi.sh[j], lo.sh[j]);
            }
            *(uint4*)&jb.dh[dbase + (size_t)p * 8] = hi.v;
            *(uint4*)&jb.dm[dbase + (size_t)p * 8] = mi.v;
            *(uint4*)&jb.dl[dbase + (size_t)p * 8] = lo.v;
        }
    }
}

// ---------------- 2-layer MLP body via 3-split MFMA: Y = gelu(LN?(X)@W1+b1)@W2+b2 ----------------
// !DO_LN: layer-1 A-frags built in-register from X (no LDS staging — zero reuse there).
// DO_LN (KB_TOT==4): LDS staging with fused LayerNorm.
template <int KB_TOT, bool DO_LN>
__device__ __forceinline__ void enc2_body(
        int bx, char* smem,
        const float* __restrict__ X,
        const float* __restrict__ lng, const float* __restrict__ lnb,
        const short* __restrict__ W1h, const short* __restrict__ W1m, const short* __restrict__ W1l,
        const float* __restrict__ B1,
        const short* __restrict__ W2h, const short* __restrict__ W2m, const short* __restrict__ W2l,
        const float* __restrict__ B2,
        float* __restrict__ Y) {
    constexpr int K = KB_TOT * 32;
    const int n0 = bx * 32;
    const int tid = threadIdx.x;
    const int wave = tid >> 6, lane = tid & 63;
    const int quad = lane >> 4, lm = lane & 15;
    const int mt = wave & 1;
    const int ngb = (wave >> 1) * 4;   // 4 n-tiles per wave

    short (*Ah)[132] = (short(*)[132])smem;
    short (*Am)[132] = (short(*)[132])(smem + 32 * 132 * 2);
    short (*Al)[132] = (short(*)[132])(smem + 2 * 32 * 132 * 2);

    f32x4 acc[4];
#pragma unroll
    for (int i = 0; i < 4; i++) acc[i] = (f32x4)(0.f);

    if (DO_LN) {
        // single-chunk LDS staging with fused LN (K == 128)
        for (int idx = tid; idx < 1024; idx += 256) {
            int row = idx >> 5, c4 = (idx & 31) * 4;
            float4 v = *(const float4*)&X[(size_t)(n0 + row) * K + c4];
            float s = v.x + v.y + v.z + v.w;
            float q = v.x * v.x + v.y * v.y + v.z * v.z + v.w * v.w;
#pragma unroll
            for (int o = 16; o; o >>= 1) { s += __shfl_xor(s, o); q += __shfl_xor(q, o); }
            float mean = s * (1.0f / 128.0f);
            float var = q * (1.0f / 128.0f) - mean * mean;
            float rs = rsqrtf(var + LN_EPS);
            float xv[4] = {(v.x - mean) * rs * lng[c4 + 0] + lnb[c4 + 0],
                           (v.y - mean) * rs * lng[c4 + 1] + lnb[c4 + 1],
                           (v.z - mean) * rs * lng[c4 + 2] + lnb[c4 + 2],
                           (v.w - mean) * rs * lng[c4 + 3] + lnb[c4 + 3]};
#pragma unroll
            for (int j = 0; j < 4; j++) {
                short h, m, l; split3(xv[j], h, m, l);
                Ah[row][c4 + j] = h; Am[row][c4 + j] = m; Al[row][c4 + j] = l;
            }
        }
        __syncthreads();
#pragma unroll
        for (int kb = 0; kb < KB_TOT; kb++) {
            bf16x8 ah = *(const bf16x8*)&Ah[mt * 16 + lm][kb * 32 + quad * 8];
            bf16x8 am = *(const bf16x8*)&Am[mt * 16 + lm][kb * 32 + quad * 8];
            bf16x8 al = *(const bf16x8*)&Al[mt * 16 + lm][kb * 32 + quad * 8];
#pragma unroll
            for (int nt = 0; nt < 4; nt++) {
                size_t bi = (((size_t)kb * 8 + ngb + nt) * 64 + lane) * 8;
                bf16x8 bh = *(const bf16x8*)&W1h[bi];
                bf16x8 bm = *(const bf16x8*)&W1m[bi];
                bf16x8 bl = *(const bf16x8*)&W1l[bi];
                acc[nt] = MFMA16(al, bh, acc[nt]);
                acc[nt] = MFMA16(am, bm, acc[nt]);
                acc[nt] = MFMA16(ah, bl, acc[nt]);
                acc[nt] = MFMA16(am, bh, acc[nt]);
                acc[nt] = MFMA16(ah, bm, acc[nt]);
                acc[nt] = MFMA16(ah, bh, acc[nt]);
            }
        }
    } else {
        for (int kb = 0; kb < KB_TOT; kb++) {
            // in-register A frag: this lane's 8 contiguous X values, split3'd locally
            const float* xs = X + (size_t)(n0 + mt * 16 + lm) * K + kb * 32 + quad * 8;
            float4 x0 = *(const float4*)xs, x1 = *(const float4*)(xs + 4);
            float xv[8] = {x0.x, x0.y, x0.z, x0.w, x1.x, x1.y, x1.z, x1.w};
            bf16x8 ah, am, al;
#pragma unroll
            for (int j = 0; j < 8; j++) {
                short h, m, l; split3(xv[j], h, m, l);
                ah[j] = h; am[j] = m; al[j] = l;
            }
#pragma unroll
            for (int nt = 0; nt < 4; nt++) {
                size_t bi = (((size_t)kb * 8 + ngb + nt) * 64 + lane) * 8;
                bf16x8 bh = *(const bf16x8*)&W1h[bi];
                bf16x8 bm = *(const bf16x8*)&W1m[bi];
                bf16x8 bl = *(const bf16x8*)&W1l[bi];
                acc[nt] = MFMA16(al, bh, acc[nt]);
                acc[nt] = MFMA16(am, bm, acc[nt]);
                acc[nt] = MFMA16(ah, bl, acc[nt]);
                acc[nt] = MFMA16(am, bh, acc[nt]);
                acc[nt] = MFMA16(ah, bm, acc[nt]);
                acc[nt] = MFMA16(ah, bh, acc[nt]);
            }
        }
    }
    __syncthreads();
    // layer-1 epilogue: +b1, gelu, split -> A2 frags (reuse Ah/Am/Al)
#pragma unroll
    for (int nt = 0; nt < 4; nt++) {
        int col = (ngb + nt) * 16 + lm;
        float b1 = B1[col];
#pragma unroll
        for (int r = 0; r < 4; r++) {
            int row = mt * 16 + quad * 4 + r;
            short h, m, l; split3(gelu_t(acc[nt][r] + b1), h, m, l);
            Ah[row][col] = h; Am[row][col] = m; Al[row][col] = l;
        }
    }
    __syncthreads();
    f32x4 acc2[4];
#pragma unroll
    for (int i = 0; i < 4; i++) acc2[i] = (f32x4)(0.f);
#pragma unroll
    for (int kb = 0; kb < 4; kb++) {
        bf16x8 ah = *(const bf16x8*)&Ah[mt * 16 + lm][kb * 32 + quad * 8];
        bf16x8 am = *(const bf16x8*)&Am[mt * 16 + lm][kb * 32 + quad * 8];
        bf16x8 al = *(const bf16x8*)&Al[mt * 16 + lm][kb * 32 + quad * 8];
#pragma unroll
        for (int nt = 0; nt < 4; nt++) {
            size_t bi = (((size_t)kb * 8 + ngb + nt) * 64 + lane) * 8;
            bf16x8 bh = *(const bf16x8*)&W2h[bi];
            bf16x8 bm = *(const bf16x8*)&W2m[bi];
            bf16x8 bl = *(const bf16x8*)&W2l[bi];
            acc2[nt] = MFMA16(al, bh, acc2[nt]);
            acc2[nt] = MFMA16(am, bm, acc2[nt]);
            acc2[nt] = MFMA16(ah, bl, acc2[nt]);
            acc2[nt] = MFMA16(am, bh, acc2[nt]);
            acc2[nt] = MFMA16(ah, bm, acc2[nt]);
            acc2[nt] = MFMA16(ah, bh, acc2[nt]);
        }
    }
#pragma unroll
    for (int nt = 0; nt < 4; nt++) {
        int col = (ngb + nt) * 16 + lm;
        float b2 = B2[col];
#pragma unroll
        for (int r = 0; r < 4; r++) {
            int row = mt * 16 + quad * 4 + r;
            Y[(size_t)(n0 + row) * DH + col] = acc2[nt][r] + b2;
        }
    }
}

// ---------------- single-group encoder body: one (32-token tile, group) per block ----------------
// A1 (K=32 padded) and A2 (K=128) alias the same 3x8448B LDS buffers (barrier-separated).
__device__ __forceinline__ void genc_one(
        int bx, int g, char* smem,
        const float* __restrict__ feat,
        const float* __restrict__ gln_g, const float* __restrict__ gln_b,
        const short* __restrict__ W1h, const short* __restrict__ W1m, const short* __restrict__ W1l,
        const float* __restrict__ gb1,
        const short* __restrict__ W2h, const short* __restrict__ W2m, const short* __restrict__ W2l,
        const float* __restrict__ gb2,
        float* __restrict__ g_enc) {
    const int n0 = bx * 32;
    const int tid = threadIdx.x;
    const int wave = tid >> 6, lane = tid & 63;
    const int quad = lane >> 4, lm = lane & 15;
    const int mt = wave & 1;
    const int ngb = (wave >> 1) * 4;

    short (*Ah)[132] = (short(*)[132])smem;
    short (*Am)[132] = (short(*)[132])(smem + 8448);
    short (*Al)[132] = (short(*)[132])(smem + 2 * 8448);

    // LN stage: 8 threads/token, serial 16-sum (bit-identical to prior rounds), 2 elems each
    {
        int t = tid >> 3, sub = tid & 7;
        const float* fr = feat + (size_t)(n0 + t) * FDIM + g * FG;
        float xv[FG];
        float mean = 0.f;
#pragma unroll
        for (int i = 0; i < FG; i++) { xv[i] = fr[i]; mean += xv[i]; }
        mean *= (1.0f / FG);
        float var = 0.f;
#pragma unroll
        for (int i = 0; i < FG; i++) { float d = xv[i] - mean; var += d * d; }
        var *= (1.0f / FG);
        float rs = rsqrtf(var + LN_EPS);
#pragma unroll
        for (int j = 0; j < 2; j++) {
            int i = sub * 2 + j;
            float xn = (xv[i] - mean) * rs * gln_g[g * FG + i] + gln_b[g * FG + i];
            short h, m, l; split3(xn, h, m, l);
            Ah[t][i] = h; Am[t][i] = m; Al[t][i] = l;
            Ah[t][16 + i] = 0; Am[t][16 + i] = 0; Al[t][16 + i] = 0;  // K pad to 32
        }
    }
    __syncthreads();
    // layer-1: K=32 (single kb)
    f32x4 acc[4];
#pragma unroll
    for (int i = 0; i < 4; i++) acc[i] = (f32x4)(0.f);
    {
        bf16x8 ah = *(const bf16x8*)&Ah[mt * 16 + lm][quad * 8];
        bf16x8 am = *(const bf16x8*)&Am[mt * 16 + lm][quad * 8];
        bf16x8 al = *(const bf16x8*)&Al[mt * 16 + lm][quad * 8];
#pragma unroll
        for (int nt = 0; nt < 4; nt++) {
            size_t bi = (((size_t)g * 8 + ngb + nt) * 64 + lane) * 8;  // KB=1 per mat
            bf16x8 bh = *(const bf16x8*)&W1h[bi];
            bf16x8 bm = *(const bf16x8*)&W1m[bi];
            bf16x8 bl = *(const bf16x8*)&W1l[bi];
            acc[nt] = MFMA16(al, bh, acc[nt]);
            acc[nt] = MFMA16(am, bm, acc[nt]);
            acc[nt] = MFMA16(ah, bl, acc[nt]);
            acc[nt] = MFMA16(am, bh, acc[nt]);
            acc[nt] = MFMA16(ah, bm, acc[nt]);
            acc[nt] = MFMA16(ah, bh, acc[nt]);
        }
    }
    __syncthreads();   // all waves done reading A1 before A2 overwrite
#pragma unroll
    for (int nt = 0; nt < 4; nt++) {
        int col = (ngb + nt) * 16 + lm;
        float b1 = gb1[g * DH + col];
#pragma unroll
        for (int r = 0; r < 4; r++) {
            int row = mt * 16 + quad * 4 + r;
            short h, m, l; split3(gelu_t(acc[nt][r] + b1), h, m, l);
            Ah[row][col] = h; Am[row][col] = m; Al[row][col] = l;
        }
    }
    __syncthreads();
    // layer-2: K=128 (4 kb)
    f32x4 acc2[4];
#pragma unroll
    for (int i = 0; i < 4; i++) acc2[i] = (f32x4)(0.f);
#pragma unroll
    for (int kb = 0; kb < 4; kb++) {
        bf16x8 a2h = *(const bf16x8*)&Ah[mt * 16 + lm][kb * 32 + quad * 8];
        bf16x8 a2m = *(const bf16x8*)&Am[mt * 16 + lm][kb * 32 + quad * 8];
        bf16x8 a2l = *(const bf16x8*)&Al[mt * 16 + lm][kb * 32 + quad * 8];
#pragma unroll
        for (int nt = 0; nt < 4; nt++) {
            size_t bi = ((((size_t)g * 4 + kb) * 8 + ngb + nt) * 64 + lane) * 8;
            bf16x8 bh = *(const bf16x8*)&W2h[bi];
            bf16x8 bm = *(const bf16x8*)&W2m[bi];
            bf16x8 bl = *(const bf16x8*)&W2l[bi];
            acc2[nt] = MFMA16(a2l, bh, acc2[nt]);
            acc2[nt] = MFMA16(a2m, bm, acc2[nt]);
            acc2[nt] = MFMA16(a2h, bl, acc2[nt]);
            acc2[nt] = MFMA16(a2m, bh, acc2[nt]);
            acc2[nt] = MFMA16(a2h, bm, acc2[nt]);
            acc2[nt] = MFMA16(a2h, bh, acc2[nt]);
        }
    }
#pragma unroll
    for (int nt = 0; nt < 4; nt++) {
        int col = (ngb + nt) * 16 + lm;
        float b2 = gb2[g * DH + col];
#pragma unroll
        for (int r = 0; r < 4; r++) {
            int row = mt * 16 + quad * 4 + r;
            g_enc[((size_t)(n0 + row) * G + g) * DH + col] = acc2[nt][r] + b2;
        }
    }
}

// ---------------- fused encoder launch: rh(128) + sf(128) + genc(1024) blocks ----------------
__global__ __launch_bounds__(256) void k_enc_all(
        const float* __restrict__ hL, const float* __restrict__ feat,
        const float* __restrict__ sf_g, const float* __restrict__ sf_b,
        const float* __restrict__ gln_g, const float* __restrict__ gln_b,
        const short* Brh1H, const short* Brh1M, const short* Brh1L, const float* rh_b1,
        const short* Brh2H, const short* Brh2M, const short* Brh2L, const float* rh_b2,
        const short* Bsf1H, const short* Bsf1M, const short* Bsf1L, const float* sf_b1,
        const short* Bsf2H, const short* Bsf2M, const short* Bsf2L, const float* sf_b2,
        const short* Bgf1H, const short* Bgf1M, const short* Bgf1L, const float* gf_b1,
        const short* Bgf2H, const short* Bgf2M, const short* Bgf2L, const float* gf_b2,
        float* __restrict__ h_enc, float* __restrict__ s_enc, float* __restrict__ g_enc) {
    __shared__ __align__(16) char smem[3 * 8448];   // 25.3 KB -> 6 blocks/CU
    int bid = blockIdx.x;
    if (bid < 128)
        enc2_body<16, false>(bid, smem, hL, nullptr, nullptr,
                             Brh1H, Brh1M, Brh1L, rh_b1, Brh2H, Brh2M, Brh2L, rh_b2, h_enc);
    else if (bid < 256)
        enc2_body<4, true>(bid - 128, smem, feat, sf_g, sf_b,
                           Bsf1H, Bsf1M, Bsf1L, sf_b1, Bsf2H, Bsf2M, Bsf2L, sf_b2, s_enc);
    else {
        int idx = bid - 256;    // (idx & 7) = group -> XCD affinity for gf weights
        genc_one(idx >> 3, idx & 7, smem, feat, gln_g, gln_b,
                 Bgf1H, Bgf1M, Bgf1L, gf_b1, Bgf2H, Bgf2M, Bgf2L, gf_b2, g_enc);
    }
}

// ---------------- stage A-fragments (3-way split bf16) for router k<256 (h|s) ----------------
__global__ void k_stage_hs(const float* __restrict__ h_enc, const float* __restrict__ s_enc,
                           short* __restrict__ Ah, short* __restrict__ Am, short* __restrict__ Al) {
    int T16 = blockIdx.x;
    for (int slot = threadIdx.x; slot < 512; slot += 256) {
        int kb = slot >> 6, lane = slot & 63;
        int quad = lane >> 4, lm = lane & 15;
        int n = T16 * 16 + lm;
        int c0 = kb * 32 + quad * 8; // 0..255
        const float* src = (c0 < 128) ? (h_enc + (size_t)n * DH + c0)
                                      : (s_enc + (size_t)n * DH + (c0 - 128));
        float4 x0 = *(const float4*)src;
        float4 x1 = *(const float4*)(src + 4);
        float xv[8] = {x0.x, x0.y, x0.z, x0.w, x1.x, x1.y, x1.z, x1.w};
        union { short sh[8]; uint4 v; } hi, mi, lo;
#pragma unroll
        for (int j = 0; j < 8; j++) split3(xv[j], hi.sh[j], mi.sh[j], lo.sh[j]);
        size_t base = ((size_t)T16 * 512 + slot) * 8;
        *(uint4*)&Ah[base] = hi.v;
        *(uint4*)&Am[base] = mi.v;
        *(uint4*)&Al[base] = lo.v;
    }
}

// ---------------- MFMA router: in-register g-part staging (LDS = epilogue only, 33KB) ----------------
__global__ __launch_bounds__(256) void k_router_mfma(
        const short* __restrict__ AhsH, const short* __restrict__ AhsM, const short* __restrict__ AhsL,
        const float* __restrict__ h_enc, const float* __restrict__ g_enc,
        const short* __restrict__ BpgH, const short* __restrict__ BpgM, const short* __restrict__ BpgL,
        const short* __restrict__ BirH, const short* __restrict__ BirM, const short* __restrict__ BirL,
        const float* __restrict__ pb1, const float* __restrict__ pw2, const float* __restrict__ pb2,
        const float* __restrict__ ib1, const float* __restrict__ iw2, const float* __restrict__ ib2,
        float* __restrict__ glog, float* __restrict__ ilog) {
    const int g = blockIdx.x & 7;       // group -> XCD affinity for B
    const int bx = blockIdx.x >> 3;     // 32-token tile
    const int tid = threadIdx.x;
    const int wave = tid >> 6, lane = tid & 63;
    const int quad = lane >> 4, lm = lane & 15;
    const bool is_pg = wave < 2;
    const int nbase = (wave & 1) * 4;          // 4 n-tiles per wave
    const short* Bh = is_pg ? BpgH : (BirH + (size_t)g * 65536);
    const short* Bm = is_pg ? BpgM : (BirM + (size_t)g * 65536);
    const short* Bl = is_pg ? BpgL : (BirL + (size_t)g * 65536);
    const int n0 = bx * 32;

    __shared__ float ph[32][129];
    __shared__ float ih[32][129];

    f32x4 acc[2][4];
#pragma unroll
    for (int mt = 0; mt < 2; mt++)
#pragma unroll
        for (int nt = 0; nt < 4; nt++) acc[mt][nt] = (f32x4)(0.f);

    for (int kb = 0; kb < 16; kb++) {
        bf16x8 Ahf[2], Amf[2], Alf[2];
#pragma unroll
        for (int mt = 0; mt < 2; mt++) {
            if (kb < 8) {
                size_t ai = (((size_t)(2 * bx + mt) * 8 + kb) * 64 + lane) * 8;
                Ahf[mt] = *(const bf16x8*)&AhsH[ai];
                Amf[mt] = *(const bf16x8*)&AhsM[ai];
                Alf[mt] = *(const bf16x8*)&AhsL[ai];
            } else {
                // in-register g-part frag: k in [0,256) = [g_enc | h_enc*g_enc]
                int n = n0 + mt * 16 + lm;
                int c0 = (kb - 8) * 32 + quad * 8;
                float xv[8];
                if (c0 < 128) {
                    const float* gs = g_enc + ((size_t)n * G + g) * DH + c0;
                    float4 x0 = *(const float4*)gs, x1 = *(const float4*)(gs + 4);
                    xv[0]=x0.x; xv[1]=x0.y; xv[2]=x0.z; xv[3]=x0.w;
                    xv[4]=x1.x; xv[5]=x1.y; xv[6]=x1.z; xv[7]=x1.w;
                } else {
                    int c = c0 - 128;
                    const float* gs = g_enc + ((size_t)n * G + g) * DH + c;
                    const float* hsrc = h_enc + (size_t)n * DH + c;
                    float4 g0 = *(const float4*)gs, g1 = *(const float4*)(gs + 4);
                    float4 h0 = *(const float4*)hsrc, h1 = *(const float4*)(hsrc + 4);
                    xv[0]=h0.x*g0.x; xv[1]=h0.y*g0.y; xv[2]=h0.z*g0.z; xv[3]=h0.w*g0.w;
                    xv[4]=h1.x*g1.x; xv[5]=h1.y*g1.y; xv[6]=h1.z*g1.z; xv[7]=h1.w*g1.w;
                }
#pragma unroll
                for (int j = 0; j < 8; j++) {
                    short h, m, l; split3(xv[j], h, m, l);
                    Ahf[mt][j] = h; Amf[mt][j] = m; Alf[mt][j] = l;
                }
            }
        }
#pragma unroll
        for (int nt = 0; nt < 4; nt++) {
            int nb = nbase + nt;
            size_t bi = (((size_t)kb * 8 + nb) * 64 + lane) * 8;
            bf16x8 bh = *(const bf16x8*)&Bh[bi];
            bf16x8 bm = *(const bf16x8*)&Bm[bi];
            bf16x8 bl = *(const bf16x8*)&Bl[bi];
#pragma unroll
            for (int mt = 0; mt < 2; mt++) {
                acc[mt][nt] = MFMA16(Alf[mt], bh, acc[mt][nt]);
                acc[mt][nt] = MFMA16(Amf[mt], bm, acc[mt][nt]);
                acc[mt][nt] = MFMA16(Ahf[mt], bl, acc[mt][nt]);
                acc[mt][nt] = MFMA16(Amf[mt], bh, acc[mt][nt]);
                acc[mt][nt] = MFMA16(Ahf[mt], bm, acc[mt][nt]);
                acc[mt][nt] = MFMA16(Ahf[mt], bh, acc[mt][nt]);
            }
        }
    }

    float* dst = is_pg ? &ph[0][0] : &ih[0][0];
#pragma unroll
    for (int mt = 0; mt < 2; mt++)
#pragma unroll
    for (int nt = 0; nt < 4; nt++) {
        int col = (wave & 1) * 64 + nt * 16 + lm;
        float b1 = is_pg ? pb1[col] : ib1[g * DH + col];
#pragma unroll
        for (int r = 0; r < 4; r++) {
            int row = mt * 16 + quad * 4 + r;
            dst[row * 129 + col] = gelu_t(acc[mt][nt][r] + b1);
        }
    }
    __syncthreads();

    if (tid < 32) {
        float s = pb2[0];
        for (int i = 0; i < DH; i++) s += ph[tid][i] * pw2[i];
        glog[(size_t)(n0 + tid) * G + g] = s; // TEMP = 1.0
    } else if (tid >= 128) {
        int t = (tid - 128) >> 2, e = (tid - 128) & 3;
        float s = ib2[g * ES + e];
        const float* w = iw2 + (size_t)g * DH * ES;
        for (int i = 0; i < DH; i++) s += ih[t][i] * w[i * ES + e];
        ilog[((size_t)(n0 + t) * G + g) * ES + e] = s;
    }
}

// ---------------- top-k softmax + dispatch to per-expert lists ----------------
__global__ void k_topk(const float* __restrict__ glog, const float* __restrict__ ilog,
                       int* __restrict__ cnt, int* __restrict__ toks, float* __restrict__ wgts) {
    int n = blockIdx.x * blockDim.x + threadIdx.x;
    if (n >= N_TOK) return;
    float gl[G];
#pragma unroll
    for (int g = 0; g < G; g++) gl[g] = glog[(size_t)n * G + g];
    int i1 = 0; float v1 = gl[0];
#pragma unroll
    for (int g = 1; g < G; g++) if (gl[g] > v1) { v1 = gl[g]; i1 = g; }
    int i2 = -1; float v2 = -1e30f;
#pragma unroll
    for (int g = 0; g < G; g++) if (g != i1 && gl[g] > v2) { v2 = gl[g]; i2 = g; }
    float eg = expf(v2 - v1);
    float den = 1.0f / (1.0f + eg);
    float gw_sel[2] = { den, eg * den };
    int g_sel[2] = { i1, i2 };
#pragma unroll
    for (int s = 0; s < 2; s++) {
        int g = g_sel[s]; float gw = gw_sel[s];
        float il[ES];
#pragma unroll
        for (int e = 0; e < ES; e++) il[e] = ilog[((size_t)n * G + g) * ES + e];
        int j1 = 0; float u1 = il[0];
#pragma unroll
        for (int e = 1; e < ES; e++) if (il[e] > u1) { u1 = il[e]; j1 = e; }
        int j2 = -1; float u2 = -1e30f;
#pragma unroll
        for (int e = 0; e < ES; e++) if (e != j1 && il[e] > u2) { u2 = il[e]; j2 = e; }
        float ei = expf(u2 - u1);
        float d2 = 1.0f / (1.0f + ei);
        int ex1 = g * ES + j1, ex2 = g * ES + j2;
        int p1 = atomicAdd(&cnt[ex1], 1);
        toks[(size_t)ex1 * N_TOK + p1] = n * 4 + s * 2;     wgts[(size_t)ex1 * N_TOK + p1] = gw * d2;
        int p2 = atomicAdd(&cnt[ex2], 1);
        toks[(size_t)ex2 * N_TOK + p2] = n * 4 + s * 2 + 1; wgts[(size_t)ex2 * N_TOK + p2] = gw * ei * d2;
    }
}

// ---------------- sparse expert MLPs via bf16 MFMA; XCD-swizzled, no duplicate B reads ----------------
__global__ __launch_bounds__(512) void k_expert_mfma(
        const __hip_bfloat16* __restrict__ h_normb,
        const short* __restrict__ wB1, const float* __restrict__ eb1,
        const short* __restrict__ wB2, const float* __restrict__ eb2,
        const int* __restrict__ cnt, const int* __restrict__ toks,
        const float* __restrict__ wgts, float* __restrict__ part) {
    const int e = blockIdx.x & 31;
    const int slot = blockIdx.x >> 5;
    const int c = cnt[e];
    const int start = slot * BT;
    if (start >= c) return;
    const int m = min(BT, c - start);

    __shared__ short hs[BT][520];
    __shared__ short es[BT][264];
    __shared__ int   tok_s[BT];
    __shared__ float w_s[BT];

    const int tid = threadIdx.x;
    if (tid < BT) {
        bool ok = tid < m;
        tok_s[tid] = ok ? toks[(size_t)e * N_TOK + start + tid] : 0;
        w_s[tid]   = ok ? wgts[(size_t)e * N_TOK + start + tid] : 0.f;
    }
    __syncthreads();
    for (int idx = tid; idx < BT * 64; idx += 512) {
        int t = idx >> 6, ch = idx & 63;
        uint4 v = make_uint4(0, 0, 0, 0);
        if (t < m) v = *((const uint4*)(h_normb + (size_t)(tok_s[t] >> 2) * DM) + ch);
        *(uint4*)&hs[t][ch * 8] = v;
    }
    __syncthreads();

    const int wave = tid >> 6, lane = tid & 63;
    const int quad = lane >> 4, lm = lane & 15;

    {
        const int ng = wave * 2;
        f32x4 acc[2][2];
#pragma unroll
        for (int a = 0; a < 2; a++)
#pragma unroll
            for (int b = 0; b < 2; b++) acc[a][b] = (f32x4)(0.f);
        const short* w1e = wB1 + (size_t)e * DM * DE;
        for (int kb = 0; kb < 16; kb++) {
            bf16x8 a0 = *(const bf16x8*)&hs[lm][kb * 32 + quad * 8];
            bf16x8 a1 = *(const bf16x8*)&hs[16 + lm][kb * 32 + quad * 8];
            const short* wp = w1e + ((size_t)kb * 16 + ng) * 512 + lane * 8;
#pragma unroll
            for (int nt = 0; nt < 2; nt++) {
                bf16x8 b = *(const bf16x8*)(wp + nt * 512);
                acc[0][nt] = MFMA16(a0, b, acc[0][nt]);
                acc[1][nt] = MFMA16(a1, b, acc[1][nt]);
            }
        }
#pragma unroll
        for (int nt = 0; nt < 2; nt++) {
            int col = (ng + nt) * 16 + lm;
            float b1 = eb1[e * DE + col];
#pragma unroll
            for (int mt = 0; mt < 2; mt++)
#pragma unroll
            for (int r = 0; r < 4; r++) {
                int row = mt * 16 + quad * 4 + r;
                es[row][col] = f2bf(gelu_t(acc[mt][nt][r] + b1));
            }
        }
    }
    __syncthreads();

    {
        const int ng2 = wave * 4;
        f32x4 acc[2][4];
#pragma unroll
        for (int a = 0; a < 2; a++)
#pragma unroll
            for (int b = 0; b < 4; b++) acc[a][b] = (f32x4)(0.f);
        const short* w2e = wB2 + (size_t)e * DE * DM;
        for (int kb = 0; kb < 8; kb++) {
            bf16x8 a0 = *(const bf16x8*)&es[lm][kb * 32 + quad * 8];
            bf16x8 a1 = *(const bf16x8*)&es[16 + lm][kb * 32 + quad * 8];
            const short* wp = w2e + ((size_t)kb * 32 + ng2) * 512 + lane * 8;
#pragma unroll
            for (int nt = 0; nt < 4; nt++) {
                bf16x8 b = *(const bf16x8*)(wp + nt * 512);
                acc[0][nt] = MFMA16(a0, b, acc[0][nt]);
                acc[1][nt] = MFMA16(a1, b, acc[1][nt]);
            }
        }
        const float* b2 = eb2 + (size_t)e * DM;
#pragma unroll
        for (int mt = 0; mt < 2; mt++)
#pragma unroll
        for (int r = 0; r < 4; r++) {
            int row = mt * 16 + quad * 4 + r;
            if (row < m) {
                float w = w_s[row];
                float* prow = part + (size_t)tok_s[row] * DM;
#pragma unroll
                for (int nt = 0; nt < 4; nt++) {
                    int col = (ng2 + nt) * 16 + lm;
                    prow[col] = w * (acc[mt][nt][r] + b2[col]);
                }
            }
        }
    }
}

// ---------------- final reduce: out[n] = sum_s part[n*4+s] ----------------
__global__ void k_reduce(const float* __restrict__ part, float* __restrict__ out) {
    int n = blockIdx.x;
    int j = threadIdx.x; // 0..127
    const float4* p = (const float4*)(part + (size_t)n * 4 * DM);
    float4 a = p[j], b = p[128 + j], c = p[256 + j], d = p[384 + j];
    float4 r = make_float4(a.x + b.x + c.x + d.x, a.y + b.y + c.y + d.y,
                           a.z + b.z + c.z + d.z, a.w + b.w + c.w + d.w);
    ((float4*)(out + (size_t)n * DM))[j] = r;
}

extern "C" void kernel_launch(void* const* d_in, const int* in_sizes, int n_in,
                              void* d_out, int out_size, void* d_ws, size_t ws_size,
                              hipStream_t stream) {
    const float* hidden  = (const float*)d_in[0];
    const float* feat    = (const float*)d_in[1];
    const float* pre_g   = (const float*)d_in[2];
    const float* pre_b   = (const float*)d_in[3];
    const float* rh_g    = (const float*)d_in[4];
    const float* rh_b    = (const float*)d_in[5];
    const float* rh_w1   = (const float*)d_in[6];
    const float* rh_b1   = (const float*)d_in[7];
    const float* rh_w2   = (const float*)d_in[8];
    const float* rh_b2   = (const float*)d_in[9];
    const float* sf_g    = (const float*)d_in[10];
    const float* sf_b    = (const float*)d_in[11];
    const float* sf_w1   = (const float*)d_in[12];
    const float* sf_b1   = (const float*)d_in[13];
    const float* sf_w2   = (const float*)d_in[14];
    const float* sf_b2   = (const float*)d_in[15];
    const float* gln_g   = (const float*)d_in[16];
    const float* gln_b   = (const float*)d_in[17];
    const float* gf_w1   = (const float*)d_in[18];
    const float* gf_b1   = (const float*)d_in[19];
    const float* gf_w2   = (const float*)d_in[20];
    const float* gf_b2   = (const float*)d_in[21];
    const float* pgs_w1  = (const float*)d_in[22];
    const float* pgs_b1  = (const float*)d_in[23];
    const float* pgs_w2  = (const float*)d_in[24];
    const float* pgs_b2  = (const float*)d_in[25];
    const float* ir_w1   = (const float*)d_in[26];
    const float* ir_b1   = (const float*)d_in[27];
    const float* ir_w2   = (const float*)d_in[28];
    const float* ir_b2   = (const float*)d_in[29];
    const float* ex_w1   = (const float*)d_in[30];
    const float* ex_b1   = (const float*)d_in[31];
    const float* ex_w2   = (const float*)d_in[32];
    const float* ex_b2   = (const float*)d_in[33];
    float* out = (float*)d_out;

    // workspace carving (256B-aligned)
    char* w = (char*)d_ws;
    auto alloc = [&](size_t bytes) { void* r = (void*)w; w += (bytes + 255) & ~(size_t)255; return r; };
    __hip_bfloat16* h_normb = (__hip_bfloat16*)alloc((size_t)N_TOK * DM * 2);
    float* h_enc = (float*)alloc((size_t)N_TOK * DH * 4);
    float* s_enc = (float*)alloc((size_t)N_TOK * DH * 4);
    float* g_enc = (float*)alloc((size_t)N_TOK * G * DH * 4);
    float* glog  = (float*)alloc((size_t)N_TOK * G * 4);
    float* ilog  = (float*)alloc((size_t)N_TOK * G * ES * 4);
    float* wgts  = (float*)alloc((size_t)E_EXP * N_TOK * 4);
    short* wB1   = (short*)alloc((size_t)E_EXP * DM * DE * 2);
    short* wB2   = (short*)alloc((size_t)E_EXP * DE * DM * 2);
    short* AhsH  = (short*)alloc((size_t)N_TOK * 256 * 2);
    short* AhsM  = (short*)alloc((size_t)N_TOK * 256 * 2);
    short* AhsL  = (short*)alloc((size_t)N_TOK * 256 * 2);
    short* BpgH  = (short*)alloc((size_t)16 * 8 * 512 * 2);
    short* BpgM  = (short*)alloc((size_t)16 * 8 * 512 * 2);
    short* BpgL  = (short*)alloc((size_t)16 * 8 * 512 * 2);
    short* BirH  = (short*)alloc((size_t)G * 16 * 8 * 512 * 2);
    short* BirM  = (short*)alloc((size_t)G * 16 * 8 * 512 * 2);
    short* BirL  = (short*)alloc((size_t)G * 16 * 8 * 512 * 2);
    short* Brh1H = (short*)alloc((size_t)16 * 8 * 512 * 2);
    short* Brh1M = (short*)alloc((size_t)16 * 8 * 512 * 2);
    short* Brh1L = (short*)alloc((size_t)16 * 8 * 512 * 2);
    short* Brh2H = (short*)alloc((size_t)4 * 8 * 512 * 2);
    short* Brh2M = (short*)alloc((size_t)4 * 8 * 512 * 2);
    short* Brh2L = (short*)alloc((size_t)4 * 8 * 512 * 2);
    short* Bsf1H = (short*)alloc((size_t)4 * 8 * 512 * 2);
    short* Bsf1M = (short*)alloc((size_t)4 * 8 * 512 * 2);
    short* Bsf1L = (short*)alloc((size_t)4 * 8 * 512 * 2);
    short* Bsf2H = (short*)alloc((size_t)4 * 8 * 512 * 2);
    short* Bsf2M = (short*)alloc((size_t)4 * 8 * 512 * 2);
    short* Bsf2L = (short*)alloc((size_t)4 * 8 * 512 * 2);
    short* Bgf1H = (short*)alloc((size_t)G * 1 * 8 * 512 * 2);
    short* Bgf1M = (short*)alloc((size_t)G * 1 * 8 * 512 * 2);
    short* Bgf1L = (short*)alloc((size_t)G * 1 * 8 * 512 * 2);
    short* Bgf2H = (short*)alloc((size_t)G * 4 * 8 * 512 * 2);
    short* Bgf2M = (short*)alloc((size_t)G * 4 * 8 * 512 * 2);
    short* Bgf2L = (short*)alloc((size_t)G * 4 * 8 * 512 * 2);
    int* cnt     = (int*)alloc(E_EXP * 4);
    int* toks    = (int*)alloc((size_t)E_EXP * N_TOK * 4);
    // union region (disjoint live ranges, stream-ordered):
    //   hL   [k_ln_hidden -> k_enc_all]    8.4 MB
    //   part [k_expert_mfma -> k_reduce]  33.6 MB
    char* uni   = (char*)alloc((size_t)N_TOK * 4 * DM * 4); // 33.6 MB = max
    float* hL   = (float*)uni;
    float* part = (float*)uni;

    hipMemsetAsync(cnt, 0, E_EXP * sizeof(int), stream);

    // single fused weight-conversion launch (10 jobs)
    ConvJobs J;
    int b0 = 0;
    auto mkjob = [&](int i, const float* s, short* dh, short* dm, short* dl,
                     int KB, int NB, int Kreal, int plain, int nmat) {
        J.j[i] = ConvJob{s, dh, dm, dl, KB, NB, Kreal, plain, b0};
        b0 += KB * nmat;
    };
    mkjob(0, ex_w1, wB1, nullptr, nullptr, 16, 16, 512, 1, E_EXP);
    mkjob(1, ex_w2, wB2, nullptr, nullptr, 8, 32, 256, 1, E_EXP);
    mkjob(2, pgs_w1, BpgH, BpgM, BpgL, 16, 8, 512, 0, 1);
    mkjob(3, ir_w1, BirH, BirM, BirL, 16, 8, 512, 0, G);
    mkjob(4, rh_w1, Brh1H, Brh1M, Brh1L, 16, 8, 512, 0, 1);
    mkjob(5, rh_w2, Brh2H, Brh2M, Brh2L, 4, 8, 128, 0, 1);
    mkjob(6, sf_w1, Bsf1H, Bsf1M, Bsf1L, 4, 8, 128, 0, 1);
    mkjob(7, sf_w2, Bsf2H, Bsf2M, Bsf2L, 4, 8, 128, 0, 1);
    mkjob(8, gf_w1, Bgf1H, Bgf1M, Bgf1L, 1, 8, 16, 0, G);
    mkjob(9, gf_w2, Bgf2H, Bgf2M, Bgf2L, 4, 8, 128, 0, G);
    k_conv_all<<<b0, 256, 0, stream>>>(J);

    k_ln_hidden<<<N_TOK, 256, 0, stream>>>(hidden, pre_g, pre_b, rh_g, rh_b, h_normb, hL);

    // fused encoders: rh(128) + sf(128) + per-(tile,group) genc(1024) = 1280 blocks
    k_enc_all<<<256 + (N_TOK / 32) * G, 256, 0, stream>>>(
        hL, feat, sf_g, sf_b, gln_g, gln_b,
        Brh1H, Brh1M, Brh1L, rh_b1, Brh2H, Brh2M, Brh2L, rh_b2,
        Bsf1H, Bsf1M, Bsf1L, sf_b1, Bsf2H, Bsf2M, Bsf2L, sf_b2,
        Bgf1H, Bgf1M, Bgf1L, gf_b1, Bgf2H, Bgf2M, Bgf2L, gf_b2,
        h_enc, s_enc, g_enc);

    k_stage_hs<<<N_TOK / 16, 256, 0, stream>>>(h_enc, s_enc, AhsH, AhsM, AhsL);

    // router: XCD-swizzled 1D grid (bid&7 = group), g-part staged in-register
    k_router_mfma<<<(N_TOK / 32) * G, 256, 0, stream>>>(AhsH, AhsM, AhsL, h_enc, g_enc,
                                             BpgH, BpgM, BpgL, BirH, BirM, BirL,
                                             pgs_b1, pgs_w2, pgs_b2, ir_b1, ir_w2, ir_b2,
                                             glog, ilog);

    k_topk<<<N_TOK / 256, 256, 0, stream>>>(glog, ilog, cnt, toks, wgts);
    // XCD-swizzled 1D expert grid: bid = slot*32 + e
    k_expert_mfma<<<(N_TOK / BT) * E_EXP, 512, 0, stream>>>(h_normb, wB1, ex_b1, wB2, ex_b2,
                                                            cnt, toks, wgts, part);
    k_reduce<<<N_TOK, 128, 0, stream>>>(part, out);
}

// Round 10
// 335.795 us; speedup vs baseline: 3.2988x; 1.0308x over previous
//
#include <hip/hip_runtime.h>
#include <hip/hip_bf16.h>
#include <math.h>

#define N_TOK 4096
#define DM 512
#define FDIM 128
#define G 8
#define FG 16
#define DH 128
#define DE 256
#define ES 4
#define E_EXP 32
#define LN_EPS 1e-5f
#define BT 32   // expert token tile (MFMA)

typedef __attribute__((ext_vector_type(8))) short bf16x8;  // 8 bf16 = 4 VGPRs
typedef __attribute__((ext_vector_type(4))) float f32x4;

#define MFMA16(a, b, c) __builtin_amdgcn_mfma_f32_16x16x32_bf16((a), (b), (c), 0, 0, 0)

__device__ __forceinline__ float gelu_t(float x) {
    const float c = 0.7978845608028654f; // sqrt(2/pi)
    float x3 = x * x * x;
    return 0.5f * x * (1.0f + tanhf(c * (x + 0.044715f * x3)));
}

__device__ __forceinline__ short f2bf(float f) {
    __hip_bfloat16 h = __float2bfloat16(f);
    return *reinterpret_cast<short*>(&h);
}
__device__ __forceinline__ float bf2f(short s) {
    __hip_bfloat16 h = *reinterpret_cast<__hip_bfloat16*>(&s);
    return __bfloat162float(h);
}
// exact 3-way split: x == bf2f(h)+bf2f(m)+bf2f(l) bit-exactly for fp32 x
__device__ __forceinline__ void split3(float x, short& h, short& m, short& l) {
    h = f2bf(x);
    float r = x - bf2f(h);   // exact in fp32
    m = f2bf(r);
    float r2 = r - bf2f(m);  // exact; <=6 significant bits remain
    l = f2bf(r2);            // exact
}

// ---------------- LN of hidden: pre_ln -> h_norm (bf16) and rh_ln -> hL (fp32) ----------------
__global__ void k_ln_hidden(const float* __restrict__ hidden,
                            const float* __restrict__ pg, const float* __restrict__ pb,
                            const float* __restrict__ rg, const float* __restrict__ rb,
                            __hip_bfloat16* __restrict__ h_normb, float* __restrict__ hL) {
    int n = blockIdx.x;
    int j = threadIdx.x; // 0..255
    const float* x = hidden + (size_t)n * DM;
    float v0 = x[j], v1 = x[j + 256];
    float s = v0 + v1, q = v0 * v0 + v1 * v1;
#pragma unroll
    for (int o = 32; o; o >>= 1) { s += __shfl_down(s, o); q += __shfl_down(q, o); }
    __shared__ float red[8];
    int w = j >> 6;
    if ((j & 63) == 0) { red[w] = s; red[4 + w] = q; }
    __syncthreads();
    float sum = red[0] + red[1] + red[2] + red[3];
    float sq  = red[4] + red[5] + red[6] + red[7];
    float m = sum * (1.0f / DM);
    float var = sq * (1.0f / DM) - m * m;
    float rs = rsqrtf(var + LN_EPS);
    float t0 = (v0 - m) * rs, t1 = (v1 - m) * rs;
    size_t base = (size_t)n * DM;
    h_normb[base + j]       = __float2bfloat16(t0 * pg[j]       + pb[j]);
    h_normb[base + j + 256] = __float2bfloat16(t1 * pg[j + 256] + pb[j + 256]);
    hL[base + j]           = t0 * rg[j]       + rb[j];
    hL[base + j + 256]     = t1 * rg[j + 256] + rb[j + 256];
}

// ---------------- unified weight conversion: plain bf16 or 3-way split, K zero-pad ----------------
struct ConvJob { const float* src; short* dh; short* dm; short* dl;
                 int KB, NB, Kreal, plain, blk0; };
struct ConvJobs { ConvJob j[10]; };

__global__ void k_conv_all(ConvJobs J) {
    int b = blockIdx.x;
    int ji = 0;
#pragma unroll
    for (int i = 1; i < 10; i++) if (b >= J.j[i].blk0) ji = i;
    const ConvJob jb = J.j[ji];
    int rel = b - jb.blk0;
    int mat = rel / jb.KB, kb = rel % jb.KB;
    int ncols = jb.NB * 16;
    const float* s = jb.src + (size_t)mat * jb.Kreal * ncols;
    size_t dbase = ((size_t)mat * jb.KB + kb) * jb.NB * 512;
    for (int p = threadIdx.x; p < jb.NB * 64; p += 256) {
        int nb = p >> 6, lane = p & 63;
        int row0 = kb * 32 + ((lane >> 4) << 3);
        int col = nb * 16 + (lane & 15);
        if (jb.plain) {
            union { short sh[8]; uint4 v; } t;
#pragma unroll
            for (int j = 0; j < 8; j++) {
                float x = (row0 + j < jb.Kreal) ? s[(size_t)(row0 + j) * ncols + col] : 0.f;
                t.sh[j] = f2bf(x);
            }
            *(uint4*)&jb.dh[dbase + (size_t)p * 8] = t.v;
        } else {
            union { short sh[8]; uint4 v; } hi, mi, lo;
#pragma unroll
            for (int j = 0; j < 8; j++) {
                float x = (row0 + j < jb.Kreal) ? s[(size_t)(row0 + j) * ncols + col] : 0.f;
                split3(x, hi.sh[j], mi.sh[j], lo.sh[j]);
            }
            *(uint4*)&jb.dh[dbase + (size_t)p * 8] = hi.v;
            *(uint4*)&jb.dm[dbase + (size_t)p * 8] = mi.v;
            *(uint4*)&jb.dl[dbase + (size_t)p * 8] = lo.v;
        }
    }
}

// ---------------- 2-layer MLP body via 3-split MFMA: Y = gelu(LN?(X)@W1+b1)@W2+b2 ----------------
template <int KB_TOT, bool DO_LN>
__device__ __forceinline__ void enc2_body(
        int bx, char* smem,
        const float* __restrict__ X,
        const float* __restrict__ lng, const float* __restrict__ lnb,
        const short* __restrict__ W1h, const short* __restrict__ W1m, const short* __restrict__ W1l,
        const float* __restrict__ B1,
        const short* __restrict__ W2h, const short* __restrict__ W2m, const short* __restrict__ W2l,
        const float* __restrict__ B2,
        float* __restrict__ Y) {
    constexpr int K = KB_TOT * 32;
    const int n0 = bx * 32;
    const int tid = threadIdx.x;
    const int wave = tid >> 6, lane = tid & 63;
    const int quad = lane >> 4, lm = lane & 15;
    const int mt = wave & 1;
    const int ngb = (wave >> 1) * 4;   // 4 n-tiles per wave

    short (*Ah)[132] = (short(*)[132])smem;
    short (*Am)[132] = (short(*)[132])(smem + 32 * 132 * 2);
    short (*Al)[132] = (short(*)[132])(smem + 2 * 32 * 132 * 2);

    f32x4 acc[4];
#pragma unroll
    for (int i = 0; i < 4; i++) acc[i] = (f32x4)(0.f);

    if (DO_LN) {
        for (int idx = tid; idx < 1024; idx += 256) {
            int row = idx >> 5, c4 = (idx & 31) * 4;
            float4 v = *(const float4*)&X[(size_t)(n0 + row) * K + c4];
            float s = v.x + v.y + v.z + v.w;
            float q = v.x * v.x + v.y * v.y + v.z * v.z + v.w * v.w;
#pragma unroll
            for (int o = 16; o; o >>= 1) { s += __shfl_xor(s, o); q += __shfl_xor(q, o); }
            float mean = s * (1.0f / 128.0f);
            float var = q * (1.0f / 128.0f) - mean * mean;
            float rs = rsqrtf(var + LN_EPS);
            float xv[4] = {(v.x - mean) * rs * lng[c4 + 0] + lnb[c4 + 0],
                           (v.y - mean) * rs * lng[c4 + 1] + lnb[c4 + 1],
                           (v.z - mean) * rs * lng[c4 + 2] + lnb[c4 + 2],
                           (v.w - mean) * rs * lng[c4 + 3] + lnb[c4 + 3]};
#pragma unroll
            for (int j = 0; j < 4; j++) {
                short h, m, l; split3(xv[j], h, m, l);
                Ah[row][c4 + j] = h; Am[row][c4 + j] = m; Al[row][c4 + j] = l;
            }
        }
        __syncthreads();
#pragma unroll
        for (int kb = 0; kb < KB_TOT; kb++) {
            bf16x8 ah = *(const bf16x8*)&Ah[mt * 16 + lm][kb * 32 + quad * 8];
            bf16x8 am = *(const bf16x8*)&Am[mt * 16 + lm][kb * 32 + quad * 8];
            bf16x8 al = *(const bf16x8*)&Al[mt * 16 + lm][kb * 32 + quad * 8];
#pragma unroll
            for (int nt = 0; nt < 4; nt++) {
                size_t bi = (((size_t)kb * 8 + ngb + nt) * 64 + lane) * 8;
                bf16x8 bh = *(const bf16x8*)&W1h[bi];
                bf16x8 bm = *(const bf16x8*)&W1m[bi];
                bf16x8 bl = *(const bf16x8*)&W1l[bi];
                acc[nt] = MFMA16(al, bh, acc[nt]);
                acc[nt] = MFMA16(am, bm, acc[nt]);
                acc[nt] = MFMA16(ah, bl, acc[nt]);
                acc[nt] = MFMA16(am, bh, acc[nt]);
                acc[nt] = MFMA16(ah, bm, acc[nt]);
                acc[nt] = MFMA16(ah, bh, acc[nt]);
            }
        }
    } else {
        for (int kb = 0; kb < KB_TOT; kb++) {
            const float* xs = X + (size_t)(n0 + mt * 16 + lm) * K + kb * 32 + quad * 8;
            float4 x0 = *(const float4*)xs, x1 = *(const float4*)(xs + 4);
            float xv[8] = {x0.x, x0.y, x0.z, x0.w, x1.x, x1.y, x1.z, x1.w};
            bf16x8 ah, am, al;
#pragma unroll
            for (int j = 0; j < 8; j++) {
                short h, m, l; split3(xv[j], h, m, l);
                ah[j] = h; am[j] = m; al[j] = l;
            }
#pragma unroll
            for (int nt = 0; nt < 4; nt++) {
                size_t bi = (((size_t)kb * 8 + ngb + nt) * 64 + lane) * 8;
                bf16x8 bh = *(const bf16x8*)&W1h[bi];
                bf16x8 bm = *(const bf16x8*)&W1m[bi];
                bf16x8 bl = *(const bf16x8*)&W1l[bi];
                acc[nt] = MFMA16(al, bh, acc[nt]);
                acc[nt] = MFMA16(am, bm, acc[nt]);
                acc[nt] = MFMA16(ah, bl, acc[nt]);
                acc[nt] = MFMA16(am, bh, acc[nt]);
                acc[nt] = MFMA16(ah, bm, acc[nt]);
                acc[nt] = MFMA16(ah, bh, acc[nt]);
            }
        }
    }
    __syncthreads();
#pragma unroll
    for (int nt = 0; nt < 4; nt++) {
        int col = (ngb + nt) * 16 + lm;
        float b1 = B1[col];
#pragma unroll
        for (int r = 0; r < 4; r++) {
            int row = mt * 16 + quad * 4 + r;
            short h, m, l; split3(gelu_t(acc[nt][r] + b1), h, m, l);
            Ah[row][col] = h; Am[row][col] = m; Al[row][col] = l;
        }
    }
    __syncthreads();
    f32x4 acc2[4];
#pragma unroll
    for (int i = 0; i < 4; i++) acc2[i] = (f32x4)(0.f);
#pragma unroll
    for (int kb = 0; kb < 4; kb++) {
        bf16x8 ah = *(const bf16x8*)&Ah[mt * 16 + lm][kb * 32 + quad * 8];
        bf16x8 am = *(const bf16x8*)&Am[mt * 16 + lm][kb * 32 + quad * 8];
        bf16x8 al = *(const bf16x8*)&Al[mt * 16 + lm][kb * 32 + quad * 8];
#pragma unroll
        for (int nt = 0; nt < 4; nt++) {
            size_t bi = (((size_t)kb * 8 + ngb + nt) * 64 + lane) * 8;
            bf16x8 bh = *(const bf16x8*)&W2h[bi];
            bf16x8 bm = *(const bf16x8*)&W2m[bi];
            bf16x8 bl = *(const bf16x8*)&W2l[bi];
            acc2[nt] = MFMA16(al, bh, acc2[nt]);
            acc2[nt] = MFMA16(am, bm, acc2[nt]);
            acc2[nt] = MFMA16(ah, bl, acc2[nt]);
            acc2[nt] = MFMA16(am, bh, acc2[nt]);
            acc2[nt] = MFMA16(ah, bm, acc2[nt]);
            acc2[nt] = MFMA16(ah, bh, acc2[nt]);
        }
    }
#pragma unroll
    for (int nt = 0; nt < 4; nt++) {
        int col = (ngb + nt) * 16 + lm;
        float b2 = B2[col];
#pragma unroll
        for (int r = 0; r < 4; r++) {
            int row = mt * 16 + quad * 4 + r;
            Y[(size_t)(n0 + row) * DH + col] = acc2[nt][r] + b2;
        }
    }
}

// ---------------- single-group encoder body: one (32-token tile, group) per block ----------------
__device__ __forceinline__ void genc_one(
        int bx, int g, char* smem,
        const float* __restrict__ feat,
        const float* __restrict__ gln_g, const float* __restrict__ gln_b,
        const short* __restrict__ W1h, const short* __restrict__ W1m, const short* __restrict__ W1l,
        const float* __restrict__ gb1,
        const short* __restrict__ W2h, const short* __restrict__ W2m, const short* __restrict__ W2l,
        const float* __restrict__ gb2,
        float* __restrict__ g_enc) {
    const int n0 = bx * 32;
    const int tid = threadIdx.x;
    const int wave = tid >> 6, lane = tid & 63;
    const int quad = lane >> 4, lm = lane & 15;
    const int mt = wave & 1;
    const int ngb = (wave >> 1) * 4;

    short (*Ah)[132] = (short(*)[132])smem;
    short (*Am)[132] = (short(*)[132])(smem + 8448);
    short (*Al)[132] = (short(*)[132])(smem + 2 * 8448);

    {
        int t = tid >> 3, sub = tid & 7;
        const float* fr = feat + (size_t)(n0 + t) * FDIM + g * FG;
        float xv[FG];
        float mean = 0.f;
#pragma unroll
        for (int i = 0; i < FG; i++) { xv[i] = fr[i]; mean += xv[i]; }
        mean *= (1.0f / FG);
        float var = 0.f;
#pragma unroll
        for (int i = 0; i < FG; i++) { float d = xv[i] - mean; var += d * d; }
        var *= (1.0f / FG);
        float rs = rsqrtf(var + LN_EPS);
#pragma unroll
        for (int j = 0; j < 2; j++) {
            int i = sub * 2 + j;
            float xn = (xv[i] - mean) * rs * gln_g[g * FG + i] + gln_b[g * FG + i];
            short h, m, l; split3(xn, h, m, l);
            Ah[t][i] = h; Am[t][i] = m; Al[t][i] = l;
            Ah[t][16 + i] = 0; Am[t][16 + i] = 0; Al[t][16 + i] = 0;  // K pad to 32
        }
    }
    __syncthreads();
    f32x4 acc[4];
#pragma unroll
    for (int i = 0; i < 4; i++) acc[i] = (f32x4)(0.f);
    {
        bf16x8 ah = *(const bf16x8*)&Ah[mt * 16 + lm][quad * 8];
        bf16x8 am = *(const bf16x8*)&Am[mt * 16 + lm][quad * 8];
        bf16x8 al = *(const bf16x8*)&Al[mt * 16 + lm][quad * 8];
#pragma unroll
        for (int nt = 0; nt < 4; nt++) {
            size_t bi = (((size_t)g * 8 + ngb + nt) * 64 + lane) * 8;  // KB=1 per mat
            bf16x8 bh = *(const bf16x8*)&W1h[bi];
            bf16x8 bm = *(const bf16x8*)&W1m[bi];
            bf16x8 bl = *(const bf16x8*)&W1l[bi];
            acc[nt] = MFMA16(al, bh, acc[nt]);
            acc[nt] = MFMA16(am, bm, acc[nt]);
            acc[nt] = MFMA16(ah, bl, acc[nt]);
            acc[nt] = MFMA16(am, bh, acc[nt]);
            acc[nt] = MFMA16(ah, bm, acc[nt]);
            acc[nt] = MFMA16(ah, bh, acc[nt]);
        }
    }
    __syncthreads();
#pragma unroll
    for (int nt = 0; nt < 4; nt++) {
        int col = (ngb + nt) * 16 + lm;
        float b1 = gb1[g * DH + col];
#pragma unroll
        for (int r = 0; r < 4; r++) {
            int row = mt * 16 + quad * 4 + r;
            short h, m, l; split3(gelu_t(acc[nt][r] + b1), h, m, l);
            Ah[row][col] = h; Am[row][col] = m; Al[row][col] = l;
        }
    }
    __syncthreads();
    f32x4 acc2[4];
#pragma unroll
    for (int i = 0; i < 4; i++) acc2[i] = (f32x4)(0.f);
#pragma unroll
    for (int kb = 0; kb < 4; kb++) {
        bf16x8 a2h = *(const bf16x8*)&Ah[mt * 16 + lm][kb * 32 + quad * 8];
        bf16x8 a2m = *(const bf16x8*)&Am[mt * 16 + lm][kb * 32 + quad * 8];
        bf16x8 a2l = *(const bf16x8*)&Al[mt * 16 + lm][kb * 32 + quad * 8];
#pragma unroll
        for (int nt = 0; nt < 4; nt++) {
            size_t bi = ((((size_t)g * 4 + kb) * 8 + ngb + nt) * 64 + lane) * 8;
            bf16x8 bh = *(const bf16x8*)&W2h[bi];
            bf16x8 bm = *(const bf16x8*)&W2m[bi];
            bf16x8 bl = *(const bf16x8*)&W2l[bi];
            acc2[nt] = MFMA16(a2l, bh, acc2[nt]);
            acc2[nt] = MFMA16(a2m, bm, acc2[nt]);
            acc2[nt] = MFMA16(a2h, bl, acc2[nt]);
            acc2[nt] = MFMA16(a2m, bh, acc2[nt]);
            acc2[nt] = MFMA16(a2h, bm, acc2[nt]);
            acc2[nt] = MFMA16(a2h, bh, acc2[nt]);
        }
    }
#pragma unroll
    for (int nt = 0; nt < 4; nt++) {
        int col = (ngb + nt) * 16 + lm;
        float b2 = gb2[g * DH + col];
#pragma unroll
        for (int r = 0; r < 4; r++) {
            int row = mt * 16 + quad * 4 + r;
            g_enc[((size_t)(n0 + row) * G + g) * DH + col] = acc2[nt][r] + b2;
        }
    }
}

// ---------------- fused encoder launch: rh(128) + sf(128) + genc(1024) blocks ----------------
__global__ __launch_bounds__(256) void k_enc_all(
        const float* __restrict__ hL, const float* __restrict__ feat,
        const float* __restrict__ sf_g, const float* __restrict__ sf_b,
        const float* __restrict__ gln_g, const float* __restrict__ gln_b,
        const short* Brh1H, const short* Brh1M, const short* Brh1L, const float* rh_b1,
        const short* Brh2H, const short* Brh2M, const short* Brh2L, const float* rh_b2,
        const short* Bsf1H, const short* Bsf1M, const short* Bsf1L, const float* sf_b1,
        const short* Bsf2H, const short* Bsf2M, const short* Bsf2L, const float* sf_b2,
        const short* Bgf1H, const short* Bgf1M, const short* Bgf1L, const float* gf_b1,
        const short* Bgf2H, const short* Bgf2M, const short* Bgf2L, const float* gf_b2,
        float* __restrict__ h_enc, float* __restrict__ s_enc, float* __restrict__ g_enc) {
    __shared__ __align__(16) char smem[3 * 8448];   // 25.3 KB -> 6 blocks/CU
    int bid = blockIdx.x;
    if (bid < 128)
        enc2_body<16, false>(bid, smem, hL, nullptr, nullptr,
                             Brh1H, Brh1M, Brh1L, rh_b1, Brh2H, Brh2M, Brh2L, rh_b2, h_enc);
    else if (bid < 256)
        enc2_body<4, true>(bid - 128, smem, feat, sf_g, sf_b,
                           Bsf1H, Bsf1M, Bsf1L, sf_b1, Bsf2H, Bsf2M, Bsf2L, sf_b2, s_enc);
    else {
        int idx = bid - 256;    // (idx & 7) = group -> XCD affinity for gf weights
        genc_one(idx >> 3, idx & 7, smem, feat, gln_g, gln_b,
                 Bgf1H, Bgf1M, Bgf1L, gf_b1, Bgf2H, Bgf2M, Bgf2L, gf_b2, g_enc);
    }
}

// ---------------- stage A-fragments (3-way split bf16) for router k<256 (h|s) ----------------
__global__ void k_stage_hs(const float* __restrict__ h_enc, const float* __restrict__ s_enc,
                           short* __restrict__ Ah, short* __restrict__ Am, short* __restrict__ Al) {
    int T16 = blockIdx.x;
    for (int slot = threadIdx.x; slot < 512; slot += 256) {
        int kb = slot >> 6, lane = slot & 63;
        int quad = lane >> 4, lm = lane & 15;
        int n = T16 * 16 + lm;
        int c0 = kb * 32 + quad * 8; // 0..255
        const float* src = (c0 < 128) ? (h_enc + (size_t)n * DH + c0)
                                      : (s_enc + (size_t)n * DH + (c0 - 128));
        float4 x0 = *(const float4*)src;
        float4 x1 = *(const float4*)(src + 4);
        float xv[8] = {x0.x, x0.y, x0.z, x0.w, x1.x, x1.y, x1.z, x1.w};
        union { short sh[8]; uint4 v; } hi, mi, lo;
#pragma unroll
        for (int j = 0; j < 8; j++) split3(xv[j], hi.sh[j], mi.sh[j], lo.sh[j]);
        size_t base = ((size_t)T16 * 512 + slot) * 8;
        *(uint4*)&Ah[base] = hi.v;
        *(uint4*)&Am[base] = mi.v;
        *(uint4*)&Al[base] = lo.v;
    }
}

// ---------------- MFMA router v3: 64 tokens x 1 group, 8 waves, LDS-staged A (4-kb chunks) ----------------
// Waves 0-3: pg, waves 4-7: ir. Each wave: 4 m-tiles x 2 n-tiles. A fragments staged once per
// block per chunk (A_hs = copy, g-part = split3 once per element), read via ds_read_b128.
__global__ __launch_bounds__(512) void k_router_mfma(
        const short* __restrict__ AhsH, const short* __restrict__ AhsM, const short* __restrict__ AhsL,
        const float* __restrict__ h_enc, const float* __restrict__ g_enc,
        const short* __restrict__ BpgH, const short* __restrict__ BpgM, const short* __restrict__ BpgL,
        const short* __restrict__ BirH, const short* __restrict__ BirM, const short* __restrict__ BirL,
        const float* __restrict__ pb1, const float* __restrict__ pw2, const float* __restrict__ pb2,
        const float* __restrict__ ib1, const float* __restrict__ iw2, const float* __restrict__ ib2,
        float* __restrict__ glog, float* __restrict__ ilog) {
    const int g = blockIdx.x & 7;       // group -> XCD affinity for B + g_enc
    const int bx = blockIdx.x >> 3;     // 64-token tile (0..63)
    const int n0 = bx * 64;
    const int tid = threadIdx.x;
    const int wave = tid >> 6, lane = tid & 63;
    const int quad = lane >> 4, lm = lane & 15;
    const bool is_pg = wave < 4;
    const int nbase = (wave & 3) * 2;   // 2 n-tiles per wave, 4 waves cover 8
    const short* Bh = is_pg ? BpgH : (BirH + (size_t)g * 65536);
    const short* Bm = is_pg ? BpgM : (BirM + (size_t)g * 65536);
    const short* Bl = is_pg ? BpgL : (BirL + (size_t)g * 65536);

    // LDS: A staging for one 4-kb chunk: [split 3][kbl 4][t16 4][lane 64][8 shorts] = 48 KB.
    // Epilogue (2 x 32x129 fp32 = 33 KB) aliases it after the K-loop.
    __shared__ __align__(16) char smem[49152];

    f32x4 acc[4][2];
#pragma unroll
    for (int mt = 0; mt < 4; mt++)
#pragma unroll
        for (int nt = 0; nt < 2; nt++) acc[mt][nt] = (f32x4)(0.f);

    for (int ch = 0; ch < 4; ch++) {
        __syncthreads();   // previous chunk's LDS reads complete
        // stage chunk: items = (kbl, t16, lane2)
        for (int idx = tid; idx < 1024; idx += 512) {
            int kbl = idx >> 8, rem = idx & 255;
            int t16 = rem >> 6, lane2 = rem & 63;
            int gkb = ch * 4 + kbl;
            size_t loff = (size_t)kbl * 4096 + t16 * 1024 + (size_t)lane2 * 16;
            if (gkb < 8) {
                int T16g = bx * 4 + t16;
                size_t ai = (((size_t)T16g * 8 + gkb) * 64 + lane2) * 8;
                *(uint4*)(smem + loff)         = *(const uint4*)&AhsH[ai];
                *(uint4*)(smem + 16384 + loff) = *(const uint4*)&AhsM[ai];
                *(uint4*)(smem + 32768 + loff) = *(const uint4*)&AhsL[ai];
            } else {
                int n = n0 + t16 * 16 + (lane2 & 15);
                int c0 = (gkb - 8) * 32 + (lane2 >> 4) * 8;
                float xv[8];
                if (c0 < 128) {
                    const float* gs = g_enc + ((size_t)n * G + g) * DH + c0;
                    float4 x0 = *(const float4*)gs, x1 = *(const float4*)(gs + 4);
                    xv[0]=x0.x; xv[1]=x0.y; xv[2]=x0.z; xv[3]=x0.w;
                    xv[4]=x1.x; xv[5]=x1.y; xv[6]=x1.z; xv[7]=x1.w;
                } else {
                    int c = c0 - 128;
                    const float* gs = g_enc + ((size_t)n * G + g) * DH + c;
                    const float* hsrc = h_enc + (size_t)n * DH + c;
                    float4 g0 = *(const float4*)gs, g1 = *(const float4*)(gs + 4);
                    float4 h0 = *(const float4*)hsrc, h1 = *(const float4*)(hsrc + 4);
                    xv[0]=h0.x*g0.x; xv[1]=h0.y*g0.y; xv[2]=h0.z*g0.z; xv[3]=h0.w*g0.w;
                    xv[4]=h1.x*g1.x; xv[5]=h1.y*g1.y; xv[6]=h1.z*g1.z; xv[7]=h1.w*g1.w;
                }
                union { short sh[8]; uint4 v; } hi, mi, lo;
#pragma unroll
                for (int j = 0; j < 8; j++) split3(xv[j], hi.sh[j], mi.sh[j], lo.sh[j]);
                *(uint4*)(smem + loff)         = hi.v;
                *(uint4*)(smem + 16384 + loff) = mi.v;
                *(uint4*)(smem + 32768 + loff) = lo.v;
            }
        }
        __syncthreads();
        // compute chunk
#pragma unroll
        for (int kbl = 0; kbl < 4; kbl++) {
            int kb = ch * 4 + kbl;
            bf16x8 Ahf[4], Amf[4], Alf[4];
#pragma unroll
            for (int mt = 0; mt < 4; mt++) {
                size_t loff = (size_t)kbl * 4096 + mt * 1024 + (size_t)lane * 16;
                Ahf[mt] = *(const bf16x8*)(smem + loff);
                Amf[mt] = *(const bf16x8*)(smem + 16384 + loff);
                Alf[mt] = *(const bf16x8*)(smem + 32768 + loff);
            }
#pragma unroll
            for (int nt = 0; nt < 2; nt++) {
                int nb = nbase + nt;
                size_t bi = (((size_t)kb * 8 + nb) * 64 + lane) * 8;
                bf16x8 bh = *(const bf16x8*)&Bh[bi];
                bf16x8 bm = *(const bf16x8*)&Bm[bi];
                bf16x8 bl = *(const bf16x8*)&Bl[bi];
#pragma unroll
                for (int mt = 0; mt < 4; mt++) {
                    acc[mt][nt] = MFMA16(Alf[mt], bh, acc[mt][nt]);
                    acc[mt][nt] = MFMA16(Amf[mt], bm, acc[mt][nt]);
                    acc[mt][nt] = MFMA16(Ahf[mt], bl, acc[mt][nt]);
                    acc[mt][nt] = MFMA16(Amf[mt], bh, acc[mt][nt]);
                    acc[mt][nt] = MFMA16(Ahf[mt], bm, acc[mt][nt]);
                    acc[mt][nt] = MFMA16(Ahf[mt], bh, acc[mt][nt]);
                }
            }
        }
    }

    // epilogue: two 32-row halves reusing staging LDS (ph 32x129 + ih 32x129 = 33 KB)
    float (*ph)[129] = (float(*)[129])smem;
    float (*ih)[129] = (float(*)[129])(smem + 32 * 129 * 4);
    for (int h = 0; h < 2; h++) {
        __syncthreads();   // h=0: K-loop LDS reads done; h=1: prev half's logit reads done
#pragma unroll
        for (int mi = 0; mi < 2; mi++) {
            int mt = 2 * h + mi;
#pragma unroll
            for (int nt = 0; nt < 2; nt++) {
                int col = (nbase + nt) * 16 + lm;
                float b1 = is_pg ? pb1[col] : ib1[g * DH + col];
                float* dst = is_pg ? &ph[0][0] : &ih[0][0];
#pragma unroll
                for (int r = 0; r < 4; r++) {
                    int row = mi * 16 + quad * 4 + r;
                    dst[row * 129 + col] = gelu_t(acc[mt][nt][r] + b1);
                }
            }
        }
        __syncthreads();
        if (tid < 32) {
            float s = pb2[0];
            for (int i = 0; i < DH; i++) s += ph[tid][i] * pw2[i];
            glog[(size_t)(n0 + h * 32 + tid) * G + g] = s; // TEMP = 1.0
        } else if (tid >= 128 && tid < 256) {
            int t = (tid - 128) >> 2, e = (tid - 128) & 3;
            float s = ib2[g * ES + e];
            const float* w = iw2 + (size_t)g * DH * ES;
            for (int i = 0; i < DH; i++) s += ih[t][i] * w[i * ES + e];
            ilog[((size_t)(n0 + h * 32 + t) * G + g) * ES + e] = s;
        }
    }
}

// ---------------- top-k softmax + dispatch to per-expert lists ----------------
__global__ void k_topk(const float* __restrict__ glog, const float* __restrict__ ilog,
                       int* __restrict__ cnt, int* __restrict__ toks, float* __restrict__ wgts) {
    int n = blockIdx.x * blockDim.x + threadIdx.x;
    if (n >= N_TOK) return;
    float gl[G];
#pragma unroll
    for (int g = 0; g < G; g++) gl[g] = glog[(size_t)n * G + g];
    int i1 = 0; float v1 = gl[0];
#pragma unroll
    for (int g = 1; g < G; g++) if (gl[g] > v1) { v1 = gl[g]; i1 = g; }
    int i2 = -1; float v2 = -1e30f;
#pragma unroll
    for (int g = 0; g < G; g++) if (g != i1 && gl[g] > v2) { v2 = gl[g]; i2 = g; }
    float eg = expf(v2 - v1);
    float den = 1.0f / (1.0f + eg);
    float gw_sel[2] = { den, eg * den };
    int g_sel[2] = { i1, i2 };
#pragma unroll
    for (int s = 0; s < 2; s++) {
        int g = g_sel[s]; float gw = gw_sel[s];
        float il[ES];
#pragma unroll
        for (int e = 0; e < ES; e++) il[e] = ilog[((size_t)n * G + g) * ES + e];
        int j1 = 0; float u1 = il[0];
#pragma unroll
        for (int e = 1; e < ES; e++) if (il[e] > u1) { u1 = il[e]; j1 = e; }
        int j2 = -1; float u2 = -1e30f;
#pragma unroll
        for (int e = 0; e < ES; e++) if (e != j1 && il[e] > u2) { u2 = il[e]; j2 = e; }
        float ei = expf(u2 - u1);
        float d2 = 1.0f / (1.0f + ei);
        int ex1 = g * ES + j1, ex2 = g * ES + j2;
        int p1 = atomicAdd(&cnt[ex1], 1);
        toks[(size_t)ex1 * N_TOK + p1] = n * 4 + s * 2;     wgts[(size_t)ex1 * N_TOK + p1] = gw * d2;
        int p2 = atomicAdd(&cnt[ex2], 1);
        toks[(size_t)ex2 * N_TOK + p2] = n * 4 + s * 2 + 1; wgts[(size_t)ex2 * N_TOK + p2] = gw * ei * d2;
    }
}

// ---------------- sparse expert MLPs via bf16 MFMA; XCD-swizzled, no duplicate B reads ----------------
__global__ __launch_bounds__(512) void k_expert_mfma(
        const __hip_bfloat16* __restrict__ h_normb,
        const short* __restrict__ wB1, const float* __restrict__ eb1,
        const short* __restrict__ wB2, const float* __restrict__ eb2,
        const int* __restrict__ cnt, const int* __restrict__ toks,
        const float* __restrict__ wgts, float* __restrict__ part) {
    const int e = blockIdx.x & 31;
    const int slot = blockIdx.x >> 5;
    const int c = cnt[e];
    const int start = slot * BT;
    if (start >= c) return;
    const int m = min(BT, c - start);

    __shared__ short hs[BT][520];
    __shared__ short es[BT][264];
    __shared__ int   tok_s[BT];
    __shared__ float w_s[BT];

    const int tid = threadIdx.x;
    if (tid < BT) {
        bool ok = tid < m;
        tok_s[tid] = ok ? toks[(size_t)e * N_TOK + start + tid] : 0;
        w_s[tid]   = ok ? wgts[(size_t)e * N_TOK + start + tid] : 0.f;
    }
    __syncthreads();
    for (int idx = tid; idx < BT * 64; idx += 512) {
        int t = idx >> 6, ch = idx & 63;
        uint4 v = make_uint4(0, 0, 0, 0);
        if (t < m) v = *((const uint4*)(h_normb + (size_t)(tok_s[t] >> 2) * DM) + ch);
        *(uint4*)&hs[t][ch * 8] = v;
    }
    __syncthreads();

    const int wave = tid >> 6, lane = tid & 63;
    const int quad = lane >> 4, lm = lane & 15;

    {
        const int ng = wave * 2;
        f32x4 acc[2][2];
#pragma unroll
        for (int a = 0; a < 2; a++)
#pragma unroll
            for (int b = 0; b < 2; b++) acc[a][b] = (f32x4)(0.f);
        const short* w1e = wB1 + (size_t)e * DM * DE;
        for (int kb = 0; kb < 16; kb++) {
            bf16x8 a0 = *(const bf16x8*)&hs[lm][kb * 32 + quad * 8];
            bf16x8 a1 = *(const bf16x8*)&hs[16 + lm][kb * 32 + quad * 8];
            const short* wp = w1e + ((size_t)kb * 16 + ng) * 512 + lane * 8;
#pragma unroll
            for (int nt = 0; nt < 2; nt++) {
                bf16x8 b = *(const bf16x8*)(wp + nt * 512);
                acc[0][nt] = MFMA16(a0, b, acc[0][nt]);
                acc[1][nt] = MFMA16(a1, b, acc[1][nt]);
            }
        }
#pragma unroll
        for (int nt = 0; nt < 2; nt++) {
            int col = (ng + nt) * 16 + lm;
            float b1 = eb1[e * DE + col];
#pragma unroll
            for (int mt = 0; mt < 2; mt++)
#pragma unroll
            for (int r = 0; r < 4; r++) {
                int row = mt * 16 + quad * 4 + r;
                es[row][col] = f2bf(gelu_t(acc[mt][nt][r] + b1));
            }
        }
    }
    __syncthreads();

    {
        const int ng2 = wave * 4;
        f32x4 acc[2][4];
#pragma unroll
        for (int a = 0; a < 2; a++)
#pragma unroll
            for (int b = 0; b < 4; b++) acc[a][b] = (f32x4)(0.f);
        const short* w2e = wB2 + (size_t)e * DE * DM;
        for (int kb = 0; kb < 8; kb++) {
            bf16x8 a0 = *(const bf16x8*)&es[lm][kb * 32 + quad * 8];
            bf16x8 a1 = *(const bf16x8*)&es[16 + lm][kb * 32 + quad * 8];
            const short* wp = w2e + ((size_t)kb * 32 + ng2) * 512 + lane * 8;
#pragma unroll
            for (int nt = 0; nt < 4; nt++) {
                bf16x8 b = *(const bf16x8*)(wp + nt * 512);
                acc[0][nt] = MFMA16(a0, b, acc[0][nt]);
                acc[1][nt] = MFMA16(a1, b, acc[1][nt]);
            }
        }
        const float* b2 = eb2 + (size_t)e * DM;
#pragma unroll
        for (int mt = 0; mt < 2; mt++)
#pragma unroll
        for (int r = 0; r < 4; r++) {
            int row = mt * 16 + quad * 4 + r;
            if (row < m) {
                float w = w_s[row];
                float* prow = part + (size_t)tok_s[row] * DM;
#pragma unroll
                for (int nt = 0; nt < 4; nt++) {
                    int col = (ng2 + nt) * 16 + lm;
                    prow[col] = w * (acc[mt][nt][r] + b2[col]);
                }
            }
        }
    }
}

// ---------------- final reduce: out[n] = sum_s part[n*4+s] ----------------
__global__ void k_reduce(const float* __restrict__ part, float* __restrict__ out) {
    int n = blockIdx.x;
    int j = threadIdx.x; // 0..127
    const float4* p = (const float4*)(part + (size_t)n * 4 * DM);
    float4 a = p[j], b = p[128 + j], c = p[256 + j], d = p[384 + j];
    float4 r = make_float4(a.x + b.x + c.x + d.x, a.y + b.y + c.y + d.y,
                           a.z + b.z + c.z + d.z, a.w + b.w + c.w + d.w);
    ((float4*)(out + (size_t)n * DM))[j] = r;
}

extern "C" void kernel_launch(void* const* d_in, const int* in_sizes, int n_in,
                              void* d_out, int out_size, void* d_ws, size_t ws_size,
                              hipStream_t stream) {
    const float* hidden  = (const float*)d_in[0];
    const float* feat    = (const float*)d_in[1];
    const float* pre_g   = (const float*)d_in[2];
    const float* pre_b   = (const float*)d_in[3];
    const float* rh_g    = (const float*)d_in[4];
    const float* rh_b    = (const float*)d_in[5];
    const float* rh_w1   = (const float*)d_in[6];
    const float* rh_b1   = (const float*)d_in[7];
    const float* rh_w2   = (const float*)d_in[8];
    const float* rh_b2   = (const float*)d_in[9];
    const float* sf_g    = (const float*)d_in[10];
    const float* sf_b    = (const float*)d_in[11];
    const float* sf_w1   = (const float*)d_in[12];
    const float* sf_b1   = (const float*)d_in[13];
    const float* sf_w2   = (const float*)d_in[14];
    const float* sf_b2   = (const float*)d_in[15];
    const float* gln_g   = (const float*)d_in[16];
    const float* gln_b   = (const float*)d_in[17];
    const float* gf_w1   = (const float*)d_in[18];
    const float* gf_b1   = (const float*)d_in[19];
    const float* gf_w2   = (const float*)d_in[20];
    const float* gf_b2   = (const float*)d_in[21];
    const float* pgs_w1  = (const float*)d_in[22];
    const float* pgs_b1  = (const float*)d_in[23];
    const float* pgs_w2  = (const float*)d_in[24];
    const float* pgs_b2  = (const float*)d_in[25];
    const float* ir_w1   = (const float*)d_in[26];
    const float* ir_b1   = (const float*)d_in[27];
    const float* ir_w2   = (const float*)d_in[28];
    const float* ir_b2   = (const float*)d_in[29];
    const float* ex_w1   = (const float*)d_in[30];
    const float* ex_b1   = (const float*)d_in[31];
    const float* ex_w2   = (const float*)d_in[32];
    const float* ex_b2   = (const float*)d_in[33];
    float* out = (float*)d_out;

    // workspace carving (256B-aligned)
    char* w = (char*)d_ws;
    auto alloc = [&](size_t bytes) { void* r = (void*)w; w += (bytes + 255) & ~(size_t)255; return r; };
    __hip_bfloat16* h_normb = (__hip_bfloat16*)alloc((size_t)N_TOK * DM * 2);
    float* h_enc = (float*)alloc((size_t)N_TOK * DH * 4);
    float* s_enc = (float*)alloc((size_t)N_TOK * DH * 4);
    float* g_enc = (float*)alloc((size_t)N_TOK * G * DH * 4);
    float* glog  = (float*)alloc((size_t)N_TOK * G * 4);
    float* ilog  = (float*)alloc((size_t)N_TOK * G * ES * 4);
    float* wgts  = (float*)alloc((size_t)E_EXP * N_TOK * 4);
    short* wB1   = (short*)alloc((size_t)E_EXP * DM * DE * 2);
    short* wB2   = (short*)alloc((size_t)E_EXP * DE * DM * 2);
    short* AhsH  = (short*)alloc((size_t)N_TOK * 256 * 2);
    short* AhsM  = (short*)alloc((size_t)N_TOK * 256 * 2);
    short* AhsL  = (short*)alloc((size_t)N_TOK * 256 * 2);
    short* BpgH  = (short*)alloc((size_t)16 * 8 * 512 * 2);
    short* BpgM  = (short*)alloc((size_t)16 * 8 * 512 * 2);
    short* BpgL  = (short*)alloc((size_t)16 * 8 * 512 * 2);
    short* BirH  = (short*)alloc((size_t)G * 16 * 8 * 512 * 2);
    short* BirM  = (short*)alloc((size_t)G * 16 * 8 * 512 * 2);
    short* BirL  = (short*)alloc((size_t)G * 16 * 8 * 512 * 2);
    short* Brh1H = (short*)alloc((size_t)16 * 8 * 512 * 2);
    short* Brh1M = (short*)alloc((size_t)16 * 8 * 512 * 2);
    short* Brh1L = (short*)alloc((size_t)16 * 8 * 512 * 2);
    short* Brh2H = (short*)alloc((size_t)4 * 8 * 512 * 2);
    short* Brh2M = (short*)alloc((size_t)4 * 8 * 512 * 2);
    short* Brh2L = (short*)alloc((size_t)4 * 8 * 512 * 2);
    short* Bsf1H = (short*)alloc((size_t)4 * 8 * 512 * 2);
    short* Bsf1M = (short*)alloc((size_t)4 * 8 * 512 * 2);
    short* Bsf1L = (short*)alloc((size_t)4 * 8 * 512 * 2);
    short* Bsf2H = (short*)alloc((size_t)4 * 8 * 512 * 2);
    short* Bsf2M = (short*)alloc((size_t)4 * 8 * 512 * 2);
    short* Bsf2L = (short*)alloc((size_t)4 * 8 * 512 * 2);
    short* Bgf1H = (short*)alloc((size_t)G * 1 * 8 * 512 * 2);
    short* Bgf1M = (short*)alloc((size_t)G * 1 * 8 * 512 * 2);
    short* Bgf1L = (short*)alloc((size_t)G * 1 * 8 * 512 * 2);
    short* Bgf2H = (short*)alloc((size_t)G * 4 * 8 * 512 * 2);
    short* Bgf2M = (short*)alloc((size_t)G * 4 * 8 * 512 * 2);
    short* Bgf2L = (short*)alloc((size_t)G * 4 * 8 * 512 * 2);
    int* cnt     = (int*)alloc(E_EXP * 4);
    int* toks    = (int*)alloc((size_t)E_EXP * N_TOK * 4);
    // union region (disjoint live ranges, stream-ordered):
    //   hL   [k_ln_hidden -> k_enc_all]    8.4 MB
    //   part [k_expert_mfma -> k_reduce]  33.6 MB
    char* uni   = (char*)alloc((size_t)N_TOK * 4 * DM * 4); // 33.6 MB = max
    float* hL   = (float*)uni;
    float* part = (float*)uni;

    hipMemsetAsync(cnt, 0, E_EXP * sizeof(int), stream);

    // single fused weight-conversion launch (10 jobs)
    ConvJobs J;
    int b0 = 0;
    auto mkjob = [&](int i, const float* s, short* dh, short* dm, short* dl,
                     int KB, int NB, int Kreal, int plain, int nmat) {
        J.j[i] = ConvJob{s, dh, dm, dl, KB, NB, Kreal, plain, b0};
        b0 += KB * nmat;
    };
    mkjob(0, ex_w1, wB1, nullptr, nullptr, 16, 16, 512, 1, E_EXP);
    mkjob(1, ex_w2, wB2, nullptr, nullptr, 8, 32, 256, 1, E_EXP);
    mkjob(2, pgs_w1, BpgH, BpgM, BpgL, 16, 8, 512, 0, 1);
    mkjob(3, ir_w1, BirH, BirM, BirL, 16, 8, 512, 0, G);
    mkjob(4, rh_w1, Brh1H, Brh1M, Brh1L, 16, 8, 512, 0, 1);
    mkjob(5, rh_w2, Brh2H, Brh2M, Brh2L, 4, 8, 128, 0, 1);
    mkjob(6, sf_w1, Bsf1H, Bsf1M, Bsf1L, 4, 8, 128, 0, 1);
    mkjob(7, sf_w2, Bsf2H, Bsf2M, Bsf2L, 4, 8, 128, 0, 1);
    mkjob(8, gf_w1, Bgf1H, Bgf1M, Bgf1L, 1, 8, 16, 0, G);
    mkjob(9, gf_w2, Bgf2H, Bgf2M, Bgf2L, 4, 8, 128, 0, G);
    k_conv_all<<<b0, 256, 0, stream>>>(J);

    k_ln_hidden<<<N_TOK, 256, 0, stream>>>(hidden, pre_g, pre_b, rh_g, rh_b, h_normb, hL);

    // fused encoders: rh(128) + sf(128) + per-(tile,group) genc(1024) = 1280 blocks
    k_enc_all<<<256 + (N_TOK / 32) * G, 256, 0, stream>>>(
        hL, feat, sf_g, sf_b, gln_g, gln_b,
        Brh1H, Brh1M, Brh1L, rh_b1, Brh2H, Brh2M, Brh2L, rh_b2,
        Bsf1H, Bsf1M, Bsf1L, sf_b1, Bsf2H, Bsf2M, Bsf2L, sf_b2,
        Bgf1H, Bgf1M, Bgf1L, gf_b1, Bgf2H, Bgf2M, Bgf2L, gf_b2,
        h_enc, s_enc, g_enc);

    k_stage_hs<<<N_TOK / 16, 256, 0, stream>>>(h_enc, s_enc, AhsH, AhsM, AhsL);

    // router v3: 64-token tiles, 512 threads, LDS-staged A; g = bid&7 -> XCD affinity
    k_router_mfma<<<(N_TOK / 64) * G, 512, 0, stream>>>(AhsH, AhsM, AhsL, h_enc, g_enc,
                                             BpgH, BpgM, BpgL, BirH, BirM, BirL,
                                             pgs_b1, pgs_w2, pgs_b2, ir_b1, ir_w2, ir_b2,
                                             glog, ilog);

    k_topk<<<N_TOK / 256, 256, 0, stream>>>(glog, ilog, cnt, toks, wgts);
    // XCD-swizzled 1D expert grid: bid = slot*32 + e
    k_expert_mfma<<<(N_TOK / BT) * E_EXP, 512, 0, stream>>>(h_normb, wB1, ex_b1, wB2, ex_b2,
                                                            cnt, toks, wgts, part);
    k_reduce<<<N_TOK, 128, 0, stream>>>(part, out);
}

// Round 11
// 320.743 us; speedup vs baseline: 3.4536x; 1.0469x over previous
//
#include <hip/hip_runtime.h>
#include <hip/hip_bf16.h>
#include <math.h>

#define N_TOK 4096
#define DM 512
#define FDIM 128
#define G 8
#define FG 16
#define DH 128
#define DE 256
#define ES 4
#define E_EXP 32
#define LN_EPS 1e-5f
#define BT 32   // expert token tile (MFMA)

typedef __attribute__((ext_vector_type(8))) short bf16x8;  // 8 bf16 = 4 VGPRs
typedef __attribute__((ext_vector_type(4))) float f32x4;

#define MFMA16(a, b, c) __builtin_amdgcn_mfma_f32_16x16x32_bf16((a), (b), (c), 0, 0, 0)

__device__ __forceinline__ float gelu_t(float x) {
    const float c = 0.7978845608028654f; // sqrt(2/pi)
    float x3 = x * x * x;
    return 0.5f * x * (1.0f + tanhf(c * (x + 0.044715f * x3)));
}

__device__ __forceinline__ short f2bf(float f) {
    __hip_bfloat16 h = __float2bfloat16(f);
    return *reinterpret_cast<short*>(&h);
}
__device__ __forceinline__ float bf2f(short s) {
    __hip_bfloat16 h = *reinterpret_cast<__hip_bfloat16*>(&s);
    return __bfloat162float(h);
}
// exact 3-way split: x == bf2f(h)+bf2f(m)+bf2f(l) bit-exactly for fp32 x
__device__ __forceinline__ void split3(float x, short& h, short& m, short& l) {
    h = f2bf(x);
    float r = x - bf2f(h);   // exact in fp32
    m = f2bf(r);
    float r2 = r - bf2f(m);  // exact; <=6 significant bits remain
    l = f2bf(r2);            // exact
}

// ---------------- fused pre-pass: weight conversion jobs + LN(hidden) ----------------
struct ConvJob { const float* src; short* dh; short* dm; short* dl;
                 int KB, NB, Kreal, plain, blk0; };
struct ConvJobs { ConvJob j[10]; };

__global__ void k_pre(ConvJobs J, int nconv,
                      const float* __restrict__ hidden,
                      const float* __restrict__ pg, const float* __restrict__ pb,
                      const float* __restrict__ rg, const float* __restrict__ rb,
                      __hip_bfloat16* __restrict__ h_normb, float* __restrict__ hL) {
    int b = blockIdx.x;
    if (b >= nconv) {
        // -------- LN of hidden: pre_ln -> h_norm (bf16) and rh_ln -> hL (fp32) --------
        int n = b - nconv;
        int j = threadIdx.x; // 0..255
        const float* x = hidden + (size_t)n * DM;
        float v0 = x[j], v1 = x[j + 256];
        float s = v0 + v1, q = v0 * v0 + v1 * v1;
#pragma unroll
        for (int o = 32; o; o >>= 1) { s += __shfl_down(s, o); q += __shfl_down(q, o); }
        __shared__ float red[8];
        int w = j >> 6;
        if ((j & 63) == 0) { red[w] = s; red[4 + w] = q; }
        __syncthreads();
        float sum = red[0] + red[1] + red[2] + red[3];
        float sq  = red[4] + red[5] + red[6] + red[7];
        float m = sum * (1.0f / DM);
        float var = sq * (1.0f / DM) - m * m;
        float rs = rsqrtf(var + LN_EPS);
        float t0 = (v0 - m) * rs, t1 = (v1 - m) * rs;
        size_t base = (size_t)n * DM;
        h_normb[base + j]       = __float2bfloat16(t0 * pg[j]       + pb[j]);
        h_normb[base + j + 256] = __float2bfloat16(t1 * pg[j + 256] + pb[j + 256]);
        hL[base + j]           = t0 * rg[j]       + rb[j];
        hL[base + j + 256]     = t1 * rg[j + 256] + rb[j + 256];
        return;
    }
    // -------- weight conversion: plain bf16 or 3-way split, K zero-pad --------
    int ji = 0;
#pragma unroll
    for (int i = 1; i < 10; i++) if (b >= J.j[i].blk0) ji = i;
    const ConvJob jb = J.j[ji];
    int rel = b - jb.blk0;
    int mat = rel / jb.KB, kb = rel % jb.KB;
    int ncols = jb.NB * 16;
    const float* s = jb.src + (size_t)mat * jb.Kreal * ncols;
    size_t dbase = ((size_t)mat * jb.KB + kb) * jb.NB * 512;
    for (int p = threadIdx.x; p < jb.NB * 64; p += 256) {
        int nb = p >> 6, lane = p & 63;
        int row0 = kb * 32 + ((lane >> 4) << 3);
        int col = nb * 16 + (lane & 15);
        if (jb.plain) {
            union { short sh[8]; uint4 v; } t;
#pragma unroll
            for (int j = 0; j < 8; j++) {
                float x = (row0 + j < jb.Kreal) ? s[(size_t)(row0 + j) * ncols + col] : 0.f;
                t.sh[j] = f2bf(x);
            }
            *(uint4*)&jb.dh[dbase + (size_t)p * 8] = t.v;
        } else {
            union { short sh[8]; uint4 v; } hi, mi, lo;
#pragma unroll
            for (int j = 0; j < 8; j++) {
                float x = (row0 + j < jb.Kreal) ? s[(size_t)(row0 + j) * ncols + col] : 0.f;
                split3(x, hi.sh[j], mi.sh[j], lo.sh[j]);
            }
            *(uint4*)&jb.dh[dbase + (size_t)p * 8] = hi.v;
            *(uint4*)&jb.dm[dbase + (size_t)p * 8] = mi.v;
            *(uint4*)&jb.dl[dbase + (size_t)p * 8] = lo.v;
        }
    }
}

// ---------------- 2-layer MLP body via 3-split MFMA: Y = gelu(LN?(X)@W1+b1)@W2+b2 ----------------
template <int KB_TOT, bool DO_LN>
__device__ __forceinline__ void enc2_body(
        int bx, char* smem,
        const float* __restrict__ X,
        const float* __restrict__ lng, const float* __restrict__ lnb,
        const short* __restrict__ W1h, const short* __restrict__ W1m, const short* __restrict__ W1l,
        const float* __restrict__ B1,
        const short* __restrict__ W2h, const short* __restrict__ W2m, const short* __restrict__ W2l,
        const float* __restrict__ B2,
        float* __restrict__ Y) {
    constexpr int K = KB_TOT * 32;
    const int n0 = bx * 32;
    const int tid = threadIdx.x;
    const int wave = tid >> 6, lane = tid & 63;
    const int quad = lane >> 4, lm = lane & 15;
    const int mt = wave & 1;
    const int ngb = (wave >> 1) * 4;   // 4 n-tiles per wave

    short (*Ah)[132] = (short(*)[132])smem;
    short (*Am)[132] = (short(*)[132])(smem + 32 * 132 * 2);
    short (*Al)[132] = (short(*)[132])(smem + 2 * 32 * 132 * 2);

    f32x4 acc[4];
#pragma unroll
    for (int i = 0; i < 4; i++) acc[i] = (f32x4)(0.f);

    if (DO_LN) {
        for (int idx = tid; idx < 1024; idx += 256) {
            int row = idx >> 5, c4 = (idx & 31) * 4;
            float4 v = *(const float4*)&X[(size_t)(n0 + row) * K + c4];
            float s = v.x + v.y + v.z + v.w;
            float q = v.x * v.x + v.y * v.y + v.z * v.z + v.w * v.w;
#pragma unroll
            for (int o = 16; o; o >>= 1) { s += __shfl_xor(s, o); q += __shfl_xor(q, o); }
            float mean = s * (1.0f / 128.0f);
            float var = q * (1.0f / 128.0f) - mean * mean;
            float rs = rsqrtf(var + LN_EPS);
            float xv[4] = {(v.x - mean) * rs * lng[c4 + 0] + lnb[c4 + 0],
                           (v.y - mean) * rs * lng[c4 + 1] + lnb[c4 + 1],
                           (v.z - mean) * rs * lng[c4 + 2] + lnb[c4 + 2],
                           (v.w - mean) * rs * lng[c4 + 3] + lnb[c4 + 3]};
#pragma unroll
            for (int j = 0; j < 4; j++) {
                short h, m, l; split3(xv[j], h, m, l);
                Ah[row][c4 + j] = h; Am[row][c4 + j] = m; Al[row][c4 + j] = l;
            }
        }
        __syncthreads();
#pragma unroll
        for (int kb = 0; kb < KB_TOT; kb++) {
            bf16x8 ah = *(const bf16x8*)&Ah[mt * 16 + lm][kb * 32 + quad * 8];
            bf16x8 am = *(const bf16x8*)&Am[mt * 16 + lm][kb * 32 + quad * 8];
            bf16x8 al = *(const bf16x8*)&Al[mt * 16 + lm][kb * 32 + quad * 8];
#pragma unroll
            for (int nt = 0; nt < 4; nt++) {
                size_t bi = (((size_t)kb * 8 + ngb + nt) * 64 + lane) * 8;
                bf16x8 bh = *(const bf16x8*)&W1h[bi];
                bf16x8 bm = *(const bf16x8*)&W1m[bi];
                bf16x8 bl = *(const bf16x8*)&W1l[bi];
                acc[nt] = MFMA16(al, bh, acc[nt]);
                acc[nt] = MFMA16(am, bm, acc[nt]);
                acc[nt] = MFMA16(ah, bl, acc[nt]);
                acc[nt] = MFMA16(am, bh, acc[nt]);
                acc[nt] = MFMA16(ah, bm, acc[nt]);
                acc[nt] = MFMA16(ah, bh, acc[nt]);
            }
        }
    } else {
        for (int kb = 0; kb < KB_TOT; kb++) {
            const float* xs = X + (size_t)(n0 + mt * 16 + lm) * K + kb * 32 + quad * 8;
            float4 x0 = *(const float4*)xs, x1 = *(const float4*)(xs + 4);
            float xv[8] = {x0.x, x0.y, x0.z, x0.w, x1.x, x1.y, x1.z, x1.w};
            bf16x8 ah, am, al;
#pragma unroll
            for (int j = 0; j < 8; j++) {
                short h, m, l; split3(xv[j], h, m, l);
                ah[j] = h; am[j] = m; al[j] = l;
            }
#pragma unroll
            for (int nt = 0; nt < 4; nt++) {
                size_t bi = (((size_t)kb * 8 + ngb + nt) * 64 + lane) * 8;
                bf16x8 bh = *(const bf16x8*)&W1h[bi];
                bf16x8 bm = *(const bf16x8*)&W1m[bi];
                bf16x8 bl = *(const bf16x8*)&W1l[bi];
                acc[nt] = MFMA16(al, bh, acc[nt]);
                acc[nt] = MFMA16(am, bm, acc[nt]);
                acc[nt] = MFMA16(ah, bl, acc[nt]);
                acc[nt] = MFMA16(am, bh, acc[nt]);
                acc[nt] = MFMA16(ah, bm, acc[nt]);
                acc[nt] = MFMA16(ah, bh, acc[nt]);
            }
        }
    }
    __syncthreads();
#pragma unroll
    for (int nt = 0; nt < 4; nt++) {
        int col = (ngb + nt) * 16 + lm;
        float b1 = B1[col];
#pragma unroll
        for (int r = 0; r < 4; r++) {
            int row = mt * 16 + quad * 4 + r;
            short h, m, l; split3(gelu_t(acc[nt][r] + b1), h, m, l);
            Ah[row][col] = h; Am[row][col] = m; Al[row][col] = l;
        }
    }
    __syncthreads();
    f32x4 acc2[4];
#pragma unroll
    for (int i = 0; i < 4; i++) acc2[i] = (f32x4)(0.f);
#pragma unroll
    for (int kb = 0; kb < 4; kb++) {
        bf16x8 ah = *(const bf16x8*)&Ah[mt * 16 + lm][kb * 32 + quad * 8];
        bf16x8 am = *(const bf16x8*)&Am[mt * 16 + lm][kb * 32 + quad * 8];
        bf16x8 al = *(const bf16x8*)&Al[mt * 16 + lm][kb * 32 + quad * 8];
#pragma unroll
        for (int nt = 0; nt < 4; nt++) {
            size_t bi = (((size_t)kb * 8 + ngb + nt) * 64 + lane) * 8;
            bf16x8 bh = *(const bf16x8*)&W2h[bi];
            bf16x8 bm = *(const bf16x8*)&W2m[bi];
            bf16x8 bl = *(const bf16x8*)&W2l[bi];
            acc2[nt] = MFMA16(al, bh, acc2[nt]);
            acc2[nt] = MFMA16(am, bm, acc2[nt]);
            acc2[nt] = MFMA16(ah, bl, acc2[nt]);
            acc2[nt] = MFMA16(am, bh, acc2[nt]);
            acc2[nt] = MFMA16(ah, bm, acc2[nt]);
            acc2[nt] = MFMA16(ah, bh, acc2[nt]);
        }
    }
#pragma unroll
    for (int nt = 0; nt < 4; nt++) {
        int col = (ngb + nt) * 16 + lm;
        float b2 = B2[col];
#pragma unroll
        for (int r = 0; r < 4; r++) {
            int row = mt * 16 + quad * 4 + r;
            Y[(size_t)(n0 + row) * DH + col] = acc2[nt][r] + b2;
        }
    }
}

// ---------------- single-group encoder body: one (32-token tile, group) per block ----------------
__device__ __forceinline__ void genc_one(
        int bx, int g, char* smem,
        const float* __restrict__ feat,
        const float* __restrict__ gln_g, const float* __restrict__ gln_b,
        const short* __restrict__ W1h, const short* __restrict__ W1m, const short* __restrict__ W1l,
        const float* __restrict__ gb1,
        const short* __restrict__ W2h, const short* __restrict__ W2m, const short* __restrict__ W2l,
        const float* __restrict__ gb2,
        float* __restrict__ g_enc) {
    const int n0 = bx * 32;
    const int tid = threadIdx.x;
    const int wave = tid >> 6, lane = tid & 63;
    const int quad = lane >> 4, lm = lane & 15;
    const int mt = wave & 1;
    const int ngb = (wave >> 1) * 4;

    short (*Ah)[132] = (short(*)[132])smem;
    short (*Am)[132] = (short(*)[132])(smem + 8448);
    short (*Al)[132] = (short(*)[132])(smem + 2 * 8448);

    {
        int t = tid >> 3, sub = tid & 7;
        const float* fr = feat + (size_t)(n0 + t) * FDIM + g * FG;
        float xv[FG];
        float mean = 0.f;
#pragma unroll
        for (int i = 0; i < FG; i++) { xv[i] = fr[i]; mean += xv[i]; }
        mean *= (1.0f / FG);
        float var = 0.f;
#pragma unroll
        for (int i = 0; i < FG; i++) { float d = xv[i] - mean; var += d * d; }
        var *= (1.0f / FG);
        float rs = rsqrtf(var + LN_EPS);
#pragma unroll
        for (int j = 0; j < 2; j++) {
            int i = sub * 2 + j;
            float xn = (xv[i] - mean) * rs * gln_g[g * FG + i] + gln_b[g * FG + i];
            short h, m, l; split3(xn, h, m, l);
            Ah[t][i] = h; Am[t][i] = m; Al[t][i] = l;
            Ah[t][16 + i] = 0; Am[t][16 + i] = 0; Al[t][16 + i] = 0;  // K pad to 32
        }
    }
    __syncthreads();
    f32x4 acc[4];
#pragma unroll
    for (int i = 0; i < 4; i++) acc[i] = (f32x4)(0.f);
    {
        bf16x8 ah = *(const bf16x8*)&Ah[mt * 16 + lm][quad * 8];
        bf16x8 am = *(const bf16x8*)&Am[mt * 16 + lm][quad * 8];
        bf16x8 al = *(const bf16x8*)&Al[mt * 16 + lm][quad * 8];
#pragma unroll
        for (int nt = 0; nt < 4; nt++) {
            size_t bi = (((size_t)g * 8 + ngb + nt) * 64 + lane) * 8;  // KB=1 per mat
            bf16x8 bh = *(const bf16x8*)&W1h[bi];
            bf16x8 bm = *(const bf16x8*)&W1m[bi];
            bf16x8 bl = *(const bf16x8*)&W1l[bi];
            acc[nt] = MFMA16(al, bh, acc[nt]);
            acc[nt] = MFMA16(am, bm, acc[nt]);
            acc[nt] = MFMA16(ah, bl, acc[nt]);
            acc[nt] = MFMA16(am, bh, acc[nt]);
            acc[nt] = MFMA16(ah, bm, acc[nt]);
            acc[nt] = MFMA16(ah, bh, acc[nt]);
        }
    }
    __syncthreads();
#pragma unroll
    for (int nt = 0; nt < 4; nt++) {
        int col = (ngb + nt) * 16 + lm;
        float b1 = gb1[g * DH + col];
#pragma unroll
        for (int r = 0; r < 4; r++) {
            int row = mt * 16 + quad * 4 + r;
            short h, m, l; split3(gelu_t(acc[nt][r] + b1), h, m, l);
            Ah[row][col] = h; Am[row][col] = m; Al[row][col] = l;
        }
    }
    __syncthreads();
    f32x4 acc2[4];
#pragma unroll
    for (int i = 0; i < 4; i++) acc2[i] = (f32x4)(0.f);
#pragma unroll
    for (int kb = 0; kb < 4; kb++) {
        bf16x8 a2h = *(const bf16x8*)&Ah[mt * 16 + lm][kb * 32 + quad * 8];
        bf16x8 a2m = *(const bf16x8*)&Am[mt * 16 + lm][kb * 32 + quad * 8];
        bf16x8 a2l = *(const bf16x8*)&Al[mt * 16 + lm][kb * 32 + quad * 8];
#pragma unroll
        for (int nt = 0; nt < 4; nt++) {
            size_t bi = ((((size_t)g * 4 + kb) * 8 + ngb + nt) * 64 + lane) * 8;
            bf16x8 bh = *(const bf16x8*)&W2h[bi];
            bf16x8 bm = *(const bf16x8*)&W2m[bi];
            bf16x8 bl = *(const bf16x8*)&W2l[bi];
            acc2[nt] = MFMA16(a2l, bh, acc2[nt]);
            acc2[nt] = MFMA16(a2m, bm, acc2[nt]);
            acc2[nt] = MFMA16(a2h, bl, acc2[nt]);
            acc2[nt] = MFMA16(a2m, bh, acc2[nt]);
            acc2[nt] = MFMA16(a2h, bm, acc2[nt]);
            acc2[nt] = MFMA16(a2h, bh, acc2[nt]);
        }
    }
#pragma unroll
    for (int nt = 0; nt < 4; nt++) {
        int col = (ngb + nt) * 16 + lm;
        float b2 = gb2[g * DH + col];
#pragma unroll
        for (int r = 0; r < 4; r++) {
            int row = mt * 16 + quad * 4 + r;
            g_enc[((size_t)(n0 + row) * G + g) * DH + col] = acc2[nt][r] + b2;
        }
    }
}

// ---------------- fused encoder launch: rh(128) + sf(128) + genc(1024) blocks ----------------
__global__ __launch_bounds__(256) void k_enc_all(
        const float* __restrict__ hL, const float* __restrict__ feat,
        const float* __restrict__ sf_g, const float* __restrict__ sf_b,
        const float* __restrict__ gln_g, const float* __restrict__ gln_b,
        const short* Brh1H, const short* Brh1M, const short* Brh1L, const float* rh_b1,
        const short* Brh2H, const short* Brh2M, const short* Brh2L, const float* rh_b2,
        const short* Bsf1H, const short* Bsf1M, const short* Bsf1L, const float* sf_b1,
        const short* Bsf2H, const short* Bsf2M, const short* Bsf2L, const float* sf_b2,
        const short* Bgf1H, const short* Bgf1M, const short* Bgf1L, const float* gf_b1,
        const short* Bgf2H, const short* Bgf2M, const short* Bgf2L, const float* gf_b2,
        float* __restrict__ h_enc, float* __restrict__ s_enc, float* __restrict__ g_enc) {
    __shared__ __align__(16) char smem[3 * 8448];   // 25.3 KB -> 6 blocks/CU
    int bid = blockIdx.x;
    if (bid < 128)
        enc2_body<16, false>(bid, smem, hL, nullptr, nullptr,
                             Brh1H, Brh1M, Brh1L, rh_b1, Brh2H, Brh2M, Brh2L, rh_b2, h_enc);
    else if (bid < 256)
        enc2_body<4, true>(bid - 128, smem, feat, sf_g, sf_b,
                           Bsf1H, Bsf1M, Bsf1L, sf_b1, Bsf2H, Bsf2M, Bsf2L, sf_b2, s_enc);
    else {
        int idx = bid - 256;    // (idx & 7) = group -> XCD affinity for gf weights
        genc_one(idx >> 3, idx & 7, smem, feat, gln_g, gln_b,
                 Bgf1H, Bgf1M, Bgf1L, gf_b1, Bgf2H, Bgf2M, Bgf2L, gf_b2, g_enc);
    }
}

// ---------------- MFMA router v4: 64 tokens x 1 group, 8 waves, LDS-staged A from raw enc ----------------
// All A fragments (h|s for k<256, g|h*g for k>=256) are built by split3 from raw fp32 encoder
// outputs directly in the staging loop — no pre-staged A_hs arrays, no k_stage_hs kernel.
__global__ __launch_bounds__(512) void k_router_mfma(
        const float* __restrict__ h_enc, const float* __restrict__ s_enc,
        const float* __restrict__ g_enc,
        const short* __restrict__ BpgH, const short* __restrict__ BpgM, const short* __restrict__ BpgL,
        const short* __restrict__ BirH, const short* __restrict__ BirM, const short* __restrict__ BirL,
        const float* __restrict__ pb1, const float* __restrict__ pw2, const float* __restrict__ pb2,
        const float* __restrict__ ib1, const float* __restrict__ iw2, const float* __restrict__ ib2,
        float* __restrict__ glog, float* __restrict__ ilog) {
    const int g = blockIdx.x & 7;       // group -> XCD affinity for B + g_enc
    const int bx = blockIdx.x >> 3;     // 64-token tile (0..63)
    const int n0 = bx * 64;
    const int tid = threadIdx.x;
    const int wave = tid >> 6, lane = tid & 63;
    const int quad = lane >> 4, lm = lane & 15;
    const bool is_pg = wave < 4;
    const int nbase = (wave & 3) * 2;   // 2 n-tiles per wave, 4 waves cover 8
    const short* Bh = is_pg ? BpgH : (BirH + (size_t)g * 65536);
    const short* Bm = is_pg ? BpgM : (BirM + (size_t)g * 65536);
    const short* Bl = is_pg ? BpgL : (BirL + (size_t)g * 65536);

    // LDS: A staging for one 4-kb chunk: [split 3][kbl 4][t16 4][lane 64][8 shorts] = 48 KB.
    // Epilogue (2 x 32x129 fp32 = 33 KB) aliases it after the K-loop.
    __shared__ __align__(16) char smem[49152];

    f32x4 acc[4][2];
#pragma unroll
    for (int mt = 0; mt < 4; mt++)
#pragma unroll
        for (int nt = 0; nt < 2; nt++) acc[mt][nt] = (f32x4)(0.f);

    for (int ch = 0; ch < 4; ch++) {
        __syncthreads();   // previous chunk's LDS reads complete
        // stage chunk: items = (kbl, t16, lane2); split3 from raw encoder fp32
        for (int idx = tid; idx < 1024; idx += 512) {
            int kbl = idx >> 8, rem = idx & 255;
            int t16 = rem >> 6, lane2 = rem & 63;
            int gkb = ch * 4 + kbl;
            size_t loff = (size_t)kbl * 4096 + t16 * 1024 + (size_t)lane2 * 16;
            int n = n0 + t16 * 16 + (lane2 & 15);
            int csub = (lane2 >> 4) * 8;
            float xv[8];
            if (gkb < 8) {
                // k in [0,256) = [h_enc | s_enc]
                int c0 = gkb * 32 + csub;
                const float* src = (c0 < 128) ? (h_enc + (size_t)n * DH + c0)
                                              : (s_enc + (size_t)n * DH + (c0 - 128));
                float4 x0 = *(const float4*)src, x1 = *(const float4*)(src + 4);
                xv[0]=x0.x; xv[1]=x0.y; xv[2]=x0.z; xv[3]=x0.w;
                xv[4]=x1.x; xv[5]=x1.y; xv[6]=x1.z; xv[7]=x1.w;
            } else {
                // k in [256,512) = [g_enc | h_enc*g_enc]
                int c0 = (gkb - 8) * 32 + csub;
                if (c0 < 128) {
                    const float* gs = g_enc + ((size_t)n * G + g) * DH + c0;
                    float4 x0 = *(const float4*)gs, x1 = *(const float4*)(gs + 4);
                    xv[0]=x0.x; xv[1]=x0.y; xv[2]=x0.z; xv[3]=x0.w;
                    xv[4]=x1.x; xv[5]=x1.y; xv[6]=x1.z; xv[7]=x1.w;
                } else {
                    int c = c0 - 128;
                    const float* gs = g_enc + ((size_t)n * G + g) * DH + c;
                    const float* hsrc = h_enc + (size_t)n * DH + c;
                    float4 g0 = *(const float4*)gs, g1 = *(const float4*)(gs + 4);
                    float4 h0 = *(const float4*)hsrc, h1 = *(const float4*)(hsrc + 4);
                    xv[0]=h0.x*g0.x; xv[1]=h0.y*g0.y; xv[2]=h0.z*g0.z; xv[3]=h0.w*g0.w;
                    xv[4]=h1.x*g1.x; xv[5]=h1.y*g1.y; xv[6]=h1.z*g1.z; xv[7]=h1.w*g1.w;
                }
            }
            union { short sh[8]; uint4 v; } hi, mi, lo;
#pragma unroll
            for (int j = 0; j < 8; j++) split3(xv[j], hi.sh[j], mi.sh[j], lo.sh[j]);
            *(uint4*)(smem + loff)         = hi.v;
            *(uint4*)(smem + 16384 + loff) = mi.v;
            *(uint4*)(smem + 32768 + loff) = lo.v;
        }
        __syncthreads();
        // compute chunk
#pragma unroll
        for (int kbl = 0; kbl < 4; kbl++) {
            int kb = ch * 4 + kbl;
            bf16x8 Ahf[4], Amf[4], Alf[4];
#pragma unroll
            for (int mt = 0; mt < 4; mt++) {
                size_t loff = (size_t)kbl * 4096 + mt * 1024 + (size_t)lane * 16;
                Ahf[mt] = *(const bf16x8*)(smem + loff);
                Amf[mt] = *(const bf16x8*)(smem + 16384 + loff);
                Alf[mt] = *(const bf16x8*)(smem + 32768 + loff);
            }
#pragma unroll
            for (int nt = 0; nt < 2; nt++) {
                int nb = nbase + nt;
                size_t bi = (((size_t)kb * 8 + nb) * 64 + lane) * 8;
                bf16x8 bh = *(const bf16x8*)&Bh[bi];
                bf16x8 bm = *(const bf16x8*)&Bm[bi];
                bf16x8 bl = *(const bf16x8*)&Bl[bi];
#pragma unroll
                for (int mt = 0; mt < 4; mt++) {
                    acc[mt][nt] = MFMA16(Alf[mt], bh, acc[mt][nt]);
                    acc[mt][nt] = MFMA16(Amf[mt], bm, acc[mt][nt]);
                    acc[mt][nt] = MFMA16(Ahf[mt], bl, acc[mt][nt]);
                    acc[mt][nt] = MFMA16(Amf[mt], bh, acc[mt][nt]);
                    acc[mt][nt] = MFMA16(Ahf[mt], bm, acc[mt][nt]);
                    acc[mt][nt] = MFMA16(Ahf[mt], bh, acc[mt][nt]);
                }
            }
        }
    }

    // epilogue: two 32-row halves reusing staging LDS (ph 32x129 + ih 32x129 = 33 KB)
    float (*ph)[129] = (float(*)[129])smem;
    float (*ih)[129] = (float(*)[129])(smem + 32 * 129 * 4);
    for (int h = 0; h < 2; h++) {
        __syncthreads();   // h=0: K-loop LDS reads done; h=1: prev half's logit reads done
#pragma unroll
        for (int mi = 0; mi < 2; mi++) {
            int mt = 2 * h + mi;
#pragma unroll
            for (int nt = 0; nt < 2; nt++) {
                int col = (nbase + nt) * 16 + lm;
                float b1 = is_pg ? pb1[col] : ib1[g * DH + col];
                float* dst = is_pg ? &ph[0][0] : &ih[0][0];
#pragma unroll
                for (int r = 0; r < 4; r++) {
                    int row = mi * 16 + quad * 4 + r;
                    dst[row * 129 + col] = gelu_t(acc[mt][nt][r] + b1);
                }
            }
        }
        __syncthreads();
        if (tid < 32) {
            float s = pb2[0];
            for (int i = 0; i < DH; i++) s += ph[tid][i] * pw2[i];
            glog[(size_t)(n0 + h * 32 + tid) * G + g] = s; // TEMP = 1.0
        } else if (tid >= 128 && tid < 256) {
            int t = (tid - 128) >> 2, e = (tid - 128) & 3;
            float s = ib2[g * ES + e];
            const float* w = iw2 + (size_t)g * DH * ES;
            for (int i = 0; i < DH; i++) s += ih[t][i] * w[i * ES + e];
            ilog[((size_t)(n0 + h * 32 + t) * G + g) * ES + e] = s;
        }
    }
}

// ---------------- top-k softmax + dispatch to per-expert lists ----------------
__global__ void k_topk(const float* __restrict__ glog, const float* __restrict__ ilog,
                       int* __restrict__ cnt, int* __restrict__ toks, float* __restrict__ wgts) {
    int n = blockIdx.x * blockDim.x + threadIdx.x;
    if (n >= N_TOK) return;
    float gl[G];
#pragma unroll
    for (int g = 0; g < G; g++) gl[g] = glog[(size_t)n * G + g];
    int i1 = 0; float v1 = gl[0];
#pragma unroll
    for (int g = 1; g < G; g++) if (gl[g] > v1) { v1 = gl[g]; i1 = g; }
    int i2 = -1; float v2 = -1e30f;
#pragma unroll
    for (int g = 0; g < G; g++) if (g != i1 && gl[g] > v2) { v2 = gl[g]; i2 = g; }
    float eg = expf(v2 - v1);
    float den = 1.0f / (1.0f + eg);
    float gw_sel[2] = { den, eg * den };
    int g_sel[2] = { i1, i2 };
#pragma unroll
    for (int s = 0; s < 2; s++) {
        int g = g_sel[s]; float gw = gw_sel[s];
        float il[ES];
#pragma unroll
        for (int e = 0; e < ES; e++) il[e] = ilog[((size_t)n * G + g) * ES + e];
        int j1 = 0; float u1 = il[0];
#pragma unroll
        for (int e = 1; e < ES; e++) if (il[e] > u1) { u1 = il[e]; j1 = e; }
        int j2 = -1; float u2 = -1e30f;
#pragma unroll
        for (int e = 0; e < ES; e++) if (e != j1 && il[e] > u2) { u2 = il[e]; j2 = e; }
        float ei = expf(u2 - u1);
        float d2 = 1.0f / (1.0f + ei);
        int ex1 = g * ES + j1, ex2 = g * ES + j2;
        int p1 = atomicAdd(&cnt[ex1], 1);
        toks[(size_t)ex1 * N_TOK + p1] = n * 4 + s * 2;     wgts[(size_t)ex1 * N_TOK + p1] = gw * d2;
        int p2 = atomicAdd(&cnt[ex2], 1);
        toks[(size_t)ex2 * N_TOK + p2] = n * 4 + s * 2 + 1; wgts[(size_t)ex2 * N_TOK + p2] = gw * ei * d2;
    }
}

// ---------------- sparse expert MLPs via bf16 MFMA; XCD-swizzled; es aliases hs (33KB LDS) ----------------
__global__ __launch_bounds__(512) void k_expert_mfma(
        const __hip_bfloat16* __restrict__ h_normb,
        const short* __restrict__ wB1, const float* __restrict__ eb1,
        const short* __restrict__ wB2, const float* __restrict__ eb2,
        const int* __restrict__ cnt, const int* __restrict__ toks,
        const float* __restrict__ wgts, float* __restrict__ part) {
    const int e = blockIdx.x & 31;
    const int slot = blockIdx.x >> 5;
    const int c = cnt[e];
    const int start = slot * BT;
    if (start >= c) return;
    const int m = min(BT, c - start);

    __shared__ short hs[BT][520];                   // 33.3 KB; es aliases (dead after phase 1)
    short (*es)[264] = (short(*)[264])&hs[0][0];    // 16.9 KB
    __shared__ int   tok_s[BT];
    __shared__ float w_s[BT];

    const int tid = threadIdx.x;
    if (tid < BT) {
        bool ok = tid < m;
        tok_s[tid] = ok ? toks[(size_t)e * N_TOK + start + tid] : 0;
        w_s[tid]   = ok ? wgts[(size_t)e * N_TOK + start + tid] : 0.f;
    }
    __syncthreads();
    for (int idx = tid; idx < BT * 64; idx += 512) {
        int t = idx >> 6, ch = idx & 63;
        uint4 v = make_uint4(0, 0, 0, 0);
        if (t < m) v = *((const uint4*)(h_normb + (size_t)(tok_s[t] >> 2) * DM) + ch);
        *(uint4*)&hs[t][ch * 8] = v;
    }
    __syncthreads();

    const int wave = tid >> 6, lane = tid & 63;
    const int quad = lane >> 4, lm = lane & 15;

    // ---- phase 1: acc = hs @ W1 (reads hs) ----
    const int ng = wave * 2;
    f32x4 acc1[2][2];
#pragma unroll
    for (int a = 0; a < 2; a++)
#pragma unroll
        for (int b = 0; b < 2; b++) acc1[a][b] = (f32x4)(0.f);
    {
        const short* w1e = wB1 + (size_t)e * DM * DE;
        for (int kb = 0; kb < 16; kb++) {
            bf16x8 a0 = *(const bf16x8*)&hs[lm][kb * 32 + quad * 8];
            bf16x8 a1 = *(const bf16x8*)&hs[16 + lm][kb * 32 + quad * 8];
            const short* wp = w1e + ((size_t)kb * 16 + ng) * 512 + lane * 8;
#pragma unroll
            for (int nt = 0; nt < 2; nt++) {
                bf16x8 b = *(const bf16x8*)(wp + nt * 512);
                acc1[0][nt] = MFMA16(a0, b, acc1[0][nt]);
                acc1[1][nt] = MFMA16(a1, b, acc1[1][nt]);
            }
        }
    }
    __syncthreads();   // all waves done reading hs before es overwrite
#pragma unroll
    for (int nt = 0; nt < 2; nt++) {
        int col = (ng + nt) * 16 + lm;
        float b1 = eb1[e * DE + col];
#pragma unroll
        for (int mt = 0; mt < 2; mt++)
#pragma unroll
        for (int r = 0; r < 4; r++) {
            int row = mt * 16 + quad * 4 + r;
            es[row][col] = f2bf(gelu_t(acc1[mt][nt][r] + b1));
        }
    }
    __syncthreads();

    // ---- phase 2: part[tok] = w * (es @ W2 + b2) ----
    {
        const int ng2 = wave * 4;
        f32x4 acc[2][4];
#pragma unroll
        for (int a = 0; a < 2; a++)
#pragma unroll
            for (int b = 0; b < 4; b++) acc[a][b] = (f32x4)(0.f);
        const short* w2e = wB2 + (size_t)e * DE * DM;
        for (int kb = 0; kb < 8; kb++) {
            bf16x8 a0 = *(const bf16x8*)&es[lm][kb * 32 + quad * 8];
            bf16x8 a1 = *(const bf16x8*)&es[16 + lm][kb * 32 + quad * 8];
            const short* wp = w2e + ((size_t)kb * 32 + ng2) * 512 + lane * 8;
#pragma unroll
            for (int nt = 0; nt < 4; nt++) {
                bf16x8 b = *(const bf16x8*)(wp + nt * 512);
                acc[0][nt] = MFMA16(a0, b, acc[0][nt]);
                acc[1][nt] = MFMA16(a1, b, acc[1][nt]);
            }
        }
        const float* b2 = eb2 + (size_t)e * DM;
#pragma unroll
        for (int mt = 0; mt < 2; mt++)
#pragma unroll
        for (int r = 0; r < 4; r++) {
            int row = mt * 16 + quad * 4 + r;
            if (row < m) {
                float w = w_s[row];
                float* prow = part + (size_t)tok_s[row] * DM;
#pragma unroll
                for (int nt = 0; nt < 4; nt++) {
                    int col = (ng2 + nt) * 16 + lm;
                    prow[col] = w * (acc[mt][nt][r] + b2[col]);
                }
            }
        }
    }
}

// ---------------- final reduce: out[n] = sum_s part[n*4+s] ----------------
__global__ void k_reduce(const float* __restrict__ part, float* __restrict__ out) {
    int n = blockIdx.x;
    int j = threadIdx.x; // 0..127
    const float4* p = (const float4*)(part + (size_t)n * 4 * DM);
    float4 a = p[j], b = p[128 + j], c = p[256 + j], d = p[384 + j];
    float4 r = make_float4(a.x + b.x + c.x + d.x, a.y + b.y + c.y + d.y,
                           a.z + b.z + c.z + d.z, a.w + b.w + c.w + d.w);
    ((float4*)(out + (size_t)n * DM))[j] = r;
}

extern "C" void kernel_launch(void* const* d_in, const int* in_sizes, int n_in,
                              void* d_out, int out_size, void* d_ws, size_t ws_size,
                              hipStream_t stream) {
    const float* hidden  = (const float*)d_in[0];
    const float* feat    = (const float*)d_in[1];
    const float* pre_g   = (const float*)d_in[2];
    const float* pre_b   = (const float*)d_in[3];
    const float* rh_g    = (const float*)d_in[4];
    const float* rh_b    = (const float*)d_in[5];
    const float* rh_w1   = (const float*)d_in[6];
    const float* rh_b1   = (const float*)d_in[7];
    const float* rh_w2   = (const float*)d_in[8];
    const float* rh_b2   = (const float*)d_in[9];
    const float* sf_g    = (const float*)d_in[10];
    const float* sf_b    = (const float*)d_in[11];
    const float* sf_w1   = (const float*)d_in[12];
    const float* sf_b1   = (const float*)d_in[13];
    const float* sf_w2   = (const float*)d_in[14];
    const float* sf_b2   = (const float*)d_in[15];
    const float* gln_g   = (const float*)d_in[16];
    const float* gln_b   = (const float*)d_in[17];
    const float* gf_w1   = (const float*)d_in[18];
    const float* gf_b1   = (const float*)d_in[19];
    const float* gf_w2   = (const float*)d_in[20];
    const float* gf_b2   = (const float*)d_in[21];
    const float* pgs_w1  = (const float*)d_in[22];
    const float* pgs_b1  = (const float*)d_in[23];
    const float* pgs_w2  = (const float*)d_in[24];
    const float* pgs_b2  = (const float*)d_in[25];
    const float* ir_w1   = (const float*)d_in[26];
    const float* ir_b1   = (const float*)d_in[27];
    const float* ir_w2   = (const float*)d_in[28];
    const float* ir_b2   = (const float*)d_in[29];
    const float* ex_w1   = (const float*)d_in[30];
    const float* ex_b1   = (const float*)d_in[31];
    const float* ex_w2   = (const float*)d_in[32];
    const float* ex_b2   = (const float*)d_in[33];
    float* out = (float*)d_out;

    // workspace carving (256B-aligned)
    char* w = (char*)d_ws;
    auto alloc = [&](size_t bytes) { void* r = (void*)w; w += (bytes + 255) & ~(size_t)255; return r; };
    __hip_bfloat16* h_normb = (__hip_bfloat16*)alloc((size_t)N_TOK * DM * 2);
    float* h_enc = (float*)alloc((size_t)N_TOK * DH * 4);
    float* s_enc = (float*)alloc((size_t)N_TOK * DH * 4);
    float* g_enc = (float*)alloc((size_t)N_TOK * G * DH * 4);
    float* glog  = (float*)alloc((size_t)N_TOK * G * 4);
    float* ilog  = (float*)alloc((size_t)N_TOK * G * ES * 4);
    float* wgts  = (float*)alloc((size_t)E_EXP * N_TOK * 4);
    short* wB1   = (short*)alloc((size_t)E_EXP * DM * DE * 2);
    short* wB2   = (short*)alloc((size_t)E_EXP * DE * DM * 2);
    short* BpgH  = (short*)alloc((size_t)16 * 8 * 512 * 2);
    short* BpgM  = (short*)alloc((size_t)16 * 8 * 512 * 2);
    short* BpgL  = (short*)alloc((size_t)16 * 8 * 512 * 2);
    short* BirH  = (short*)alloc((size_t)G * 16 * 8 * 512 * 2);
    short* BirM  = (short*)alloc((size_t)G * 16 * 8 * 512 * 2);
    short* BirL  = (short*)alloc((size_t)G * 16 * 8 * 512 * 2);
    short* Brh1H = (short*)alloc((size_t)16 * 8 * 512 * 2);
    short* Brh1M = (short*)alloc((size_t)16 * 8 * 512 * 2);
    short* Brh1L = (short*)alloc((size_t)16 * 8 * 512 * 2);
    short* Brh2H = (short*)alloc((size_t)4 * 8 * 512 * 2);
    short* Brh2M = (short*)alloc((size_t)4 * 8 * 512 * 2);
    short* Brh2L = (short*)alloc((size_t)4 * 8 * 512 * 2);
    short* Bsf1H = (short*)alloc((size_t)4 * 8 * 512 * 2);
    short* Bsf1M = (short*)alloc((size_t)4 * 8 * 512 * 2);
    short* Bsf1L = (short*)alloc((size_t)4 * 8 * 512 * 2);
    short* Bsf2H = (short*)alloc((size_t)4 * 8 * 512 * 2);
    short* Bsf2M = (short*)alloc((size_t)4 * 8 * 512 * 2);
    short* Bsf2L = (short*)alloc((size_t)4 * 8 * 512 * 2);
    short* Bgf1H = (short*)alloc((size_t)G * 1 * 8 * 512 * 2);
    short* Bgf1M = (short*)alloc((size_t)G * 1 * 8 * 512 * 2);
    short* Bgf1L = (short*)alloc((size_t)G * 1 * 8 * 512 * 2);
    short* Bgf2H = (short*)alloc((size_t)G * 4 * 8 * 512 * 2);
    short* Bgf2M = (short*)alloc((size_t)G * 4 * 8 * 512 * 2);
    short* Bgf2L = (short*)alloc((size_t)G * 4 * 8 * 512 * 2);
    int* cnt     = (int*)alloc(E_EXP * 4);
    int* toks    = (int*)alloc((size_t)E_EXP * N_TOK * 4);
    // union region (disjoint live ranges, stream-ordered):
    //   hL   [k_pre -> k_enc_all]          8.4 MB
    //   part [k_expert_mfma -> k_reduce]  33.6 MB
    char* uni   = (char*)alloc((size_t)N_TOK * 4 * DM * 4); // 33.6 MB = max
    float* hL   = (float*)uni;
    float* part = (float*)uni;

    hipMemsetAsync(cnt, 0, E_EXP * sizeof(int), stream);

    // fused pre-pass: 10 weight-conversion jobs + 4096 LN blocks, one launch
    ConvJobs J;
    int b0 = 0;
    auto mkjob = [&](int i, const float* s, short* dh, short* dm, short* dl,
                     int KB, int NB, int Kreal, int plain, int nmat) {
        J.j[i] = ConvJob{s, dh, dm, dl, KB, NB, Kreal, plain, b0};
        b0 += KB * nmat;
    };
    mkjob(0, ex_w1, wB1, nullptr, nullptr, 16, 16, 512, 1, E_EXP);
    mkjob(1, ex_w2, wB2, nullptr, nullptr, 8, 32, 256, 1, E_EXP);
    mkjob(2, pgs_w1, BpgH, BpgM, BpgL, 16, 8, 512, 0, 1);
    mkjob(3, ir_w1, BirH, BirM, BirL, 16, 8, 512, 0, G);
    mkjob(4, rh_w1, Brh1H, Brh1M, Brh1L, 16, 8, 512, 0, 1);
    mkjob(5, rh_w2, Brh2H, Brh2M, Brh2L, 4, 8, 128, 0, 1);
    mkjob(6, sf_w1, Bsf1H, Bsf1M, Bsf1L, 4, 8, 128, 0, 1);
    mkjob(7, sf_w2, Bsf2H, Bsf2M, Bsf2L, 4, 8, 128, 0, 1);
    mkjob(8, gf_w1, Bgf1H, Bgf1M, Bgf1L, 1, 8, 16, 0, G);
    mkjob(9, gf_w2, Bgf2H, Bgf2M, Bgf2L, 4, 8, 128, 0, G);
    k_pre<<<b0 + N_TOK, 256, 0, stream>>>(J, b0, hidden, pre_g, pre_b, rh_g, rh_b, h_normb, hL);

    // fused encoders: rh(128) + sf(128) + per-(tile,group) genc(1024) = 1280 blocks
    k_enc_all<<<256 + (N_TOK / 32) * G, 256, 0, stream>>>(
        hL, feat, sf_g, sf_b, gln_g, gln_b,
        Brh1H, Brh1M, Brh1L, rh_b1, Brh2H, Brh2M, Brh2L, rh_b2,
        Bsf1H, Bsf1M, Bsf1L, sf_b1, Bsf2H, Bsf2M, Bsf2L, sf_b2,
        Bgf1H, Bgf1M, Bgf1L, gf_b1, Bgf2H, Bgf2M, Bgf2L, gf_b2,
        h_enc, s_enc, g_enc);

    // router v4: 64-token tiles, 512 threads, all A staged in-kernel from raw enc outputs
    k_router_mfma<<<(N_TOK / 64) * G, 512, 0, stream>>>(h_enc, s_enc, g_enc,
                                             BpgH, BpgM, BpgL, BirH, BirM, BirL,
                                             pgs_b1, pgs_w2, pgs_b2, ir_b1, ir_w2, ir_b2,
                                             glog, ilog);

    k_topk<<<N_TOK / 256, 256, 0, stream>>>(glog, ilog, cnt, toks, wgts);
    // XCD-swizzled 1D expert grid: bid = slot*32 + e
    k_expert_mfma<<<(N_TOK / BT) * E_EXP, 512, 0, stream>>>(h_normb, wB1, ex_b1, wB2, ex_b2,
                                                            cnt, toks, wgts, part);
    k_reduce<<<N_TOK, 128, 0, stream>>>(part, out);
}